// Round 1
// baseline (5176.886 us; speedup 1.0000x reference)
//
#include <hip/hip_runtime.h>

#define D 1024
#define HD 128
#define EA 8
#define EF 16
#define FH 512
#define MAXPOS 64
#define RNUM 129
#define SEQ 1024
#define NTOK 4096
#define LN_EPS 1e-5f

// ---------------- LayerNorm: one block (256 thr) per row of 1024 ----------------
__global__ void ln_kernel(const float* __restrict__ x, const float* __restrict__ w,
                          const float* __restrict__ b, float* __restrict__ y) {
    int row = blockIdx.x;
    const float* xr = x + (size_t)row * D;
    float v[4];
    float s = 0.f, s2 = 0.f;
#pragma unroll
    for (int i = 0; i < 4; i++) {
        v[i] = xr[threadIdx.x + i * 256];
        s += v[i]; s2 += v[i] * v[i];
    }
#pragma unroll
    for (int off = 32; off; off >>= 1) { s += __shfl_down(s, off); s2 += __shfl_down(s2, off); }
    __shared__ float red0[4], red1[4];
    int wave = threadIdx.x >> 6, lane = threadIdx.x & 63;
    if (lane == 0) { red0[wave] = s; red1[wave] = s2; }
    __syncthreads();
    float ts = red0[0] + red0[1] + red0[2] + red0[3];
    float ts2 = red1[0] + red1[1] + red1[2] + red1[3];
    float mu = ts * (1.f / D);
    float var = ts2 * (1.f / D) - mu * mu;
    float inv = rsqrtf(var + LN_EPS);
#pragma unroll
    for (int i = 0; i < 4; i++) {
        int d = threadIdx.x + i * 256;
        y[(size_t)row * D + d] = (v[i] - mu) * inv * w[d] + b[d];
    }
}

// ---------------- Router: one wave per token, top-2 + softmax ----------------
template <int E>
__global__ void router_kernel(const float* __restrict__ xn, const float* __restrict__ gw,
                              int* __restrict__ idx, float* __restrict__ gate) {
    int t = blockIdx.x;
    int lane = threadIdx.x;  // block=64
    float acc[E];
#pragma unroll
    for (int e = 0; e < E; e++) acc[e] = 0.f;
    const float* xr = xn + (size_t)t * D;
    for (int d = lane; d < D; d += 64) {
        float xv = xr[d];
#pragma unroll
        for (int e = 0; e < E; e++) acc[e] += xv * gw[d * E + e];
    }
#pragma unroll
    for (int e = 0; e < E; e++) {
#pragma unroll
        for (int off = 32; off; off >>= 1) acc[e] += __shfl_down(acc[e], off);
    }
    if (lane == 0) {
        float v0 = -1e30f, v1 = -1e30f;
        int i0 = 0, i1 = 0;
#pragma unroll
        for (int e = 0; e < E; e++) {
            float a = acc[e];
            if (a > v0) { v1 = v0; i1 = i0; v0 = a; i0 = e; }
            else if (a > v1) { v1 = a; i1 = e; }
        }
        float g0 = 1.f / (1.f + expf(v1 - v0));  // softmax of [v0, v1]
        idx[t * 2] = i0; idx[t * 2 + 1] = i1;
        gate[t * 2] = g0; gate[t * 2 + 1] = 1.f - g0;
    }
}

// ---------------- Shared K/V projection: one block (128 thr) per token ----------------
__global__ void kv_kernel(const float* __restrict__ xn,
                          const float* __restrict__ kw, const float* __restrict__ kb,
                          const float* __restrict__ vw, const float* __restrict__ vb,
                          float* __restrict__ kbuf, float* __restrict__ vbuf) {
    int t = blockIdx.x;
    __shared__ float x[D];
    for (int d = threadIdx.x; d < D; d += 128) x[d] = xn[(size_t)t * D + d];
    __syncthreads();
    int h = threadIdx.x;
    float ak = kb[h], av = vb[h];
    for (int d = 0; d < D; d++) {
        float xv = x[d];
        ak += xv * kw[d * HD + h];
        av += xv * vw[d * HD + h];
    }
    kbuf[(size_t)t * HD + h] = ak;
    vbuf[(size_t)t * HD + h] = av;
}

// ---------------- Q projection for selected experts: block per (token, j) ----------------
__global__ void q_kernel(const float* __restrict__ xn, const float* __restrict__ qw,
                         const float* __restrict__ qb, const int* __restrict__ aidx,
                         float* __restrict__ qbuf) {
    int tj = blockIdx.x;
    int t = tj >> 1, j = tj & 1;
    int e = aidx[t * 2 + j];
    __shared__ float x[D];
    for (int d = threadIdx.x; d < D; d += 128) x[d] = xn[(size_t)t * D + d];
    __syncthreads();
    int h = threadIdx.x;
    const float* w = qw + (size_t)e * D * HD;
    float a = 0.f;
    for (int d = 0; d < D; d++) a += x[d] * w[d * HD + h];
    qbuf[(size_t)tj * HD + h] = (a + qb[e * HD + h]) * 0.08838834764831845f;  // HD^-0.5
}

// ---------------- Attention: block (128 thr) per token, both selected experts ----------------
__global__ void attn_kernel(const float* __restrict__ qbuf, const float* __restrict__ kbuf,
                            const float* __restrict__ vbuf, const float* __restrict__ rel,
                            float* __restrict__ ctx) {
    int t = blockIdx.x;
    int b = t / SEQ;
    int qpos = t % SEQ;
    int tid = threadIdx.x;
    __shared__ float q0[HD], q1[HD];
    __shared__ float r0[RNUM + 3], r1[RNUM + 3];
    __shared__ float s0[SEQ], s1[SEQ];
    __shared__ float wred[4][2];
    q0[tid] = qbuf[((size_t)t * 2 + 0) * HD + tid];
    q1[tid] = qbuf[((size_t)t * 2 + 1) * HD + tid];
    __syncthreads();
    // rel-pos dot-products: relvals[r] = q . rel_table[r]
    for (int r = tid; r < RNUM; r += 128) {
        const float* rr = rel + r * HD;
        float a0 = 0.f, a1 = 0.f;
        for (int h = 0; h < HD; h++) { float rv = rr[h]; a0 += q0[h] * rv; a1 += q1[h] * rv; }
        r0[r] = a0; r1[r] = a1;
    }
    __syncthreads();
    float m0 = -1e30f, m1 = -1e30f;
    const float* kbase = kbuf + (size_t)b * SEQ * HD;
    const float4* q0v = (const float4*)q0;
    const float4* q1v = (const float4*)q1;
    for (int key = tid; key < SEQ; key += 128) {
        const float4* kr = (const float4*)(kbase + (size_t)key * HD);
        float a0 = 0.f, a1 = 0.f;
#pragma unroll
        for (int h4 = 0; h4 < HD / 4; h4++) {
            float4 kv = kr[h4];
            float4 qa = q0v[h4];
            float4 qc = q1v[h4];
            a0 += qa.x * kv.x + qa.y * kv.y + qa.z * kv.z + qa.w * kv.w;
            a1 += qc.x * kv.x + qc.y * kv.y + qc.z * kv.z + qc.w * kv.w;
        }
        int ri = key - qpos;
        ri = (ri < -MAXPOS ? -MAXPOS : (ri > MAXPOS ? MAXPOS : ri)) + MAXPOS;
        a0 += r0[ri]; a1 += r1[ri];
        s0[key] = a0; s1[key] = a1;
        m0 = fmaxf(m0, a0); m1 = fmaxf(m1, a1);
    }
#pragma unroll
    for (int off = 32; off; off >>= 1) {
        m0 = fmaxf(m0, __shfl_down(m0, off));
        m1 = fmaxf(m1, __shfl_down(m1, off));
    }
    int wave = tid >> 6, lane = tid & 63;
    if (lane == 0) { wred[0][wave] = m0; wred[1][wave] = m1; }
    __syncthreads();
    m0 = fmaxf(wred[0][0], wred[0][1]);
    m1 = fmaxf(wred[1][0], wred[1][1]);
    float sum0 = 0.f, sum1 = 0.f;
    for (int key = tid; key < SEQ; key += 128) {
        float e0 = __expf(s0[key] - m0);
        float e1 = __expf(s1[key] - m1);
        s0[key] = e0; s1[key] = e1;
        sum0 += e0; sum1 += e1;
    }
#pragma unroll
    for (int off = 32; off; off >>= 1) {
        sum0 += __shfl_down(sum0, off);
        sum1 += __shfl_down(sum1, off);
    }
    if (lane == 0) { wred[2][wave] = sum0; wred[3][wave] = sum1; }
    __syncthreads();
    float inv0 = 1.f / (wred[2][0] + wred[2][1]);
    float inv1 = 1.f / (wred[3][0] + wred[3][1]);
    // ctx accumulation: thread owns dim tid, coalesced V reads
    const float* vbase = vbuf + (size_t)b * SEQ * HD;
    float a0 = 0.f, a1 = 0.f;
    for (int key = 0; key < SEQ; key++) {
        float vv = vbase[(size_t)key * HD + tid];
        a0 += s0[key] * vv;
        a1 += s1[key] * vv;
    }
    ctx[((size_t)t * 2 + 0) * HD + tid] = a0 * inv0;
    ctx[((size_t)t * 2 + 1) * HD + tid] = a1 * inv1;
}

// ---------------- Gated output projection + residual: block (256 thr) per token ----------------
__global__ void oproj_kernel(const float* __restrict__ src, const float* __restrict__ ctx,
                             const float* __restrict__ ow, const float* __restrict__ ob,
                             const int* __restrict__ aidx, const float* __restrict__ aga,
                             float* __restrict__ x1) {
    int t = blockIdx.x;
    int tid = threadIdx.x;
    __shared__ float c0[HD], c1[HD];
    float g0 = aga[t * 2], g1 = aga[t * 2 + 1];
    int e0 = aidx[t * 2], e1 = aidx[t * 2 + 1];
    if (tid < 128) c0[tid] = ctx[((size_t)t * 2 + 0) * HD + tid] * g0;
    else c1[tid - 128] = ctx[((size_t)t * 2 + 1) * HD + (tid - 128)] * g1;
    __syncthreads();
    const float* w0 = ow + (size_t)e0 * HD * D;
    const float* w1 = ow + (size_t)e1 * HD * D;
    float acc[4] = {0.f, 0.f, 0.f, 0.f};
    for (int h = 0; h < HD; h++) {
        float ch0 = c0[h], ch1 = c1[h];
        const float* r0 = w0 + (size_t)h * D;
        const float* r1 = w1 + (size_t)h * D;
#pragma unroll
        for (int i = 0; i < 4; i++) {
            int d = tid + i * 256;
            acc[i] += ch0 * r0[d] + ch1 * r1[d];
        }
    }
#pragma unroll
    for (int i = 0; i < 4; i++) {
        int d = tid + i * 256;
        x1[(size_t)t * D + d] = src[(size_t)t * D + d] + acc[i]
                              + g0 * ob[e0 * D + d] + g1 * ob[e1 * D + d];
    }
}

// ---------------- MoE FFN + residual: block (256 thr) per token, both experts ----------------
__global__ void ffn_kernel(const float* __restrict__ x1, const float* __restrict__ xn2,
                           const float* __restrict__ w1, const float* __restrict__ b1,
                           const float* __restrict__ w2, const float* __restrict__ b2,
                           const int* __restrict__ fidx, const float* __restrict__ fga,
                           float* __restrict__ out) {
    int t = blockIdx.x;
    int tid = threadIdx.x;
    __shared__ float x[D];
    __shared__ float h[FH];
    for (int d = tid; d < D; d += 256) x[d] = xn2[(size_t)t * D + d];
    float acc[4] = {0.f, 0.f, 0.f, 0.f};
    for (int j = 0; j < 2; j++) {
        int e = fidx[t * 2 + j];
        float g = fga[t * 2 + j];
        const float* W1 = w1 + (size_t)e * D * FH;
        const float* W2 = w2 + (size_t)e * FH * D;
        __syncthreads();  // x ready (j=0) / previous h fully consumed (j=1)
        float a0 = b1[e * FH + tid], a1 = b1[e * FH + tid + 256];
        for (int d = 0; d < D; d++) {
            float xv = x[d];
            const float* row = W1 + (size_t)d * FH;
            a0 += xv * row[tid];
            a1 += xv * row[tid + 256];
        }
        h[tid] = fmaxf(a0, 0.f);
        h[tid + 256] = fmaxf(a1, 0.f);
        __syncthreads();
        float o0 = 0.f, o1 = 0.f, o2 = 0.f, o3 = 0.f;
        for (int f = 0; f < FH; f++) {
            float hv = h[f];
            const float* row = W2 + (size_t)f * D;
            o0 += hv * row[tid];
            o1 += hv * row[tid + 256];
            o2 += hv * row[tid + 512];
            o3 += hv * row[tid + 768];
        }
        acc[0] += g * (o0 + b2[e * D + tid]);
        acc[1] += g * (o1 + b2[e * D + tid + 256]);
        acc[2] += g * (o2 + b2[e * D + tid + 512]);
        acc[3] += g * (o3 + b2[e * D + tid + 768]);
    }
#pragma unroll
    for (int i = 0; i < 4; i++) {
        int d = tid + i * 256;
        out[(size_t)t * D + d] = x1[(size_t)t * D + d] + acc[i];
    }
}

extern "C" void kernel_launch(void* const* d_in, const int* in_sizes, int n_in,
                              void* d_out, int out_size, void* d_ws, size_t ws_size,
                              hipStream_t stream) {
    const float* src   = (const float*)d_in[0];
    const float* ln1_w = (const float*)d_in[1];
    const float* ln1_b = (const float*)d_in[2];
    const float* ln2_w = (const float*)d_in[3];
    const float* ln2_b = (const float*)d_in[4];
    const float* agw   = (const float*)d_in[5];
    const float* qw    = (const float*)d_in[6];
    const float* qb    = (const float*)d_in[7];
    const float* kw    = (const float*)d_in[8];
    const float* kb    = (const float*)d_in[9];
    const float* vw    = (const float*)d_in[10];
    const float* vb    = (const float*)d_in[11];
    const float* ow    = (const float*)d_in[12];
    const float* ob    = (const float*)d_in[13];
    const float* rel   = (const float*)d_in[14];
    const float* fgw   = (const float*)d_in[15];
    const float* w1    = (const float*)d_in[16];
    const float* b1    = (const float*)d_in[17];
    const float* w2    = (const float*)d_in[18];
    const float* b2    = (const float*)d_in[19];
    float* out = (float*)d_out;

    char* p = (char*)d_ws;
    float* xn1  = (float*)p; p += (size_t)NTOK * D * 4;       // reused as xn2
    float* x1   = (float*)p; p += (size_t)NTOK * D * 4;
    float* kbuf = (float*)p; p += (size_t)NTOK * HD * 4;
    float* vbuf = (float*)p; p += (size_t)NTOK * HD * 4;
    float* qbuf = (float*)p; p += (size_t)NTOK * 2 * HD * 4;
    float* cbuf = (float*)p; p += (size_t)NTOK * 2 * HD * 4;
    int*   aidx = (int*)p;   p += NTOK * 2 * 4;
    float* aga  = (float*)p; p += NTOK * 2 * 4;
    int*   fidx = (int*)p;   p += NTOK * 2 * 4;
    float* fga  = (float*)p; p += NTOK * 2 * 4;

    ln_kernel<<<NTOK, 256, 0, stream>>>(src, ln1_w, ln1_b, xn1);
    router_kernel<EA><<<NTOK, 64, 0, stream>>>(xn1, agw, aidx, aga);
    kv_kernel<<<NTOK, 128, 0, stream>>>(xn1, kw, kb, vw, vb, kbuf, vbuf);
    q_kernel<<<NTOK * 2, 128, 0, stream>>>(xn1, qw, qb, aidx, qbuf);
    attn_kernel<<<NTOK, 128, 0, stream>>>(qbuf, kbuf, vbuf, rel, cbuf);
    oproj_kernel<<<NTOK, 256, 0, stream>>>(src, cbuf, ow, ob, aidx, aga, x1);
    ln_kernel<<<NTOK, 256, 0, stream>>>(x1, ln2_w, ln2_b, xn1);
    router_kernel<EF><<<NTOK, 64, 0, stream>>>(xn1, fgw, fidx, fga);
    ffn_kernel<<<NTOK, 256, 0, stream>>>(x1, xn1, w1, b1, w2, b2, fidx, fga, out);
}

// Round 2
// 2153.998 us; speedup vs baseline: 2.4034x; 2.4034x over previous
//
#include <hip/hip_runtime.h>

#define D 1024
#define HD 128
#define EA 8
#define EF 16
#define FH 512
#define MAXPOS 64
#define RNUM 129
#define SEQ 1024
#define NTOK 4096
#define NPAIR (NTOK * 2)
#define LN_EPS 1e-5f

#define TM 64
#define TN 64
#define BK 16
#define LPAD 68   // LDS row stride (floats) for [BK][TM] tiles

// ---------------- LayerNorm: one block (256 thr) per row of 1024 ----------------
__global__ void ln_kernel(const float* __restrict__ x, const float* __restrict__ w,
                          const float* __restrict__ b, float* __restrict__ y) {
    int row = blockIdx.x;
    const float* xr = x + (size_t)row * D;
    float v[4];
    float s = 0.f, s2 = 0.f;
#pragma unroll
    for (int i = 0; i < 4; i++) {
        v[i] = xr[threadIdx.x + i * 256];
        s += v[i]; s2 += v[i] * v[i];
    }
#pragma unroll
    for (int off = 32; off; off >>= 1) { s += __shfl_down(s, off); s2 += __shfl_down(s2, off); }
    __shared__ float red0[4], red1[4];
    int wave = threadIdx.x >> 6, lane = threadIdx.x & 63;
    if (lane == 0) { red0[wave] = s; red1[wave] = s2; }
    __syncthreads();
    float ts = red0[0] + red0[1] + red0[2] + red0[3];
    float ts2 = red1[0] + red1[1] + red1[2] + red1[3];
    float mu = ts * (1.f / D);
    float var = ts2 * (1.f / D) - mu * mu;
    float inv = rsqrtf(var + LN_EPS);
#pragma unroll
    for (int i = 0; i < 4; i++) {
        int d = threadIdx.x + i * 256;
        y[(size_t)row * D + d] = (v[i] - mu) * inv * w[d] + b[d];
    }
}

// ---------------- Router: one wave per token, top-2 + softmax ----------------
template <int E>
__global__ void router_kernel(const float* __restrict__ xn, const float* __restrict__ gw,
                              int* __restrict__ idx, float* __restrict__ gate) {
    int t = blockIdx.x;
    int lane = threadIdx.x;  // block=64
    float acc[E];
#pragma unroll
    for (int e = 0; e < E; e++) acc[e] = 0.f;
    const float* xr = xn + (size_t)t * D;
    for (int d = lane; d < D; d += 64) {
        float xv = xr[d];
#pragma unroll
        for (int e = 0; e < E; e++) acc[e] += xv * gw[d * E + e];
    }
#pragma unroll
    for (int e = 0; e < E; e++) {
#pragma unroll
        for (int off = 32; off; off >>= 1) acc[e] += __shfl_down(acc[e], off);
    }
    if (lane == 0) {
        float v0 = -1e30f, v1 = -1e30f;
        int i0 = 0, i1 = 0;
#pragma unroll
        for (int e = 0; e < E; e++) {
            float a = acc[e];
            if (a > v0) { v1 = v0; i1 = i0; v0 = a; i0 = e; }
            else if (a > v1) { v1 = a; i1 = e; }
        }
        float g0 = 1.f / (1.f + expf(v1 - v0));  // softmax of [v0, v1]
        idx[t * 2] = i0; idx[t * 2 + 1] = i1;
        gate[t * 2] = g0; gate[t * 2 + 1] = 1.f - g0;
    }
}

// ---------------- Shared K/V projection: one block (128 thr) per token ----------------
__global__ void kv_kernel(const float* __restrict__ xn,
                          const float* __restrict__ kw, const float* __restrict__ kb,
                          const float* __restrict__ vw, const float* __restrict__ vb,
                          float* __restrict__ kbuf, float* __restrict__ vbuf) {
    int t = blockIdx.x;
    __shared__ float x[D];
    for (int d = threadIdx.x; d < D; d += 128) x[d] = xn[(size_t)t * D + d];
    __syncthreads();
    int h = threadIdx.x;
    float ak = kb[h], av = vb[h];
    for (int d = 0; d < D; d++) {
        float xv = x[d];
        ak += xv * kw[d * HD + h];
        av += xv * vw[d * HD + h];
    }
    kbuf[(size_t)t * HD + h] = ak;
    vbuf[(size_t)t * HD + h] = av;
}

// ---------------- Q projection for selected experts: block per (token, j) ----------------
__global__ void q_kernel(const float* __restrict__ xn, const float* __restrict__ qw,
                         const float* __restrict__ qb, const int* __restrict__ aidx,
                         float* __restrict__ qbuf) {
    int tj = blockIdx.x;
    int t = tj >> 1, j = tj & 1;
    int e = aidx[t * 2 + j];
    __shared__ float x[D];
    for (int d = threadIdx.x; d < D; d += 128) x[d] = xn[(size_t)t * D + d];
    __syncthreads();
    int h = threadIdx.x;
    const float* w = qw + (size_t)e * D * HD;
    float a = 0.f;
    for (int d = 0; d < D; d++) a += x[d] * w[d * HD + h];
    qbuf[(size_t)tj * HD + h] = (a + qb[e * HD + h]) * 0.08838834764831845f;  // HD^-0.5
}

// ---------------- Attention: block (128 thr) per token, both selected experts ----------------
__global__ void attn_kernel(const float* __restrict__ qbuf, const float* __restrict__ kbuf,
                            const float* __restrict__ vbuf, const float* __restrict__ rel,
                            float* __restrict__ ctx) {
    int t = blockIdx.x;
    int b = t / SEQ;
    int qpos = t % SEQ;
    int tid = threadIdx.x;
    __shared__ float q0[HD], q1[HD];
    __shared__ float r0[RNUM + 3], r1[RNUM + 3];
    __shared__ float s0[SEQ], s1[SEQ];
    __shared__ float wred[4][2];
    q0[tid] = qbuf[((size_t)t * 2 + 0) * HD + tid];
    q1[tid] = qbuf[((size_t)t * 2 + 1) * HD + tid];
    __syncthreads();
    for (int r = tid; r < RNUM; r += 128) {
        const float* rr = rel + r * HD;
        float a0 = 0.f, a1 = 0.f;
        for (int h = 0; h < HD; h++) { float rv = rr[h]; a0 += q0[h] * rv; a1 += q1[h] * rv; }
        r0[r] = a0; r1[r] = a1;
    }
    __syncthreads();
    float m0 = -1e30f, m1 = -1e30f;
    const float* kbase = kbuf + (size_t)b * SEQ * HD;
    const float4* q0v = (const float4*)q0;
    const float4* q1v = (const float4*)q1;
    for (int key = tid; key < SEQ; key += 128) {
        const float4* kr = (const float4*)(kbase + (size_t)key * HD);
        float a0 = 0.f, a1 = 0.f;
#pragma unroll
        for (int h4 = 0; h4 < HD / 4; h4++) {
            float4 kv = kr[h4];
            float4 qa = q0v[h4];
            float4 qc = q1v[h4];
            a0 += qa.x * kv.x + qa.y * kv.y + qa.z * kv.z + qa.w * kv.w;
            a1 += qc.x * kv.x + qc.y * kv.y + qc.z * kv.z + qc.w * kv.w;
        }
        int ri = key - qpos;
        ri = (ri < -MAXPOS ? -MAXPOS : (ri > MAXPOS ? MAXPOS : ri)) + MAXPOS;
        a0 += r0[ri]; a1 += r1[ri];
        s0[key] = a0; s1[key] = a1;
        m0 = fmaxf(m0, a0); m1 = fmaxf(m1, a1);
    }
#pragma unroll
    for (int off = 32; off; off >>= 1) {
        m0 = fmaxf(m0, __shfl_down(m0, off));
        m1 = fmaxf(m1, __shfl_down(m1, off));
    }
    int wave = tid >> 6, lane = tid & 63;
    if (lane == 0) { wred[0][wave] = m0; wred[1][wave] = m1; }
    __syncthreads();
    m0 = fmaxf(wred[0][0], wred[0][1]);
    m1 = fmaxf(wred[1][0], wred[1][1]);
    float sum0 = 0.f, sum1 = 0.f;
    for (int key = tid; key < SEQ; key += 128) {
        float e0 = __expf(s0[key] - m0);
        float e1 = __expf(s1[key] - m1);
        s0[key] = e0; s1[key] = e1;
        sum0 += e0; sum1 += e1;
    }
#pragma unroll
    for (int off = 32; off; off >>= 1) {
        sum0 += __shfl_down(sum0, off);
        sum1 += __shfl_down(sum1, off);
    }
    if (lane == 0) { wred[2][wave] = sum0; wred[3][wave] = sum1; }
    __syncthreads();
    float inv0 = 1.f / (wred[2][0] + wred[2][1]);
    float inv1 = 1.f / (wred[3][0] + wred[3][1]);
    const float* vbase = vbuf + (size_t)b * SEQ * HD;
    float a0 = 0.f, a1 = 0.f;
    for (int key = 0; key < SEQ; key++) {
        float vv = vbase[(size_t)key * HD + tid];
        a0 += s0[key] * vv;
        a1 += s1[key] * vv;
    }
    ctx[((size_t)t * 2 + 0) * HD + tid] = a0 * inv0;
    ctx[((size_t)t * 2 + 1) * HD + tid] = a1 * inv1;
}

// ---------------- Gated output projection + residual ----------------
__global__ void oproj_kernel(const float* __restrict__ src, const float* __restrict__ ctx,
                             const float* __restrict__ ow, const float* __restrict__ ob,
                             const int* __restrict__ aidx, const float* __restrict__ aga,
                             float* __restrict__ x1) {
    int t = blockIdx.x;
    int tid = threadIdx.x;
    __shared__ float c0[HD], c1[HD];
    float g0 = aga[t * 2], g1 = aga[t * 2 + 1];
    int e0 = aidx[t * 2], e1 = aidx[t * 2 + 1];
    if (tid < 128) c0[tid] = ctx[((size_t)t * 2 + 0) * HD + tid] * g0;
    else c1[tid - 128] = ctx[((size_t)t * 2 + 1) * HD + (tid - 128)] * g1;
    __syncthreads();
    const float* w0 = ow + (size_t)e0 * HD * D;
    const float* w1 = ow + (size_t)e1 * HD * D;
    float acc[4] = {0.f, 0.f, 0.f, 0.f};
    for (int h = 0; h < HD; h++) {
        float ch0 = c0[h], ch1 = c1[h];
        const float* r0 = w0 + (size_t)h * D;
        const float* r1 = w1 + (size_t)h * D;
#pragma unroll
        for (int i = 0; i < 4; i++) {
            int d = tid + i * 256;
            acc[i] += ch0 * r0[d] + ch1 * r1[d];
        }
    }
#pragma unroll
    for (int i = 0; i < 4; i++) {
        int d = tid + i * 256;
        x1[(size_t)t * D + d] = src[(size_t)t * D + d] + acc[i]
                              + g0 * ob[e0 * D + d] + g1 * ob[e1 * D + d];
    }
}

// ---------------- FFN expert binning ----------------
// meta layout: [0..15]=counts, [16..31]=offsets, [32..47]=cursor
__global__ void bin_zero(int* __restrict__ meta) {
    if (threadIdx.x < 48) meta[threadIdx.x] = 0;
}
__global__ void bin_count(const int* __restrict__ fidx, int* __restrict__ meta) {
    int i = blockIdx.x * 256 + threadIdx.x;
    if (i < NPAIR) atomicAdd(&meta[fidx[i]], 1);
}
__global__ void bin_scan(int* __restrict__ meta) {
    if (threadIdx.x == 0 && blockIdx.x == 0) {
        int s = 0;
        for (int e = 0; e < EF; e++) { meta[16 + e] = s; meta[32 + e] = s; s += meta[e]; }
    }
}
__global__ void bin_scatter(const int* __restrict__ fidx, int* __restrict__ meta,
                            int* __restrict__ list) {
    int i = blockIdx.x * 256 + threadIdx.x;
    if (i < NPAIR) {
        int e = fidx[i];
        int pos = atomicAdd(&meta[32 + e], 1);
        list[pos] = i;
    }
}
// gather xn2 rows into bin order: Xg[pos] = xn2[token(list[pos])]
__global__ void gather_kernel(const int* __restrict__ list, const float* __restrict__ xn,
                              float* __restrict__ Xg) {
    int pos = blockIdx.x;
    int t = list[pos] >> 1;
    const float4* s = (const float4*)(xn + (size_t)t * D);
    float4* d = (float4*)(Xg + (size_t)pos * D);
    d[threadIdx.x] = s[threadIdx.x];
}

// out = x1 + g0*b2[e0] + g1*b2[e1]  (FFN contributions atomically added later)
__global__ void out_init_kernel(const float* __restrict__ x1, const float* __restrict__ b2,
                                const int* __restrict__ fidx, const float* __restrict__ fga,
                                float* __restrict__ out) {
    int t = blockIdx.x;
    int tid = threadIdx.x;
    int e0 = fidx[t * 2], e1 = fidx[t * 2 + 1];
    float g0 = fga[t * 2], g1 = fga[t * 2 + 1];
#pragma unroll
    for (int i = 0; i < 4; i++) {
        int d = tid + i * 256;
        out[(size_t)t * D + d] = x1[(size_t)t * D + d]
                               + g0 * b2[e0 * D + d] + g1 * b2[e1 * D + d];
    }
}

// ---------------- FFN GEMM1: H[pos] = g * relu(Xg[pos] @ W1[e] + b1[e]) ----------------
__global__ __launch_bounds__(256) void ffn_gemm1(
    const float* __restrict__ Xg, const float* __restrict__ w1, const float* __restrict__ b1,
    const int* __restrict__ meta, const int* __restrict__ list,
    const float* __restrict__ fga, float* __restrict__ H) {
    int e = blockIdx.z;
    int o = meta[16 + e], c = meta[e];
    int m0 = blockIdx.x * TM;
    if (m0 >= c) return;
    int n0 = blockIdx.y * TN;
    const float* W = w1 + (size_t)e * D * FH;
    __shared__ float Xs[BK][LPAD];
    __shared__ float Ws[BK][LPAD];
    int tid = threadIdx.x;
    int lm = tid >> 2;                 // 0..63: X tile row
    int lk = (tid & 3) * 4;            // k offset
    int wk = tid >> 4;                 // 0..15: W tile k-row
    int wf = (tid & 15) * 4;           // f offset
    int ty = tid >> 4, tx = tid & 15;
    float acc[4][4] = {};
    for (int k0 = 0; k0 < D; k0 += BK) {
        float4 xv = *(const float4*)(Xg + (size_t)(o + m0 + lm) * D + k0 + lk);
        float4 wv = *(const float4*)(W + (size_t)(k0 + wk) * FH + n0 + wf);
        __syncthreads();
        Xs[lk + 0][lm] = xv.x; Xs[lk + 1][lm] = xv.y;
        Xs[lk + 2][lm] = xv.z; Xs[lk + 3][lm] = xv.w;
        *(float4*)&Ws[wk][wf] = wv;
        __syncthreads();
#pragma unroll
        for (int k = 0; k < BK; k++) {
            float4 a = *(const float4*)&Xs[k][ty * 4];
            float4 b = *(const float4*)&Ws[k][tx * 4];
            acc[0][0] += a.x * b.x; acc[0][1] += a.x * b.y; acc[0][2] += a.x * b.z; acc[0][3] += a.x * b.w;
            acc[1][0] += a.y * b.x; acc[1][1] += a.y * b.y; acc[1][2] += a.y * b.z; acc[1][3] += a.y * b.w;
            acc[2][0] += a.z * b.x; acc[2][1] += a.z * b.y; acc[2][2] += a.z * b.z; acc[2][3] += a.z * b.w;
            acc[3][0] += a.w * b.x; acc[3][1] += a.w * b.y; acc[3][2] += a.w * b.z; acc[3][3] += a.w * b.w;
        }
    }
    int n = n0 + tx * 4;
    float4 bb = *(const float4*)(b1 + e * FH + n);
#pragma unroll
    for (int i = 0; i < 4; i++) {
        int pos = o + m0 + ty * 4 + i;
        if (pos < o + c) {
            float g = fga[list[pos]];
            float4 hv;
            hv.x = g * fmaxf(acc[i][0] + bb.x, 0.f);
            hv.y = g * fmaxf(acc[i][1] + bb.y, 0.f);
            hv.z = g * fmaxf(acc[i][2] + bb.z, 0.f);
            hv.w = g * fmaxf(acc[i][3] + bb.w, 0.f);
            *(float4*)(H + (size_t)pos * FH + n) = hv;
        }
    }
}

// ---------------- FFN GEMM2: out[token] += H[pos] @ W2[e]  (atomic scatter) ----------------
__global__ __launch_bounds__(256) void ffn_gemm2(
    const float* __restrict__ H, const float* __restrict__ w2,
    const int* __restrict__ meta, const int* __restrict__ list,
    float* __restrict__ out) {
    int e = blockIdx.z;
    int o = meta[16 + e], c = meta[e];
    int m0 = blockIdx.x * TM;
    if (m0 >= c) return;
    int n0 = blockIdx.y * TN;
    const float* W = w2 + (size_t)e * FH * D;
    __shared__ float Hs[BK][LPAD];
    __shared__ float Ws[BK][LPAD];
    int tid = threadIdx.x;
    int lm = tid >> 2;
    int lk = (tid & 3) * 4;
    int wk = tid >> 4;
    int wf = (tid & 15) * 4;
    int ty = tid >> 4, tx = tid & 15;
    float acc[4][4] = {};
    for (int k0 = 0; k0 < FH; k0 += BK) {
        float4 xv = *(const float4*)(H + (size_t)(o + m0 + lm) * FH + k0 + lk);
        float4 wv = *(const float4*)(W + (size_t)(k0 + wk) * D + n0 + wf);
        __syncthreads();
        Hs[lk + 0][lm] = xv.x; Hs[lk + 1][lm] = xv.y;
        Hs[lk + 2][lm] = xv.z; Hs[lk + 3][lm] = xv.w;
        *(float4*)&Ws[wk][wf] = wv;
        __syncthreads();
#pragma unroll
        for (int k = 0; k < BK; k++) {
            float4 a = *(const float4*)&Hs[k][ty * 4];
            float4 b = *(const float4*)&Ws[k][tx * 4];
            acc[0][0] += a.x * b.x; acc[0][1] += a.x * b.y; acc[0][2] += a.x * b.z; acc[0][3] += a.x * b.w;
            acc[1][0] += a.y * b.x; acc[1][1] += a.y * b.y; acc[1][2] += a.y * b.z; acc[1][3] += a.y * b.w;
            acc[2][0] += a.z * b.x; acc[2][1] += a.z * b.y; acc[2][2] += a.z * b.z; acc[2][3] += a.z * b.w;
            acc[3][0] += a.w * b.x; acc[3][1] += a.w * b.y; acc[3][2] += a.w * b.z; acc[3][3] += a.w * b.w;
        }
    }
    int n = n0 + tx * 4;
#pragma unroll
    for (int i = 0; i < 4; i++) {
        int pos = o + m0 + ty * 4 + i;
        if (pos < o + c) {
            int t = list[pos] >> 1;
            float* op = out + (size_t)t * D + n;
            atomicAdd(op + 0, acc[i][0]);
            atomicAdd(op + 1, acc[i][1]);
            atomicAdd(op + 2, acc[i][2]);
            atomicAdd(op + 3, acc[i][3]);
        }
    }
}

extern "C" void kernel_launch(void* const* d_in, const int* in_sizes, int n_in,
                              void* d_out, int out_size, void* d_ws, size_t ws_size,
                              hipStream_t stream) {
    const float* src   = (const float*)d_in[0];
    const float* ln1_w = (const float*)d_in[1];
    const float* ln1_b = (const float*)d_in[2];
    const float* ln2_w = (const float*)d_in[3];
    const float* ln2_b = (const float*)d_in[4];
    const float* agw   = (const float*)d_in[5];
    const float* qw    = (const float*)d_in[6];
    const float* qb    = (const float*)d_in[7];
    const float* kw    = (const float*)d_in[8];
    const float* kb    = (const float*)d_in[9];
    const float* vw    = (const float*)d_in[10];
    const float* vb    = (const float*)d_in[11];
    const float* ow    = (const float*)d_in[12];
    const float* ob    = (const float*)d_in[13];
    const float* rel   = (const float*)d_in[14];
    const float* fgw   = (const float*)d_in[15];
    const float* w1    = (const float*)d_in[16];
    const float* b1    = (const float*)d_in[17];
    const float* w2    = (const float*)d_in[18];
    const float* b2    = (const float*)d_in[19];
    float* out = (float*)d_out;

    char* p = (char*)d_ws;
    float* xn1  = (float*)p; p += (size_t)NTOK * D * 4;        // xn (reused for ln2)
    float* x1   = (float*)p; p += (size_t)NTOK * D * 4;
    float* Xg   = (float*)p; p += (size_t)(NPAIR + 64) * D * 4;   // gathered rows (+slack)
    float* Hbuf = (float*)p; p += (size_t)(NPAIR + 64) * FH * 4;  // hidden (+slack)
    float* kbuf = (float*)p; p += (size_t)NTOK * HD * 4;
    float* vbuf = (float*)p; p += (size_t)NTOK * HD * 4;
    float* qbuf = (float*)p; p += (size_t)NPAIR * HD * 4;
    float* cbuf = (float*)p; p += (size_t)NPAIR * HD * 4;
    int*   aidx = (int*)p;   p += NPAIR * 4;
    float* aga  = (float*)p; p += NPAIR * 4;
    int*   fidx = (int*)p;   p += NPAIR * 4;
    float* fga  = (float*)p; p += NPAIR * 4;
    int*   meta = (int*)p;   p += 64 * 4;    // counts/off/cursor
    int*   list = (int*)p;   p += NPAIR * 4;

    // ---- attention block ----
    ln_kernel<<<NTOK, 256, 0, stream>>>(src, ln1_w, ln1_b, xn1);
    router_kernel<EA><<<NTOK, 64, 0, stream>>>(xn1, agw, aidx, aga);
    kv_kernel<<<NTOK, 128, 0, stream>>>(xn1, kw, kb, vw, vb, kbuf, vbuf);
    q_kernel<<<NPAIR, 128, 0, stream>>>(xn1, qw, qb, aidx, qbuf);
    attn_kernel<<<NTOK, 128, 0, stream>>>(qbuf, kbuf, vbuf, rel, cbuf);
    oproj_kernel<<<NTOK, 256, 0, stream>>>(src, cbuf, ow, ob, aidx, aga, x1);

    // ---- FFN block (expert-binned GEMMs) ----
    ln_kernel<<<NTOK, 256, 0, stream>>>(x1, ln2_w, ln2_b, xn1);
    router_kernel<EF><<<NTOK, 64, 0, stream>>>(xn1, fgw, fidx, fga);
    bin_zero<<<1, 64, 0, stream>>>(meta);
    bin_count<<<NPAIR / 256, 256, 0, stream>>>(fidx, meta);
    bin_scan<<<1, 64, 0, stream>>>(meta);
    bin_scatter<<<NPAIR / 256, 256, 0, stream>>>(fidx, meta, list);
    gather_kernel<<<NPAIR, 256, 0, stream>>>(list, xn1, Xg);
    out_init_kernel<<<NTOK, 256, 0, stream>>>(x1, b2, fidx, fga, out);
    {
        dim3 g1(NPAIR / TM, FH / TN, EF);
        ffn_gemm1<<<g1, 256, 0, stream>>>(Xg, w1, b1, meta, list, fga, Hbuf);
        dim3 g2(NPAIR / TM, D / TN, EF);
        ffn_gemm2<<<g2, 256, 0, stream>>>(Hbuf, w2, meta, list, out);
    }
}

// Round 3
// 1730.976 us; speedup vs baseline: 2.9907x; 1.2444x over previous
//
#include <hip/hip_runtime.h>

#define D 1024
#define HD 128
#define EA 8
#define EF 16
#define FH 512
#define MAXPOS 64
#define RNUM 129
#define RSTRIDE 132
#define SEQ 1024
#define NTOK 4096
#define NPAIR (NTOK * 2)
#define LN_EPS 1e-5f
#define QSCALE 0.08838834764831845f

#define TM 64
#define TN 64
#define BK 16
#define LPAD 68   // LDS row stride (floats)

// ---------------- LayerNorm ----------------
__global__ void ln_kernel(const float* __restrict__ x, const float* __restrict__ w,
                          const float* __restrict__ b, float* __restrict__ y) {
    int row = blockIdx.x;
    const float* xr = x + (size_t)row * D;
    float v[4];
    float s = 0.f, s2 = 0.f;
#pragma unroll
    for (int i = 0; i < 4; i++) {
        v[i] = xr[threadIdx.x + i * 256];
        s += v[i]; s2 += v[i] * v[i];
    }
#pragma unroll
    for (int off = 32; off; off >>= 1) { s += __shfl_down(s, off); s2 += __shfl_down(s2, off); }
    __shared__ float red0[4], red1[4];
    int wave = threadIdx.x >> 6, lane = threadIdx.x & 63;
    if (lane == 0) { red0[wave] = s; red1[wave] = s2; }
    __syncthreads();
    float ts = red0[0] + red0[1] + red0[2] + red0[3];
    float ts2 = red1[0] + red1[1] + red1[2] + red1[3];
    float mu = ts * (1.f / D);
    float var = ts2 * (1.f / D) - mu * mu;
    float inv = rsqrtf(var + LN_EPS);
#pragma unroll
    for (int i = 0; i < 4; i++) {
        int d = threadIdx.x + i * 256;
        y[(size_t)row * D + d] = (v[i] - mu) * inv * w[d] + b[d];
    }
}

// ---------------- Router: one wave per token, top-2 + softmax ----------------
template <int E>
__global__ void router_kernel(const float* __restrict__ xn, const float* __restrict__ gw,
                              int* __restrict__ idx, float* __restrict__ gate) {
    int t = blockIdx.x;
    int lane = threadIdx.x;  // block=64
    float acc[E];
#pragma unroll
    for (int e = 0; e < E; e++) acc[e] = 0.f;
    const float* xr = xn + (size_t)t * D;
    for (int d = lane; d < D; d += 64) {
        float xv = xr[d];
#pragma unroll
        for (int e = 0; e < E; e++) acc[e] += xv * gw[d * E + e];
    }
#pragma unroll
    for (int e = 0; e < E; e++) {
#pragma unroll
        for (int off = 32; off; off >>= 1) acc[e] += __shfl_down(acc[e], off);
    }
    if (lane == 0) {
        float v0 = -1e30f, v1 = -1e30f;
        int i0 = 0, i1 = 0;
#pragma unroll
        for (int e = 0; e < E; e++) {
            float a = acc[e];
            if (a > v0) { v1 = v0; i1 = i0; v0 = a; i0 = e; }
            else if (a > v1) { v1 = a; i1 = e; }
        }
        float g0 = 1.f / (1.f + expf(v1 - v0));
        idx[t * 2] = i0; idx[t * 2 + 1] = i1;
        gate[t * 2] = g0; gate[t * 2 + 1] = 1.f - g0;
    }
}

// ---------------- Attention binning: 32 bins keyed (expert*4 + batch) ----------------
// meta_a layout: [0,32)=counts, [32,64)=offsets, [64,96)=cursor, [96,105)=expert offsets
__global__ void abin_zero(int* __restrict__ meta) {
    if (threadIdx.x < 105) meta[threadIdx.x] = 0;
}
__global__ void abin_count(const int* __restrict__ aidx, int* __restrict__ meta) {
    int i = blockIdx.x * 256 + threadIdx.x;
    if (i < NPAIR) {
        int e = aidx[i];
        int b = (i >> 1) >> 10;      // token / SEQ
        atomicAdd(&meta[e * 4 + b], 1);
    }
}
__global__ void abin_scan(int* __restrict__ meta) {
    if (threadIdx.x == 0 && blockIdx.x == 0) {
        int s = 0;
        for (int bin = 0; bin < 32; bin++) {
            if ((bin & 3) == 0) meta[96 + (bin >> 2)] = s;
            meta[32 + bin] = s; meta[64 + bin] = s; s += meta[bin];
        }
        meta[96 + 8] = s;  // == NPAIR
    }
}
__global__ void abin_scatter(const int* __restrict__ aidx, int* __restrict__ meta,
                             int* __restrict__ list) {
    int i = blockIdx.x * 256 + threadIdx.x;
    if (i < NPAIR) {
        int e = aidx[i];
        int b = (i >> 1) >> 10;
        int pos = atomicAdd(&meta[64 + e * 4 + b], 1);
        list[pos] = i;
    }
}

// ---------------- K/V projection GEMM: [4096x1024]@[1024x128], z=0:K z=1:V ----------------
__global__ __launch_bounds__(256) void kv_gemm(
    const float* __restrict__ xn,
    const float* __restrict__ kw, const float* __restrict__ kb,
    const float* __restrict__ vw, const float* __restrict__ vb,
    float* __restrict__ kbuf, float* __restrict__ vbuf) {
    const float* W = blockIdx.z ? vw : kw;
    const float* bias = blockIdx.z ? vb : kb;
    float* outp = blockIdx.z ? vbuf : kbuf;
    int m0 = blockIdx.x * TM;
    int n0 = blockIdx.y * TN;
    __shared__ float Xs[BK][LPAD];
    __shared__ float Ws[BK][LPAD];
    int tid = threadIdx.x;
    int lm = tid >> 2, lk = (tid & 3) * 4;
    int wk = tid >> 4, wf = (tid & 15) * 4;
    int ty = tid >> 4, tx = tid & 15;
    float acc[4][4] = {};
    const float* arow = xn + (size_t)(m0 + lm) * D;
    for (int k0 = 0; k0 < D; k0 += BK) {
        float4 xv = *(const float4*)(arow + k0 + lk);
        float4 wv = *(const float4*)(W + (size_t)(k0 + wk) * HD + n0 + wf);
        __syncthreads();
        Xs[lk + 0][lm] = xv.x; Xs[lk + 1][lm] = xv.y;
        Xs[lk + 2][lm] = xv.z; Xs[lk + 3][lm] = xv.w;
        *(float4*)&Ws[wk][wf] = wv;
        __syncthreads();
#pragma unroll
        for (int k = 0; k < BK; k++) {
            float4 a = *(const float4*)&Xs[k][ty * 4];
            float4 b = *(const float4*)&Ws[k][tx * 4];
            acc[0][0] += a.x * b.x; acc[0][1] += a.x * b.y; acc[0][2] += a.x * b.z; acc[0][3] += a.x * b.w;
            acc[1][0] += a.y * b.x; acc[1][1] += a.y * b.y; acc[1][2] += a.y * b.z; acc[1][3] += a.y * b.w;
            acc[2][0] += a.z * b.x; acc[2][1] += a.z * b.y; acc[2][2] += a.z * b.z; acc[2][3] += a.z * b.w;
            acc[3][0] += a.w * b.x; acc[3][1] += a.w * b.y; acc[3][2] += a.w * b.z; acc[3][3] += a.w * b.w;
        }
    }
    int n = n0 + tx * 4;
    float4 bb = *(const float4*)(bias + n);
#pragma unroll
    for (int i = 0; i < 4; i++) {
        int m = m0 + ty * 4 + i;
        float4 ov = { acc[i][0] + bb.x, acc[i][1] + bb.y, acc[i][2] + bb.z, acc[i][3] + bb.w };
        *(float4*)(outp + (size_t)m * HD + n) = ov;
    }
}

// ---------------- Q projection GEMM (binned by expert, indirect A rows) ----------------
__global__ __launch_bounds__(256) void q_gemm(
    const float* __restrict__ xn, const float* __restrict__ qw, const float* __restrict__ qb,
    const int* __restrict__ meta, const int* __restrict__ list, float* __restrict__ Qg) {
    int e = blockIdx.z;
    int o = meta[96 + e], c = meta[97 + e] - o;
    int m0 = blockIdx.x * TM;
    if (m0 >= c) return;
    int n0 = blockIdx.y * TN;
    const float* W = qw + (size_t)e * D * HD;
    __shared__ float Xs[BK][LPAD];
    __shared__ float Ws[BK][LPAD];
    int tid = threadIdx.x;
    int lm = tid >> 2, lk = (tid & 3) * 4;
    int wk = tid >> 4, wf = (tid & 15) * 4;
    int ty = tid >> 4, tx = tid & 15;
    int ridx = o + m0 + lm; if (ridx > NPAIR - 1) ridx = NPAIR - 1;
    const float* arow = xn + (size_t)(list[ridx] >> 1) * D;
    float acc[4][4] = {};
    for (int k0 = 0; k0 < D; k0 += BK) {
        float4 xv = *(const float4*)(arow + k0 + lk);
        float4 wv = *(const float4*)(W + (size_t)(k0 + wk) * HD + n0 + wf);
        __syncthreads();
        Xs[lk + 0][lm] = xv.x; Xs[lk + 1][lm] = xv.y;
        Xs[lk + 2][lm] = xv.z; Xs[lk + 3][lm] = xv.w;
        *(float4*)&Ws[wk][wf] = wv;
        __syncthreads();
#pragma unroll
        for (int k = 0; k < BK; k++) {
            float4 a = *(const float4*)&Xs[k][ty * 4];
            float4 b = *(const float4*)&Ws[k][tx * 4];
            acc[0][0] += a.x * b.x; acc[0][1] += a.x * b.y; acc[0][2] += a.x * b.z; acc[0][3] += a.x * b.w;
            acc[1][0] += a.y * b.x; acc[1][1] += a.y * b.y; acc[1][2] += a.y * b.z; acc[1][3] += a.y * b.w;
            acc[2][0] += a.z * b.x; acc[2][1] += a.z * b.y; acc[2][2] += a.z * b.z; acc[2][3] += a.z * b.w;
            acc[3][0] += a.w * b.x; acc[3][1] += a.w * b.y; acc[3][2] += a.w * b.z; acc[3][3] += a.w * b.w;
        }
    }
    int n = n0 + tx * 4;
    float4 bb = *(const float4*)(qb + e * HD + n);
#pragma unroll
    for (int i = 0; i < 4; i++) {
        int pos = o + m0 + ty * 4 + i;
        if (pos < o + c) {
            float4 ov = { (acc[i][0] + bb.x) * QSCALE, (acc[i][1] + bb.y) * QSCALE,
                          (acc[i][2] + bb.z) * QSCALE, (acc[i][3] + bb.w) * QSCALE };
            *(float4*)(Qg + (size_t)pos * HD + n) = ov;
        }
    }
}

// ---------------- Rel-pos table dots: R[pos][r] = Qg[pos] . rel[r] ----------------
__global__ void rel_kernel(const float* __restrict__ Qg, const float* __restrict__ rel,
                           float* __restrict__ R) {
    int pos = blockIdx.x;
    __shared__ float q[HD];
    if (threadIdx.x < 32) ((float4*)q)[threadIdx.x] = ((const float4*)(Qg + (size_t)pos * HD))[threadIdx.x];
    __syncthreads();
    int r = threadIdx.x;
    if (r < RNUM) {
        const float4* rr = (const float4*)(rel + r * HD);
        const float4* qv = (const float4*)q;
        float a = 0.f;
#pragma unroll
        for (int h4 = 0; h4 < HD / 4; h4++) {
            float4 rv = rr[h4], qa = qv[h4];
            a += qa.x * rv.x + qa.y * rv.y + qa.z * rv.z + qa.w * rv.w;
        }
        R[(size_t)pos * RSTRIDE + r] = a;
    }
}

// ---------------- Score GEMM: S[pos][key] = Qg[pos] . K[b][key] + relbias ----------------
__global__ __launch_bounds__(256) void s_gemm(
    const float* __restrict__ Qg, const float* __restrict__ kbuf,
    const float* __restrict__ R, const int* __restrict__ meta,
    const int* __restrict__ list, float* __restrict__ S) {
    int bin = blockIdx.z;
    int o = meta[32 + bin], c = meta[bin];
    int m0 = blockIdx.x * TM;
    if (m0 >= c) return;
    int b = bin & 3;
    int n0 = blockIdx.y * TN;
    const float* kb = kbuf + (size_t)b * SEQ * HD;
    __shared__ float Xs[BK][LPAD];
    __shared__ float Ws[BK][LPAD];
    int tid = threadIdx.x;
    int lm = tid >> 2, lk = (tid & 3) * 4;
    int tn = tid & 63, tkq = tid >> 6;     // B-transpose staging
    int ty = tid >> 4, tx = tid & 15;
    const float* arow = Qg + (size_t)(o + m0 + lm) * HD;   // slack rows exist
    float acc[4][4] = {};
    for (int k0 = 0; k0 < HD; k0 += BK) {
        float4 xv = *(const float4*)(arow + k0 + lk);
        float4 kv = *(const float4*)(kb + (size_t)(n0 + tn) * HD + k0 + tkq * 4);
        __syncthreads();
        Xs[lk + 0][lm] = xv.x; Xs[lk + 1][lm] = xv.y;
        Xs[lk + 2][lm] = xv.z; Xs[lk + 3][lm] = xv.w;
        Ws[tkq * 4 + 0][tn] = kv.x; Ws[tkq * 4 + 1][tn] = kv.y;
        Ws[tkq * 4 + 2][tn] = kv.z; Ws[tkq * 4 + 3][tn] = kv.w;
        __syncthreads();
#pragma unroll
        for (int k = 0; k < BK; k++) {
            float4 a = *(const float4*)&Xs[k][ty * 4];
            float4 b2 = *(const float4*)&Ws[k][tx * 4];
            acc[0][0] += a.x * b2.x; acc[0][1] += a.x * b2.y; acc[0][2] += a.x * b2.z; acc[0][3] += a.x * b2.w;
            acc[1][0] += a.y * b2.x; acc[1][1] += a.y * b2.y; acc[1][2] += a.y * b2.z; acc[1][3] += a.y * b2.w;
            acc[2][0] += a.z * b2.x; acc[2][1] += a.z * b2.y; acc[2][2] += a.z * b2.z; acc[2][3] += a.z * b2.w;
            acc[3][0] += a.w * b2.x; acc[3][1] += a.w * b2.y; acc[3][2] += a.w * b2.z; acc[3][3] += a.w * b2.w;
        }
    }
#pragma unroll
    for (int i = 0; i < 4; i++) {
        int pos = o + m0 + ty * 4 + i;
        if (pos < o + c) {
            int qpos = (list[pos] >> 1) & (SEQ - 1);
            const float* Rrow = R + (size_t)pos * RSTRIDE;
            float* srow = S + (size_t)pos * SEQ;
#pragma unroll
            for (int j = 0; j < 4; j++) {
                int key = n0 + tx * 4 + j;
                int ri = key - qpos;
                ri = (ri < -MAXPOS ? -MAXPOS : (ri > MAXPOS ? MAXPOS : ri)) + MAXPOS;
                srow[key] = acc[i][j] + Rrow[ri];
            }
        }
    }
}

// ---------------- Row softmax in place over S[8192][1024] ----------------
__global__ __launch_bounds__(256) void softmax_kernel(float* __restrict__ S) {
    int row = blockIdx.x;
    float4* sr = (float4*)(S + (size_t)row * SEQ);
    float4 v = sr[threadIdx.x];
    float m = fmaxf(fmaxf(v.x, v.y), fmaxf(v.z, v.w));
#pragma unroll
    for (int off = 32; off; off >>= 1) m = fmaxf(m, __shfl_down(m, off));
    __shared__ float red0[4], red1[4];
    int wave = threadIdx.x >> 6, lane = threadIdx.x & 63;
    if (lane == 0) red0[wave] = m;
    __syncthreads();
    m = fmaxf(fmaxf(red0[0], red0[1]), fmaxf(red0[2], red0[3]));
    v.x = __expf(v.x - m); v.y = __expf(v.y - m);
    v.z = __expf(v.z - m); v.w = __expf(v.w - m);
    float s = v.x + v.y + v.z + v.w;
#pragma unroll
    for (int off = 32; off; off >>= 1) s += __shfl_down(s, off);
    if (lane == 0) red1[wave] = s;
    __syncthreads();
    float inv = 1.f / (red1[0] + red1[1] + red1[2] + red1[3]);
    v.x *= inv; v.y *= inv; v.z *= inv; v.w *= inv;
    sr[threadIdx.x] = v;
}

// ---------------- PV GEMM: ctxg[pos] = gate * (P[pos] @ V[b]) ----------------
__global__ __launch_bounds__(256) void pv_gemm(
    const float* __restrict__ S, const float* __restrict__ vbuf,
    const int* __restrict__ meta, const int* __restrict__ list,
    const float* __restrict__ aga, float* __restrict__ ctxg) {
    int bin = blockIdx.z;
    int o = meta[32 + bin], c = meta[bin];
    int m0 = blockIdx.x * TM;
    if (m0 >= c) return;
    int b = bin & 3;
    int n0 = blockIdx.y * TN;
    const float* V = vbuf + (size_t)b * SEQ * HD;
    __shared__ float Xs[BK][LPAD];
    __shared__ float Ws[BK][LPAD];
    int tid = threadIdx.x;
    int lm = tid >> 2, lk = (tid & 3) * 4;
    int wk = tid >> 4, wf = (tid & 15) * 4;
    int ty = tid >> 4, tx = tid & 15;
    const float* arow = S + (size_t)(o + m0 + lm) * SEQ;
    float acc[4][4] = {};
    for (int k0 = 0; k0 < SEQ; k0 += BK) {
        float4 xv = *(const float4*)(arow + k0 + lk);
        float4 wv = *(const float4*)(V + (size_t)(k0 + wk) * HD + n0 + wf);
        __syncthreads();
        Xs[lk + 0][lm] = xv.x; Xs[lk + 1][lm] = xv.y;
        Xs[lk + 2][lm] = xv.z; Xs[lk + 3][lm] = xv.w;
        *(float4*)&Ws[wk][wf] = wv;
        __syncthreads();
#pragma unroll
        for (int k = 0; k < BK; k++) {
            float4 a = *(const float4*)&Xs[k][ty * 4];
            float4 b2 = *(const float4*)&Ws[k][tx * 4];
            acc[0][0] += a.x * b2.x; acc[0][1] += a.x * b2.y; acc[0][2] += a.x * b2.z; acc[0][3] += a.x * b2.w;
            acc[1][0] += a.y * b2.x; acc[1][1] += a.y * b2.y; acc[1][2] += a.y * b2.z; acc[1][3] += a.y * b2.w;
            acc[2][0] += a.z * b2.x; acc[2][1] += a.z * b2.y; acc[2][2] += a.z * b2.z; acc[2][3] += a.z * b2.w;
            acc[3][0] += a.w * b2.x; acc[3][1] += a.w * b2.y; acc[3][2] += a.w * b2.z; acc[3][3] += a.w * b2.w;
        }
    }
    int n = n0 + tx * 4;
#pragma unroll
    for (int i = 0; i < 4; i++) {
        int pos = o + m0 + ty * 4 + i;
        if (pos < o + c) {
            float g = aga[list[pos]];
            float4 ov = { acc[i][0] * g, acc[i][1] * g, acc[i][2] * g, acc[i][3] * g };
            *(float4*)(ctxg + (size_t)pos * HD + n) = ov;
        }
    }
}

// ---------------- x1 init: src + gated o_b ----------------
__global__ void x1_init_kernel(const float* __restrict__ src, const float* __restrict__ ob,
                               const int* __restrict__ aidx, const float* __restrict__ aga,
                               float* __restrict__ x1) {
    int t = blockIdx.x;
    int tid = threadIdx.x;
    int e0 = aidx[t * 2], e1 = aidx[t * 2 + 1];
    float g0 = aga[t * 2], g1 = aga[t * 2 + 1];
#pragma unroll
    for (int i = 0; i < 4; i++) {
        int d = tid + i * 256;
        x1[(size_t)t * D + d] = src[(size_t)t * D + d]
                              + g0 * ob[e0 * D + d] + g1 * ob[e1 * D + d];
    }
}

// ---------------- O GEMM: x1[token] += ctxg[pos] @ o_w[e]  (atomic scatter) ----------------
__global__ __launch_bounds__(256) void o_gemm(
    const float* __restrict__ ctxg, const float* __restrict__ ow,
    const int* __restrict__ meta, const int* __restrict__ list, float* __restrict__ x1) {
    int e = blockIdx.z;
    int o = meta[96 + e], c = meta[97 + e] - o;
    int m0 = blockIdx.x * TM;
    if (m0 >= c) return;
    int n0 = blockIdx.y * TN;
    const float* W = ow + (size_t)e * HD * D;
    __shared__ float Xs[BK][LPAD];
    __shared__ float Ws[BK][LPAD];
    int tid = threadIdx.x;
    int lm = tid >> 2, lk = (tid & 3) * 4;
    int wk = tid >> 4, wf = (tid & 15) * 4;
    int ty = tid >> 4, tx = tid & 15;
    const float* arow = ctxg + (size_t)(o + m0 + lm) * HD;
    float acc[4][4] = {};
    for (int k0 = 0; k0 < HD; k0 += BK) {
        float4 xv = *(const float4*)(arow + k0 + lk);
        float4 wv = *(const float4*)(W + (size_t)(k0 + wk) * D + n0 + wf);
        __syncthreads();
        Xs[lk + 0][lm] = xv.x; Xs[lk + 1][lm] = xv.y;
        Xs[lk + 2][lm] = xv.z; Xs[lk + 3][lm] = xv.w;
        *(float4*)&Ws[wk][wf] = wv;
        __syncthreads();
#pragma unroll
        for (int k = 0; k < BK; k++) {
            float4 a = *(const float4*)&Xs[k][ty * 4];
            float4 b2 = *(const float4*)&Ws[k][tx * 4];
            acc[0][0] += a.x * b2.x; acc[0][1] += a.x * b2.y; acc[0][2] += a.x * b2.z; acc[0][3] += a.x * b2.w;
            acc[1][0] += a.y * b2.x; acc[1][1] += a.y * b2.y; acc[1][2] += a.y * b2.z; acc[1][3] += a.y * b2.w;
            acc[2][0] += a.z * b2.x; acc[2][1] += a.z * b2.y; acc[2][2] += a.z * b2.z; acc[2][3] += a.z * b2.w;
            acc[3][0] += a.w * b2.x; acc[3][1] += a.w * b2.y; acc[3][2] += a.w * b2.z; acc[3][3] += a.w * b2.w;
        }
    }
    int n = n0 + tx * 4;
#pragma unroll
    for (int i = 0; i < 4; i++) {
        int pos = o + m0 + ty * 4 + i;
        if (pos < o + c) {
            int t = list[pos] >> 1;
            float* op = x1 + (size_t)t * D + n;
            atomicAdd(op + 0, acc[i][0]);
            atomicAdd(op + 1, acc[i][1]);
            atomicAdd(op + 2, acc[i][2]);
            atomicAdd(op + 3, acc[i][3]);
        }
    }
}

// ---------------- FFN binning (16 bins) ----------------
__global__ void bin_zero(int* __restrict__ meta) {
    if (threadIdx.x < 48) meta[threadIdx.x] = 0;
}
__global__ void bin_count(const int* __restrict__ fidx, int* __restrict__ meta) {
    int i = blockIdx.x * 256 + threadIdx.x;
    if (i < NPAIR) atomicAdd(&meta[fidx[i]], 1);
}
__global__ void bin_scan(int* __restrict__ meta) {
    if (threadIdx.x == 0 && blockIdx.x == 0) {
        int s = 0;
        for (int e = 0; e < EF; e++) { meta[16 + e] = s; meta[32 + e] = s; s += meta[e]; }
    }
}
__global__ void bin_scatter(const int* __restrict__ fidx, int* __restrict__ meta,
                            int* __restrict__ list) {
    int i = blockIdx.x * 256 + threadIdx.x;
    if (i < NPAIR) {
        int e = fidx[i];
        int pos = atomicAdd(&meta[32 + e], 1);
        list[pos] = i;
    }
}

__global__ void out_init_kernel(const float* __restrict__ x1, const float* __restrict__ b2,
                                const int* __restrict__ fidx, const float* __restrict__ fga,
                                float* __restrict__ out) {
    int t = blockIdx.x;
    int tid = threadIdx.x;
    int e0 = fidx[t * 2], e1 = fidx[t * 2 + 1];
    float g0 = fga[t * 2], g1 = fga[t * 2 + 1];
#pragma unroll
    for (int i = 0; i < 4; i++) {
        int d = tid + i * 256;
        out[(size_t)t * D + d] = x1[(size_t)t * D + d]
                               + g0 * b2[e0 * D + d] + g1 * b2[e1 * D + d];
    }
}

// ---------------- FFN GEMM1 (indirect A rows) ----------------
__global__ __launch_bounds__(256) void ffn_gemm1(
    const float* __restrict__ xn2, const float* __restrict__ w1, const float* __restrict__ b1,
    const int* __restrict__ meta, const int* __restrict__ list,
    const float* __restrict__ fga, float* __restrict__ H) {
    int e = blockIdx.z;
    int o = meta[16 + e], c = meta[e];
    int m0 = blockIdx.x * TM;
    if (m0 >= c) return;
    int n0 = blockIdx.y * TN;
    const float* W = w1 + (size_t)e * D * FH;
    __shared__ float Xs[BK][LPAD];
    __shared__ float Ws[BK][LPAD];
    int tid = threadIdx.x;
    int lm = tid >> 2, lk = (tid & 3) * 4;
    int wk = tid >> 4, wf = (tid & 15) * 4;
    int ty = tid >> 4, tx = tid & 15;
    int ridx = o + m0 + lm; if (ridx > NPAIR - 1) ridx = NPAIR - 1;
    const float* arow = xn2 + (size_t)(list[ridx] >> 1) * D;
    float acc[4][4] = {};
    for (int k0 = 0; k0 < D; k0 += BK) {
        float4 xv = *(const float4*)(arow + k0 + lk);
        float4 wv = *(const float4*)(W + (size_t)(k0 + wk) * FH + n0 + wf);
        __syncthreads();
        Xs[lk + 0][lm] = xv.x; Xs[lk + 1][lm] = xv.y;
        Xs[lk + 2][lm] = xv.z; Xs[lk + 3][lm] = xv.w;
        *(float4*)&Ws[wk][wf] = wv;
        __syncthreads();
#pragma unroll
        for (int k = 0; k < BK; k++) {
            float4 a = *(const float4*)&Xs[k][ty * 4];
            float4 b = *(const float4*)&Ws[k][tx * 4];
            acc[0][0] += a.x * b.x; acc[0][1] += a.x * b.y; acc[0][2] += a.x * b.z; acc[0][3] += a.x * b.w;
            acc[1][0] += a.y * b.x; acc[1][1] += a.y * b.y; acc[1][2] += a.y * b.z; acc[1][3] += a.y * b.w;
            acc[2][0] += a.z * b.x; acc[2][1] += a.z * b.y; acc[2][2] += a.z * b.z; acc[2][3] += a.z * b.w;
            acc[3][0] += a.w * b.x; acc[3][1] += a.w * b.y; acc[3][2] += a.w * b.z; acc[3][3] += a.w * b.w;
        }
    }
    int n = n0 + tx * 4;
    float4 bb = *(const float4*)(b1 + e * FH + n);
#pragma unroll
    for (int i = 0; i < 4; i++) {
        int pos = o + m0 + ty * 4 + i;
        if (pos < o + c) {
            float g = fga[list[pos]];
            float4 hv;
            hv.x = g * fmaxf(acc[i][0] + bb.x, 0.f);
            hv.y = g * fmaxf(acc[i][1] + bb.y, 0.f);
            hv.z = g * fmaxf(acc[i][2] + bb.z, 0.f);
            hv.w = g * fmaxf(acc[i][3] + bb.w, 0.f);
            *(float4*)(H + (size_t)pos * FH + n) = hv;
        }
    }
}

// ---------------- FFN GEMM2 (atomic scatter) ----------------
__global__ __launch_bounds__(256) void ffn_gemm2(
    const float* __restrict__ H, const float* __restrict__ w2,
    const int* __restrict__ meta, const int* __restrict__ list,
    float* __restrict__ out) {
    int e = blockIdx.z;
    int o = meta[16 + e], c = meta[e];
    int m0 = blockIdx.x * TM;
    if (m0 >= c) return;
    int n0 = blockIdx.y * TN;
    const float* W = w2 + (size_t)e * FH * D;
    __shared__ float Hs[BK][LPAD];
    __shared__ float Ws[BK][LPAD];
    int tid = threadIdx.x;
    int lm = tid >> 2, lk = (tid & 3) * 4;
    int wk = tid >> 4, wf = (tid & 15) * 4;
    int ty = tid >> 4, tx = tid & 15;
    const float* arow = H + (size_t)(o + m0 + lm) * FH;
    float acc[4][4] = {};
    for (int k0 = 0; k0 < FH; k0 += BK) {
        float4 xv = *(const float4*)(arow + k0 + lk);
        float4 wv = *(const float4*)(W + (size_t)(k0 + wk) * D + n0 + wf);
        __syncthreads();
        Hs[lk + 0][lm] = xv.x; Hs[lk + 1][lm] = xv.y;
        Hs[lk + 2][lm] = xv.z; Hs[lk + 3][lm] = xv.w;
        *(float4*)&Ws[wk][wf] = wv;
        __syncthreads();
#pragma unroll
        for (int k = 0; k < BK; k++) {
            float4 a = *(const float4*)&Hs[k][ty * 4];
            float4 b = *(const float4*)&Ws[k][tx * 4];
            acc[0][0] += a.x * b.x; acc[0][1] += a.x * b.y; acc[0][2] += a.x * b.z; acc[0][3] += a.x * b.w;
            acc[1][0] += a.y * b.x; acc[1][1] += a.y * b.y; acc[1][2] += a.y * b.z; acc[1][3] += a.y * b.w;
            acc[2][0] += a.z * b.x; acc[2][1] += a.z * b.y; acc[2][2] += a.z * b.z; acc[2][3] += a.z * b.w;
            acc[3][0] += a.w * b.x; acc[3][1] += a.w * b.y; acc[3][2] += a.w * b.z; acc[3][3] += a.w * b.w;
        }
    }
    int n = n0 + tx * 4;
#pragma unroll
    for (int i = 0; i < 4; i++) {
        int pos = o + m0 + ty * 4 + i;
        if (pos < o + c) {
            int t = list[pos] >> 1;
            float* op = out + (size_t)t * D + n;
            atomicAdd(op + 0, acc[i][0]);
            atomicAdd(op + 1, acc[i][1]);
            atomicAdd(op + 2, acc[i][2]);
            atomicAdd(op + 3, acc[i][3]);
        }
    }
}

extern "C" void kernel_launch(void* const* d_in, const int* in_sizes, int n_in,
                              void* d_out, int out_size, void* d_ws, size_t ws_size,
                              hipStream_t stream) {
    const float* src   = (const float*)d_in[0];
    const float* ln1_w = (const float*)d_in[1];
    const float* ln1_b = (const float*)d_in[2];
    const float* ln2_w = (const float*)d_in[3];
    const float* ln2_b = (const float*)d_in[4];
    const float* agw   = (const float*)d_in[5];
    const float* qw    = (const float*)d_in[6];
    const float* qb    = (const float*)d_in[7];
    const float* kw    = (const float*)d_in[8];
    const float* kb    = (const float*)d_in[9];
    const float* vw    = (const float*)d_in[10];
    const float* vb    = (const float*)d_in[11];
    const float* ow    = (const float*)d_in[12];
    const float* ob    = (const float*)d_in[13];
    const float* rel   = (const float*)d_in[14];
    const float* fgw   = (const float*)d_in[15];
    const float* w1    = (const float*)d_in[16];
    const float* b1    = (const float*)d_in[17];
    const float* w2    = (const float*)d_in[18];
    const float* b2    = (const float*)d_in[19];
    float* out = (float*)d_out;

    char* p = (char*)d_ws;
    float* xn1  = (float*)p; p += (size_t)NTOK * D * 4;            // LN1 out; reused as LN2 out
    float* x1   = (float*)p; p += (size_t)NTOK * D * 4;
    float* Sbuf = (float*)p; p += (size_t)(NPAIR + TM) * SEQ * 4;  // scores/P (+slack rows)
    // Region reused across phases: [ctxg | Qg | Rbuf] then Hbuf
    char*  reg  = p;         p += (size_t)(NPAIR + TM) * FH * 4;   // 16.9 MB
    float* ctxg = (float*)reg;                                     // (NPAIR+64)*HD = 4.23 MB
    float* Qg   = (float*)(reg + (size_t)4352 * 1024);             // 4.45 MB off
    float* Rbuf = (float*)(reg + (size_t)8832 * 1024);             // 4.36 MB used
    float* Hbuf = (float*)reg;                                     // FFN phase
    float* kbuf = (float*)p; p += (size_t)NTOK * HD * 4;
    float* vbuf = (float*)p; p += (size_t)NTOK * HD * 4;
    int*   aidx = (int*)p;   p += NPAIR * 4;
    float* aga  = (float*)p; p += NPAIR * 4;
    int*   fidx = (int*)p;   p += NPAIR * 4;
    float* fga  = (float*)p; p += NPAIR * 4;
    int*   ameta = (int*)p;  p += 128 * 4;   // counts/off/cur/eoff
    int*   alist = (int*)p;  p += NPAIR * 4;
    int*   fmeta = (int*)p;  p += 64 * 4;
    int*   flist = (int*)p;  p += NPAIR * 4;
    float* xn2  = xn1;  // safe reuse: xn1 dead after q_gemm

    // ---- attention block ----
    ln_kernel<<<NTOK, 256, 0, stream>>>(src, ln1_w, ln1_b, xn1);
    router_kernel<EA><<<NTOK, 64, 0, stream>>>(xn1, agw, aidx, aga);
    abin_zero<<<1, 128, 0, stream>>>(ameta);
    abin_count<<<NPAIR / 256, 256, 0, stream>>>(aidx, ameta);
    abin_scan<<<1, 64, 0, stream>>>(ameta);
    abin_scatter<<<NPAIR / 256, 256, 0, stream>>>(aidx, ameta, alist);
    {
        dim3 g(NTOK / TM, HD / TN, 2);
        kv_gemm<<<g, 256, 0, stream>>>(xn1, kw, kb, vw, vb, kbuf, vbuf);
    }
    {
        dim3 g(NPAIR / TM, HD / TN, EA);
        q_gemm<<<g, 256, 0, stream>>>(xn1, qw, qb, ameta, alist, Qg);
    }
    rel_kernel<<<NPAIR, 192, 0, stream>>>(Qg, rel, Rbuf);
    {
        dim3 g(48, SEQ / TN, 32);  // 48 m-tiles covers bins up to 3072 rows (12x uniform)
        s_gemm<<<g, 256, 0, stream>>>(Qg, kbuf, Rbuf, ameta, alist, Sbuf);
    }
    softmax_kernel<<<NPAIR, 256, 0, stream>>>(Sbuf);
    {
        dim3 g(48, HD / TN, 32);
        pv_gemm<<<g, 256, 0, stream>>>(Sbuf, vbuf, ameta, alist, aga, ctxg);
    }
    x1_init_kernel<<<NTOK, 256, 0, stream>>>(src, ob, aidx, aga, x1);
    {
        dim3 g(NPAIR / TM, D / TN, EA);
        o_gemm<<<g, 256, 0, stream>>>(ctxg, ow, ameta, alist, x1);
    }

    // ---- FFN block ----
    ln_kernel<<<NTOK, 256, 0, stream>>>(x1, ln2_w, ln2_b, xn2);
    router_kernel<EF><<<NTOK, 64, 0, stream>>>(xn2, fgw, fidx, fga);
    bin_zero<<<1, 64, 0, stream>>>(fmeta);
    bin_count<<<NPAIR / 256, 256, 0, stream>>>(fidx, fmeta);
    bin_scan<<<1, 64, 0, stream>>>(fmeta);
    bin_scatter<<<NPAIR / 256, 256, 0, stream>>>(fidx, fmeta, flist);
    out_init_kernel<<<NTOK, 256, 0, stream>>>(x1, b2, fidx, fga, out);
    {
        dim3 g1(NPAIR / TM, FH / TN, EF);
        ffn_gemm1<<<g1, 256, 0, stream>>>(xn2, w1, b1, fmeta, flist, fga, Hbuf);
        dim3 g2(NPAIR / TM, D / TN, EF);
        ffn_gemm2<<<g2, 256, 0, stream>>>(Hbuf, w2, fmeta, flist, out);
    }
}

// Round 4
// 1229.629 us; speedup vs baseline: 4.2101x; 1.4077x over previous
//
#include <hip/hip_runtime.h>

#define D 1024
#define HD 128
#define EA 8
#define EF 16
#define FH 512
#define MAXPOS 64
#define RNUM 129
#define RSTRIDE 132
#define SEQ 1024
#define NTOK 4096
#define NPAIR (NTOK * 2)
#define LN_EPS 1e-5f
#define QSCALE 0.08838834764831845f

#define TM 64
#define TN 64
#define BK 16
#define LPAD 68   // LDS row stride (floats) for fp32 GEMMs

typedef __attribute__((ext_vector_type(8))) short bf16x8;
typedef __attribute__((ext_vector_type(4))) float f32x4;

__device__ inline ushort f2b(float f) {
    union { float f; unsigned u; } v; v.f = f;
    unsigned r = (v.u + 0x7fffu + ((v.u >> 16) & 1u)) >> 16;
    return (ushort)r;
}

// ---------------- LayerNorm ----------------
__global__ void ln_kernel(const float* __restrict__ x, const float* __restrict__ w,
                          const float* __restrict__ b, float* __restrict__ y) {
    int row = blockIdx.x;
    const float* xr = x + (size_t)row * D;
    float v[4];
    float s = 0.f, s2 = 0.f;
#pragma unroll
    for (int i = 0; i < 4; i++) {
        v[i] = xr[threadIdx.x + i * 256];
        s += v[i]; s2 += v[i] * v[i];
    }
#pragma unroll
    for (int off = 32; off; off >>= 1) { s += __shfl_down(s, off); s2 += __shfl_down(s2, off); }
    __shared__ float red0[4], red1[4];
    int wave = threadIdx.x >> 6, lane = threadIdx.x & 63;
    if (lane == 0) { red0[wave] = s; red1[wave] = s2; }
    __syncthreads();
    float ts = red0[0] + red0[1] + red0[2] + red0[3];
    float ts2 = red1[0] + red1[1] + red1[2] + red1[3];
    float mu = ts * (1.f / D);
    float var = ts2 * (1.f / D) - mu * mu;
    float inv = rsqrtf(var + LN_EPS);
#pragma unroll
    for (int i = 0; i < 4; i++) {
        int d = threadIdx.x + i * 256;
        y[(size_t)row * D + d] = (v[i] - mu) * inv * w[d] + b[d];
    }
}

// ---------------- Router ----------------
template <int E>
__global__ void router_kernel(const float* __restrict__ xn, const float* __restrict__ gw,
                              int* __restrict__ idx, float* __restrict__ gate) {
    int t = blockIdx.x;
    int lane = threadIdx.x;  // block=64
    float acc[E];
#pragma unroll
    for (int e = 0; e < E; e++) acc[e] = 0.f;
    const float* xr = xn + (size_t)t * D;
    for (int d = lane; d < D; d += 64) {
        float xv = xr[d];
#pragma unroll
        for (int e = 0; e < E; e++) acc[e] += xv * gw[d * E + e];
    }
#pragma unroll
    for (int e = 0; e < E; e++) {
#pragma unroll
        for (int off = 32; off; off >>= 1) acc[e] += __shfl_down(acc[e], off);
    }
    if (lane == 0) {
        float v0 = -1e30f, v1 = -1e30f;
        int i0 = 0, i1 = 0;
#pragma unroll
        for (int e = 0; e < E; e++) {
            float a = acc[e];
            if (a > v0) { v1 = v0; i1 = i0; v0 = a; i0 = e; }
            else if (a > v1) { v1 = a; i1 = e; }
        }
        float g0 = 1.f / (1.f + expf(v1 - v0));
        idx[t * 2] = i0; idx[t * 2 + 1] = i1;
        gate[t * 2] = g0; gate[t * 2 + 1] = 1.f - g0;
    }
}

// ---------------- Attention binning: 32 bins keyed (expert*4 + batch) ----------------
__global__ void abin_zero(int* __restrict__ meta) {
    if (threadIdx.x < 105) meta[threadIdx.x] = 0;
}
__global__ void abin_count(const int* __restrict__ aidx, int* __restrict__ meta) {
    int i = blockIdx.x * 256 + threadIdx.x;
    if (i < NPAIR) {
        int e = aidx[i];
        int b = (i >> 1) >> 10;
        atomicAdd(&meta[e * 4 + b], 1);
    }
}
__global__ void abin_scan(int* __restrict__ meta) {
    if (threadIdx.x == 0 && blockIdx.x == 0) {
        int s = 0;
        for (int bin = 0; bin < 32; bin++) {
            if ((bin & 3) == 0) meta[96 + (bin >> 2)] = s;
            meta[32 + bin] = s; meta[64 + bin] = s; s += meta[bin];
        }
        meta[96 + 8] = s;
    }
}
__global__ void abin_scatter(const int* __restrict__ aidx, int* __restrict__ meta,
                             int* __restrict__ list) {
    int i = blockIdx.x * 256 + threadIdx.x;
    if (i < NPAIR) {
        int e = aidx[i];
        int b = (i >> 1) >> 10;
        int pos = atomicAdd(&meta[64 + e * 4 + b], 1);
        list[pos] = i;
    }
}

// ---------------- K/V projection GEMM ----------------
__global__ __launch_bounds__(256) void kv_gemm(
    const float* __restrict__ xn,
    const float* __restrict__ kw, const float* __restrict__ kb,
    const float* __restrict__ vw, const float* __restrict__ vb,
    float* __restrict__ kbuf, float* __restrict__ vbuf) {
    const float* W = blockIdx.z ? vw : kw;
    const float* bias = blockIdx.z ? vb : kb;
    float* outp = blockIdx.z ? vbuf : kbuf;
    int m0 = blockIdx.x * TM;
    int n0 = blockIdx.y * TN;
    __shared__ float Xs[BK][LPAD];
    __shared__ float Ws[BK][LPAD];
    int tid = threadIdx.x;
    int lm = tid >> 2, lk = (tid & 3) * 4;
    int wk = tid >> 4, wf = (tid & 15) * 4;
    int ty = tid >> 4, tx = tid & 15;
    float acc[4][4] = {};
    const float* arow = xn + (size_t)(m0 + lm) * D;
    for (int k0 = 0; k0 < D; k0 += BK) {
        float4 xv = *(const float4*)(arow + k0 + lk);
        float4 wv = *(const float4*)(W + (size_t)(k0 + wk) * HD + n0 + wf);
        __syncthreads();
        Xs[lk + 0][lm] = xv.x; Xs[lk + 1][lm] = xv.y;
        Xs[lk + 2][lm] = xv.z; Xs[lk + 3][lm] = xv.w;
        *(float4*)&Ws[wk][wf] = wv;
        __syncthreads();
#pragma unroll
        for (int k = 0; k < BK; k++) {
            float4 a = *(const float4*)&Xs[k][ty * 4];
            float4 b = *(const float4*)&Ws[k][tx * 4];
            acc[0][0] += a.x * b.x; acc[0][1] += a.x * b.y; acc[0][2] += a.x * b.z; acc[0][3] += a.x * b.w;
            acc[1][0] += a.y * b.x; acc[1][1] += a.y * b.y; acc[1][2] += a.y * b.z; acc[1][3] += a.y * b.w;
            acc[2][0] += a.z * b.x; acc[2][1] += a.z * b.y; acc[2][2] += a.z * b.z; acc[2][3] += a.z * b.w;
            acc[3][0] += a.w * b.x; acc[3][1] += a.w * b.y; acc[3][2] += a.w * b.z; acc[3][3] += a.w * b.w;
        }
    }
    int n = n0 + tx * 4;
    float4 bb = *(const float4*)(bias + n);
#pragma unroll
    for (int i = 0; i < 4; i++) {
        int m = m0 + ty * 4 + i;
        float4 ov = { acc[i][0] + bb.x, acc[i][1] + bb.y, acc[i][2] + bb.z, acc[i][3] + bb.w };
        *(float4*)(outp + (size_t)m * HD + n) = ov;
    }
}

// ---------------- Q projection GEMM (binned, indirect A rows) ----------------
__global__ __launch_bounds__(256) void q_gemm(
    const float* __restrict__ xn, const float* __restrict__ qw, const float* __restrict__ qb,
    const int* __restrict__ meta, const int* __restrict__ list, float* __restrict__ Qg) {
    int e = blockIdx.z;
    int o = meta[96 + e], c = meta[97 + e] - o;
    int m0 = blockIdx.x * TM;
    if (m0 >= c) return;
    int n0 = blockIdx.y * TN;
    const float* W = qw + (size_t)e * D * HD;
    __shared__ float Xs[BK][LPAD];
    __shared__ float Ws[BK][LPAD];
    int tid = threadIdx.x;
    int lm = tid >> 2, lk = (tid & 3) * 4;
    int wk = tid >> 4, wf = (tid & 15) * 4;
    int ty = tid >> 4, tx = tid & 15;
    int ridx = o + m0 + lm; if (ridx > NPAIR - 1) ridx = NPAIR - 1;
    const float* arow = xn + (size_t)(list[ridx] >> 1) * D;
    float acc[4][4] = {};
    for (int k0 = 0; k0 < D; k0 += BK) {
        float4 xv = *(const float4*)(arow + k0 + lk);
        float4 wv = *(const float4*)(W + (size_t)(k0 + wk) * HD + n0 + wf);
        __syncthreads();
        Xs[lk + 0][lm] = xv.x; Xs[lk + 1][lm] = xv.y;
        Xs[lk + 2][lm] = xv.z; Xs[lk + 3][lm] = xv.w;
        *(float4*)&Ws[wk][wf] = wv;
        __syncthreads();
#pragma unroll
        for (int k = 0; k < BK; k++) {
            float4 a = *(const float4*)&Xs[k][ty * 4];
            float4 b = *(const float4*)&Ws[k][tx * 4];
            acc[0][0] += a.x * b.x; acc[0][1] += a.x * b.y; acc[0][2] += a.x * b.z; acc[0][3] += a.x * b.w;
            acc[1][0] += a.y * b.x; acc[1][1] += a.y * b.y; acc[1][2] += a.y * b.z; acc[1][3] += a.y * b.w;
            acc[2][0] += a.z * b.x; acc[2][1] += a.z * b.y; acc[2][2] += a.z * b.z; acc[2][3] += a.z * b.w;
            acc[3][0] += a.w * b.x; acc[3][1] += a.w * b.y; acc[3][2] += a.w * b.z; acc[3][3] += a.w * b.w;
        }
    }
    int n = n0 + tx * 4;
    float4 bb = *(const float4*)(qb + e * HD + n);
#pragma unroll
    for (int i = 0; i < 4; i++) {
        int pos = o + m0 + ty * 4 + i;
        if (pos < o + c) {
            float4 ov = { (acc[i][0] + bb.x) * QSCALE, (acc[i][1] + bb.y) * QSCALE,
                          (acc[i][2] + bb.z) * QSCALE, (acc[i][3] + bb.w) * QSCALE };
            *(float4*)(Qg + (size_t)pos * HD + n) = ov;
        }
    }
}

// ---------------- Rel-pos dots ----------------
__global__ void rel_kernel(const float* __restrict__ Qg, const float* __restrict__ rel,
                           float* __restrict__ R) {
    int pos = blockIdx.x;
    __shared__ float q[HD];
    if (threadIdx.x < 32) ((float4*)q)[threadIdx.x] = ((const float4*)(Qg + (size_t)pos * HD))[threadIdx.x];
    __syncthreads();
    int r = threadIdx.x;
    if (r < RNUM) {
        const float4* rr = (const float4*)(rel + r * HD);
        const float4* qv = (const float4*)q;
        float a = 0.f;
#pragma unroll
        for (int h4 = 0; h4 < HD / 4; h4++) {
            float4 rv = rr[h4], qa = qv[h4];
            a += qa.x * rv.x + qa.y * rv.y + qa.z * rv.z + qa.w * rv.w;
        }
        R[(size_t)pos * RSTRIDE + r] = a;
    }
}

// ---------------- Score GEMM ----------------
__global__ __launch_bounds__(256) void s_gemm(
    const float* __restrict__ Qg, const float* __restrict__ kbuf,
    const float* __restrict__ R, const int* __restrict__ meta,
    const int* __restrict__ list, float* __restrict__ S) {
    int bin = blockIdx.z;
    int o = meta[32 + bin], c = meta[bin];
    int m0 = blockIdx.x * TM;
    if (m0 >= c) return;
    int b = bin & 3;
    int n0 = blockIdx.y * TN;
    const float* kb = kbuf + (size_t)b * SEQ * HD;
    __shared__ float Xs[BK][LPAD];
    __shared__ float Ws[BK][LPAD];
    int tid = threadIdx.x;
    int lm = tid >> 2, lk = (tid & 3) * 4;
    int tn = tid & 63, tkq = tid >> 6;
    int ty = tid >> 4, tx = tid & 15;
    const float* arow = Qg + (size_t)(o + m0 + lm) * HD;
    float acc[4][4] = {};
    for (int k0 = 0; k0 < HD; k0 += BK) {
        float4 xv = *(const float4*)(arow + k0 + lk);
        float4 kv = *(const float4*)(kb + (size_t)(n0 + tn) * HD + k0 + tkq * 4);
        __syncthreads();
        Xs[lk + 0][lm] = xv.x; Xs[lk + 1][lm] = xv.y;
        Xs[lk + 2][lm] = xv.z; Xs[lk + 3][lm] = xv.w;
        Ws[tkq * 4 + 0][tn] = kv.x; Ws[tkq * 4 + 1][tn] = kv.y;
        Ws[tkq * 4 + 2][tn] = kv.z; Ws[tkq * 4 + 3][tn] = kv.w;
        __syncthreads();
#pragma unroll
        for (int k = 0; k < BK; k++) {
            float4 a = *(const float4*)&Xs[k][ty * 4];
            float4 b2 = *(const float4*)&Ws[k][tx * 4];
            acc[0][0] += a.x * b2.x; acc[0][1] += a.x * b2.y; acc[0][2] += a.x * b2.z; acc[0][3] += a.x * b2.w;
            acc[1][0] += a.y * b2.x; acc[1][1] += a.y * b2.y; acc[1][2] += a.y * b2.z; acc[1][3] += a.y * b2.w;
            acc[2][0] += a.z * b2.x; acc[2][1] += a.z * b2.y; acc[2][2] += a.z * b2.z; acc[2][3] += a.z * b2.w;
            acc[3][0] += a.w * b2.x; acc[3][1] += a.w * b2.y; acc[3][2] += a.w * b2.z; acc[3][3] += a.w * b2.w;
        }
    }
#pragma unroll
    for (int i = 0; i < 4; i++) {
        int pos = o + m0 + ty * 4 + i;
        if (pos < o + c) {
            int qpos = (list[pos] >> 1) & (SEQ - 1);
            const float* Rrow = R + (size_t)pos * RSTRIDE;
            float* srow = S + (size_t)pos * SEQ;
#pragma unroll
            for (int j = 0; j < 4; j++) {
                int key = n0 + tx * 4 + j;
                int ri = key - qpos;
                ri = (ri < -MAXPOS ? -MAXPOS : (ri > MAXPOS ? MAXPOS : ri)) + MAXPOS;
                srow[key] = acc[i][j] + Rrow[ri];
            }
        }
    }
}

// ---------------- Row softmax ----------------
__global__ __launch_bounds__(256) void softmax_kernel(float* __restrict__ S) {
    int row = blockIdx.x;
    float4* sr = (float4*)(S + (size_t)row * SEQ);
    float4 v = sr[threadIdx.x];
    float m = fmaxf(fmaxf(v.x, v.y), fmaxf(v.z, v.w));
#pragma unroll
    for (int off = 32; off; off >>= 1) m = fmaxf(m, __shfl_down(m, off));
    __shared__ float red0[4], red1[4];
    int wave = threadIdx.x >> 6, lane = threadIdx.x & 63;
    if (lane == 0) red0[wave] = m;
    __syncthreads();
    m = fmaxf(fmaxf(red0[0], red0[1]), fmaxf(red0[2], red0[3]));
    v.x = __expf(v.x - m); v.y = __expf(v.y - m);
    v.z = __expf(v.z - m); v.w = __expf(v.w - m);
    float s = v.x + v.y + v.z + v.w;
#pragma unroll
    for (int off = 32; off; off >>= 1) s += __shfl_down(s, off);
    if (lane == 0) red1[wave] = s;
    __syncthreads();
    float inv = 1.f / (red1[0] + red1[1] + red1[2] + red1[3]);
    v.x *= inv; v.y *= inv; v.z *= inv; v.w *= inv;
    sr[threadIdx.x] = v;
}

// ---------------- PV GEMM ----------------
__global__ __launch_bounds__(256) void pv_gemm(
    const float* __restrict__ S, const float* __restrict__ vbuf,
    const int* __restrict__ meta, const int* __restrict__ list,
    const float* __restrict__ aga, float* __restrict__ ctxg) {
    int bin = blockIdx.z;
    int o = meta[32 + bin], c = meta[bin];
    int m0 = blockIdx.x * TM;
    if (m0 >= c) return;
    int b = bin & 3;
    int n0 = blockIdx.y * TN;
    const float* V = vbuf + (size_t)b * SEQ * HD;
    __shared__ float Xs[BK][LPAD];
    __shared__ float Ws[BK][LPAD];
    int tid = threadIdx.x;
    int lm = tid >> 2, lk = (tid & 3) * 4;
    int wk = tid >> 4, wf = (tid & 15) * 4;
    int ty = tid >> 4, tx = tid & 15;
    const float* arow = S + (size_t)(o + m0 + lm) * SEQ;
    float acc[4][4] = {};
    for (int k0 = 0; k0 < SEQ; k0 += BK) {
        float4 xv = *(const float4*)(arow + k0 + lk);
        float4 wv = *(const float4*)(V + (size_t)(k0 + wk) * HD + n0 + wf);
        __syncthreads();
        Xs[lk + 0][lm] = xv.x; Xs[lk + 1][lm] = xv.y;
        Xs[lk + 2][lm] = xv.z; Xs[lk + 3][lm] = xv.w;
        *(float4*)&Ws[wk][wf] = wv;
        __syncthreads();
#pragma unroll
        for (int k = 0; k < BK; k++) {
            float4 a = *(const float4*)&Xs[k][ty * 4];
            float4 b2 = *(const float4*)&Ws[k][tx * 4];
            acc[0][0] += a.x * b2.x; acc[0][1] += a.x * b2.y; acc[0][2] += a.x * b2.z; acc[0][3] += a.x * b2.w;
            acc[1][0] += a.y * b2.x; acc[1][1] += a.y * b2.y; acc[1][2] += a.y * b2.z; acc[1][3] += a.y * b2.w;
            acc[2][0] += a.z * b2.x; acc[2][1] += a.z * b2.y; acc[2][2] += a.z * b2.z; acc[2][3] += a.z * b2.w;
            acc[3][0] += a.w * b2.x; acc[3][1] += a.w * b2.y; acc[3][2] += a.w * b2.z; acc[3][3] += a.w * b2.w;
        }
    }
    int n = n0 + tx * 4;
#pragma unroll
    for (int i = 0; i < 4; i++) {
        int pos = o + m0 + ty * 4 + i;
        if (pos < o + c) {
            float g = aga[list[pos]];
            float4 ov = { acc[i][0] * g, acc[i][1] * g, acc[i][2] * g, acc[i][3] * g };
            *(float4*)(ctxg + (size_t)pos * HD + n) = ov;
        }
    }
}

// ---------------- x1 init ----------------
__global__ void x1_init_kernel(const float* __restrict__ src, const float* __restrict__ ob,
                               const int* __restrict__ aidx, const float* __restrict__ aga,
                               float* __restrict__ x1) {
    int t = blockIdx.x;
    int tid = threadIdx.x;
    int e0 = aidx[t * 2], e1 = aidx[t * 2 + 1];
    float g0 = aga[t * 2], g1 = aga[t * 2 + 1];
#pragma unroll
    for (int i = 0; i < 4; i++) {
        int d = tid + i * 256;
        x1[(size_t)t * D + d] = src[(size_t)t * D + d]
                              + g0 * ob[e0 * D + d] + g1 * ob[e1 * D + d];
    }
}

// ---------------- O GEMM (atomic scatter) ----------------
__global__ __launch_bounds__(256) void o_gemm(
    const float* __restrict__ ctxg, const float* __restrict__ ow,
    const int* __restrict__ meta, const int* __restrict__ list, float* __restrict__ x1) {
    int e = blockIdx.z;
    int o = meta[96 + e], c = meta[97 + e] - o;
    int m0 = blockIdx.x * TM;
    if (m0 >= c) return;
    int n0 = blockIdx.y * TN;
    const float* W = ow + (size_t)e * HD * D;
    __shared__ float Xs[BK][LPAD];
    __shared__ float Ws[BK][LPAD];
    int tid = threadIdx.x;
    int lm = tid >> 2, lk = (tid & 3) * 4;
    int wk = tid >> 4, wf = (tid & 15) * 4;
    int ty = tid >> 4, tx = tid & 15;
    const float* arow = ctxg + (size_t)(o + m0 + lm) * HD;
    float acc[4][4] = {};
    for (int k0 = 0; k0 < HD; k0 += BK) {
        float4 xv = *(const float4*)(arow + k0 + lk);
        float4 wv = *(const float4*)(W + (size_t)(k0 + wk) * D + n0 + wf);
        __syncthreads();
        Xs[lk + 0][lm] = xv.x; Xs[lk + 1][lm] = xv.y;
        Xs[lk + 2][lm] = xv.z; Xs[lk + 3][lm] = xv.w;
        *(float4*)&Ws[wk][wf] = wv;
        __syncthreads();
#pragma unroll
        for (int k = 0; k < BK; k++) {
            float4 a = *(const float4*)&Xs[k][ty * 4];
            float4 b2 = *(const float4*)&Ws[k][tx * 4];
            acc[0][0] += a.x * b2.x; acc[0][1] += a.x * b2.y; acc[0][2] += a.x * b2.z; acc[0][3] += a.x * b2.w;
            acc[1][0] += a.y * b2.x; acc[1][1] += a.y * b2.y; acc[1][2] += a.y * b2.z; acc[1][3] += a.y * b2.w;
            acc[2][0] += a.z * b2.x; acc[2][1] += a.z * b2.y; acc[2][2] += a.z * b2.z; acc[2][3] += a.z * b2.w;
            acc[3][0] += a.w * b2.x; acc[3][1] += a.w * b2.y; acc[3][2] += a.w * b2.z; acc[3][3] += a.w * b2.w;
        }
    }
    int n = n0 + tx * 4;
#pragma unroll
    for (int i = 0; i < 4; i++) {
        int pos = o + m0 + ty * 4 + i;
        if (pos < o + c) {
            int t = list[pos] >> 1;
            float* op = x1 + (size_t)t * D + n;
            atomicAdd(op + 0, acc[i][0]);
            atomicAdd(op + 1, acc[i][1]);
            atomicAdd(op + 2, acc[i][2]);
            atomicAdd(op + 3, acc[i][3]);
        }
    }
}

// ---------------- FFN binning ----------------
__global__ void bin_zero(int* __restrict__ meta) {
    if (threadIdx.x < 48) meta[threadIdx.x] = 0;
}
__global__ void bin_count(const int* __restrict__ fidx, int* __restrict__ meta) {
    int i = blockIdx.x * 256 + threadIdx.x;
    if (i < NPAIR) atomicAdd(&meta[fidx[i]], 1);
}
__global__ void bin_scan(int* __restrict__ meta) {
    if (threadIdx.x == 0 && blockIdx.x == 0) {
        int s = 0;
        for (int e = 0; e < EF; e++) { meta[16 + e] = s; meta[32 + e] = s; s += meta[e]; }
    }
}
__global__ void bin_scatter(const int* __restrict__ fidx, int* __restrict__ meta,
                            int* __restrict__ list) {
    int i = blockIdx.x * 256 + threadIdx.x;
    if (i < NPAIR) {
        int e = fidx[i];
        int pos = atomicAdd(&meta[32 + e], 1);
        list[pos] = i;
    }
}

__global__ void out_init_kernel(const float* __restrict__ x1, const float* __restrict__ b2,
                                const int* __restrict__ fidx, const float* __restrict__ fga,
                                float* __restrict__ out) {
    int t = blockIdx.x;
    int tid = threadIdx.x;
    int e0 = fidx[t * 2], e1 = fidx[t * 2 + 1];
    float g0 = fga[t * 2], g1 = fga[t * 2 + 1];
#pragma unroll
    for (int i = 0; i < 4; i++) {
        int d = tid + i * 256;
        out[(size_t)t * D + d] = x1[(size_t)t * D + d]
                               + g0 * b2[e0 * D + d] + g1 * b2[e1 * D + d];
    }
}

// ---------------- fp32 -> bf16 conversions ----------------
__global__ void conv_bf16_kernel(const float* __restrict__ in, ushort* __restrict__ out) {
    size_t i = ((size_t)blockIdx.x * 256 + threadIdx.x) * 4;
    float4 v = *(const float4*)(in + i);
    ushort4 o4 = { f2b(v.x), f2b(v.y), f2b(v.z), f2b(v.w) };
    *(ushort4*)(out + i) = o4;
}

// in: [E][R][C] fp32 -> out: [E][C][R] bf16 (transpose-convert)
template <int R, int C>
__global__ void convT_kernel(const float* __restrict__ in, ushort* __restrict__ out) {
    int e = blockIdx.z;
    int r0 = blockIdx.x * 32, c0 = blockIdx.y * 32;
    __shared__ float tile[32][33];
    int tx = threadIdx.x & 31, ty = threadIdx.x >> 5;  // 256 thr: ty 0..7
    const float* src = in + (size_t)e * R * C;
#pragma unroll
    for (int i = 0; i < 32; i += 8)
        tile[ty + i][tx] = src[(size_t)(r0 + ty + i) * C + c0 + tx];
    __syncthreads();
    ushort* dst = out + (size_t)e * C * R;
#pragma unroll
    for (int i = 0; i < 32; i += 8)
        dst[(size_t)(c0 + ty + i) * R + r0 + tx] = f2b(tile[tx][ty + i]);
}

// ---------------- MFMA FFN GEMM1: Hb = g*relu(xnb @ W1 + b1), bf16 out ----------------
// 128x128 tile, BK=32, 4 waves as 2x2 of 64x64, mfma_f32_16x16x32_bf16
#define BSTR 40  // LDS row stride in bf16 elems (80 B = 5*16B, 2-way bank alias only)
__global__ __launch_bounds__(256) void ffn_mfma1(
    const ushort* __restrict__ xnb, const ushort* __restrict__ w1t,
    const float* __restrict__ b1, const int* __restrict__ meta,
    const int* __restrict__ list, const float* __restrict__ fga,
    ushort* __restrict__ Hb) {
    int e = blockIdx.z;
    int o = meta[16 + e], c = meta[e];
    int m0 = blockIdx.x * 128;
    if (m0 >= c) return;
    int n0 = blockIdx.y * 128;
    __shared__ __align__(16) short As[128 * BSTR];
    __shared__ __align__(16) short Bs[128 * BSTR];
    int tid = threadIdx.x;
    int srow = tid >> 2, sq = tid & 3;  // staging: 2 rows x 8-bf16 chunk each
    int r0i = o + m0 + srow;      if (r0i > NPAIR - 1) r0i = NPAIR - 1;
    int r1i = o + m0 + srow + 64; if (r1i > NPAIR - 1) r1i = NPAIR - 1;
    const ushort* a0 = xnb + (size_t)(list[r0i] >> 1) * D;
    const ushort* a1 = xnb + (size_t)(list[r1i] >> 1) * D;
    const ushort* b0 = w1t + ((size_t)e * FH + n0 + srow) * D;
    const ushort* bq = w1t + ((size_t)e * FH + n0 + srow + 64) * D;
    int w = tid >> 6, lid = tid & 63;
    int wr = (w >> 1) * 64, wc = (w & 1) * 64;
    int m16 = lid & 15, q = lid >> 4;
    f32x4 acc[4][4] = {};
    for (int k0 = 0; k0 < D; k0 += 32) {
        float4 va0 = *(const float4*)(a0 + k0 + sq * 8);
        float4 va1 = *(const float4*)(a1 + k0 + sq * 8);
        float4 vb0 = *(const float4*)(b0 + k0 + sq * 8);
        float4 vb1 = *(const float4*)(bq + k0 + sq * 8);
        __syncthreads();
        *(float4*)&As[srow * BSTR + sq * 8] = va0;
        *(float4*)&As[(srow + 64) * BSTR + sq * 8] = va1;
        *(float4*)&Bs[srow * BSTR + sq * 8] = vb0;
        *(float4*)&Bs[(srow + 64) * BSTR + sq * 8] = vb1;
        __syncthreads();
        bf16x8 af[4], bfr[4];
#pragma unroll
        for (int i = 0; i < 4; i++) {
            af[i]  = *(const bf16x8*)&As[(wr + i * 16 + m16) * BSTR + q * 8];
            bfr[i] = *(const bf16x8*)&Bs[(wc + i * 16 + m16) * BSTR + q * 8];
        }
#pragma unroll
        for (int i = 0; i < 4; i++)
#pragma unroll
            for (int j = 0; j < 4; j++)
                acc[i][j] = __builtin_amdgcn_mfma_f32_16x16x32_bf16(af[i], bfr[j], acc[i][j], 0, 0, 0);
    }
#pragma unroll
    for (int i = 0; i < 4; i++) {
#pragma unroll
        for (int r = 0; r < 4; r++) {
            int pos = o + m0 + wr + i * 16 + q * 4 + r;
            if (pos < o + c) {
                float g = fga[list[pos]];
#pragma unroll
                for (int j = 0; j < 4; j++) {
                    int n = n0 + wc + j * 16 + m16;
                    float vv = g * fmaxf(acc[i][j][r] + b1[e * FH + n], 0.f);
                    Hb[(size_t)pos * FH + n] = f2b(vv);
                }
            }
        }
    }
}

// ---------------- MFMA FFN GEMM2: out += Hb @ W2 (atomic scatter) ----------------
__global__ __launch_bounds__(256) void ffn_mfma2(
    const ushort* __restrict__ Hb, const ushort* __restrict__ w2t,
    const int* __restrict__ meta, const int* __restrict__ list,
    float* __restrict__ out) {
    int e = blockIdx.z;
    int o = meta[16 + e], c = meta[e];
    int m0 = blockIdx.x * 128;
    if (m0 >= c) return;
    int n0 = blockIdx.y * 128;
    __shared__ __align__(16) short As[128 * BSTR];
    __shared__ __align__(16) short Bs[128 * BSTR];
    int tid = threadIdx.x;
    int srow = tid >> 2, sq = tid & 3;
    const ushort* a0 = Hb + (size_t)(o + m0 + srow) * FH;        // slack rows exist
    const ushort* a1 = Hb + (size_t)(o + m0 + srow + 64) * FH;
    const ushort* b0 = w2t + ((size_t)e * D + n0 + srow) * FH;
    const ushort* bq = w2t + ((size_t)e * D + n0 + srow + 64) * FH;
    int w = tid >> 6, lid = tid & 63;
    int wr = (w >> 1) * 64, wc = (w & 1) * 64;
    int m16 = lid & 15, q = lid >> 4;
    f32x4 acc[4][4] = {};
    for (int k0 = 0; k0 < FH; k0 += 32) {
        float4 va0 = *(const float4*)(a0 + k0 + sq * 8);
        float4 va1 = *(const float4*)(a1 + k0 + sq * 8);
        float4 vb0 = *(const float4*)(b0 + k0 + sq * 8);
        float4 vb1 = *(const float4*)(bq + k0 + sq * 8);
        __syncthreads();
        *(float4*)&As[srow * BSTR + sq * 8] = va0;
        *(float4*)&As[(srow + 64) * BSTR + sq * 8] = va1;
        *(float4*)&Bs[srow * BSTR + sq * 8] = vb0;
        *(float4*)&Bs[(srow + 64) * BSTR + sq * 8] = vb1;
        __syncthreads();
        bf16x8 af[4], bfr[4];
#pragma unroll
        for (int i = 0; i < 4; i++) {
            af[i]  = *(const bf16x8*)&As[(wr + i * 16 + m16) * BSTR + q * 8];
            bfr[i] = *(const bf16x8*)&Bs[(wc + i * 16 + m16) * BSTR + q * 8];
        }
#pragma unroll
        for (int i = 0; i < 4; i++)
#pragma unroll
            for (int j = 0; j < 4; j++)
                acc[i][j] = __builtin_amdgcn_mfma_f32_16x16x32_bf16(af[i], bfr[j], acc[i][j], 0, 0, 0);
    }
#pragma unroll
    for (int i = 0; i < 4; i++) {
#pragma unroll
        for (int r = 0; r < 4; r++) {
            int pos = o + m0 + wr + i * 16 + q * 4 + r;
            if (pos < o + c) {
                int t = list[pos] >> 1;
#pragma unroll
                for (int j = 0; j < 4; j++) {
                    int n = n0 + wc + j * 16 + m16;
                    atomicAdd(out + (size_t)t * D + n, acc[i][j][r]);
                }
            }
        }
    }
}

extern "C" void kernel_launch(void* const* d_in, const int* in_sizes, int n_in,
                              void* d_out, int out_size, void* d_ws, size_t ws_size,
                              hipStream_t stream) {
    const float* src   = (const float*)d_in[0];
    const float* ln1_w = (const float*)d_in[1];
    const float* ln1_b = (const float*)d_in[2];
    const float* ln2_w = (const float*)d_in[3];
    const float* ln2_b = (const float*)d_in[4];
    const float* agw   = (const float*)d_in[5];
    const float* qw    = (const float*)d_in[6];
    const float* qb    = (const float*)d_in[7];
    const float* kw    = (const float*)d_in[8];
    const float* kb    = (const float*)d_in[9];
    const float* vw    = (const float*)d_in[10];
    const float* vb    = (const float*)d_in[11];
    const float* ow    = (const float*)d_in[12];
    const float* ob    = (const float*)d_in[13];
    const float* rel   = (const float*)d_in[14];
    const float* fgw   = (const float*)d_in[15];
    const float* w1    = (const float*)d_in[16];
    const float* b1    = (const float*)d_in[17];
    const float* w2    = (const float*)d_in[18];
    const float* b2    = (const float*)d_in[19];
    float* out = (float*)d_out;

    char* p = (char*)d_ws;
    float* xn1  = (float*)p; p += (size_t)NTOK * D * 4;            // LN1 out; reused as LN2 out
    float* x1   = (float*)p; p += (size_t)NTOK * D * 4;
    float* Sbuf = (float*)p; p += (size_t)(NPAIR + TM) * SEQ * 4;  // scores/P; FFN: [w1t|w2t]
    char*  reg  = p;         p += (size_t)(NPAIR + 64) * FH * 4;   // 16,908,288 B
    float* ctxg = (float*)reg;                                     // attn phase
    float* Qg   = (float*)(reg + (size_t)4352 * 1024);
    float* Rbuf = (float*)(reg + (size_t)8832 * 1024);
    ushort* Hb  = (ushort*)reg;                                    // FFN: (NPAIR+128)*FH bf16 = 8,519,680
    ushort* xnb = (ushort*)(reg + (size_t)8519680);                // 4096*1024 bf16 = 8,388,608 (exact fit)
    ushort* w1t = (ushort*)Sbuf;                                   // 16 MB
    ushort* w2t = (ushort*)((char*)Sbuf + (size_t)16777216);       // 16 MB
    float* kbuf = (float*)p; p += (size_t)NTOK * HD * 4;
    float* vbuf = (float*)p; p += (size_t)NTOK * HD * 4;
    int*   aidx = (int*)p;   p += NPAIR * 4;
    float* aga  = (float*)p; p += NPAIR * 4;
    int*   fidx = (int*)p;   p += NPAIR * 4;
    float* fga  = (float*)p; p += NPAIR * 4;
    int*   ameta = (int*)p;  p += 128 * 4;
    int*   alist = (int*)p;  p += NPAIR * 4;
    int*   fmeta = (int*)p;  p += 64 * 4;
    int*   flist = (int*)p;  p += NPAIR * 4;
    float* xn2  = xn1;

    // ---- attention block ----
    ln_kernel<<<NTOK, 256, 0, stream>>>(src, ln1_w, ln1_b, xn1);
    router_kernel<EA><<<NTOK, 64, 0, stream>>>(xn1, agw, aidx, aga);
    abin_zero<<<1, 128, 0, stream>>>(ameta);
    abin_count<<<NPAIR / 256, 256, 0, stream>>>(aidx, ameta);
    abin_scan<<<1, 64, 0, stream>>>(ameta);
    abin_scatter<<<NPAIR / 256, 256, 0, stream>>>(aidx, ameta, alist);
    {
        dim3 g(NTOK / TM, HD / TN, 2);
        kv_gemm<<<g, 256, 0, stream>>>(xn1, kw, kb, vw, vb, kbuf, vbuf);
    }
    {
        dim3 g(NPAIR / TM, HD / TN, EA);
        q_gemm<<<g, 256, 0, stream>>>(xn1, qw, qb, ameta, alist, Qg);
    }
    rel_kernel<<<NPAIR, 192, 0, stream>>>(Qg, rel, Rbuf);
    {
        dim3 g(48, SEQ / TN, 32);
        s_gemm<<<g, 256, 0, stream>>>(Qg, kbuf, Rbuf, ameta, alist, Sbuf);
    }
    softmax_kernel<<<NPAIR, 256, 0, stream>>>(Sbuf);
    {
        dim3 g(48, HD / TN, 32);
        pv_gemm<<<g, 256, 0, stream>>>(Sbuf, vbuf, ameta, alist, aga, ctxg);
    }
    x1_init_kernel<<<NTOK, 256, 0, stream>>>(src, ob, aidx, aga, x1);
    {
        dim3 g(NPAIR / TM, D / TN, EA);
        o_gemm<<<g, 256, 0, stream>>>(ctxg, ow, ameta, alist, x1);
    }

    // ---- FFN block (bf16 MFMA GEMMs) ----
    ln_kernel<<<NTOK, 256, 0, stream>>>(x1, ln2_w, ln2_b, xn2);
    router_kernel<EF><<<NTOK, 64, 0, stream>>>(xn2, fgw, fidx, fga);
    bin_zero<<<1, 64, 0, stream>>>(fmeta);
    bin_count<<<NPAIR / 256, 256, 0, stream>>>(fidx, fmeta);
    bin_scan<<<1, 64, 0, stream>>>(fmeta);
    bin_scatter<<<NPAIR / 256, 256, 0, stream>>>(fidx, fmeta, flist);
    conv_bf16_kernel<<<NTOK * D / 1024, 256, 0, stream>>>(xn2, xnb);
    convT_kernel<1024, 512><<<dim3(32, 16, 16), 256, 0, stream>>>(w1, w1t);
    convT_kernel<512, 1024><<<dim3(16, 32, 16), 256, 0, stream>>>(w2, w2t);
    out_init_kernel<<<NTOK, 256, 0, stream>>>(x1, b2, fidx, fga, out);
    {
        dim3 g1(NPAIR / 128, FH / 128, EF);
        ffn_mfma1<<<g1, 256, 0, stream>>>(xnb, w1t, b1, fmeta, flist, fga, Hb);
        dim3 g2(NPAIR / 128, D / 128, EF);
        ffn_mfma2<<<g2, 256, 0, stream>>>(Hb, w2t, fmeta, flist, out);
    }
}

// Round 5
// 866.531 us; speedup vs baseline: 5.9743x; 1.4190x over previous
//
#include <hip/hip_runtime.h>

#define D 1024
#define HD 128
#define EA 8
#define EF 16
#define FH 512
#define MAXPOS 64
#define RNUM 129
#define RSTRIDE 132
#define SEQ 1024
#define NTOK 4096
#define NPAIR (NTOK * 2)
#define LN_EPS 1e-5f
#define QSCALE 0.08838834764831845f
#define BSTR 40  // LDS row stride in bf16 elems

typedef __attribute__((ext_vector_type(8))) short bf16x8;
typedef __attribute__((ext_vector_type(4))) float f32x4;
typedef __attribute__((ext_vector_type(8))) unsigned short u16x8;

__device__ inline ushort f2b(float f) {
    union { float f; unsigned u; } v; v.f = f;
    unsigned r = (v.u + 0x7fffu + ((v.u >> 16) & 1u)) >> 16;
    return (ushort)r;
}
__device__ inline float b2f(ushort u) {
    union { unsigned u; float f; } v; v.u = (unsigned)u << 16; return v.f;
}
__device__ inline u16x8 cvt8v(float4 a, float4 b) {
    u16x8 r;
    r[0] = f2b(a.x); r[1] = f2b(a.y); r[2] = f2b(a.z); r[3] = f2b(a.w);
    r[4] = f2b(b.x); r[5] = f2b(b.y); r[6] = f2b(b.z); r[7] = f2b(b.w);
    return r;
}

// ---------------- LayerNorm ----------------
__global__ void ln_kernel(const float* __restrict__ x, const float* __restrict__ w,
                          const float* __restrict__ b, float* __restrict__ y) {
    int row = blockIdx.x;
    const float* xr = x + (size_t)row * D;
    float v[4];
    float s = 0.f, s2 = 0.f;
#pragma unroll
    for (int i = 0; i < 4; i++) {
        v[i] = xr[threadIdx.x + i * 256];
        s += v[i]; s2 += v[i] * v[i];
    }
#pragma unroll
    for (int off = 32; off; off >>= 1) { s += __shfl_down(s, off); s2 += __shfl_down(s2, off); }
    __shared__ float red0[4], red1[4];
    int wave = threadIdx.x >> 6, lane = threadIdx.x & 63;
    if (lane == 0) { red0[wave] = s; red1[wave] = s2; }
    __syncthreads();
    float ts = red0[0] + red0[1] + red0[2] + red0[3];
    float ts2 = red1[0] + red1[1] + red1[2] + red1[3];
    float mu = ts * (1.f / D);
    float var = ts2 * (1.f / D) - mu * mu;
    float inv = rsqrtf(var + LN_EPS);
#pragma unroll
    for (int i = 0; i < 4; i++) {
        int d = threadIdx.x + i * 256;
        y[(size_t)row * D + d] = (v[i] - mu) * inv * w[d] + b[d];
    }
}

// ---------------- Router ----------------
template <int E>
__global__ void router_kernel(const float* __restrict__ xn, const float* __restrict__ gw,
                              int* __restrict__ idx, float* __restrict__ gate) {
    int t = blockIdx.x;
    int lane = threadIdx.x;  // block=64
    float acc[E];
#pragma unroll
    for (int e = 0; e < E; e++) acc[e] = 0.f;
    const float* xr = xn + (size_t)t * D;
    for (int d = lane; d < D; d += 64) {
        float xv = xr[d];
#pragma unroll
        for (int e = 0; e < E; e++) acc[e] += xv * gw[d * E + e];
    }
#pragma unroll
    for (int e = 0; e < E; e++) {
#pragma unroll
        for (int off = 32; off; off >>= 1) acc[e] += __shfl_down(acc[e], off);
    }
    if (lane == 0) {
        float v0 = -1e30f, v1 = -1e30f;
        int i0 = 0, i1 = 0;
#pragma unroll
        for (int e = 0; e < E; e++) {
            float a = acc[e];
            if (a > v0) { v1 = v0; i1 = i0; v0 = a; i0 = e; }
            else if (a > v1) { v1 = a; i1 = e; }
        }
        float g0 = 1.f / (1.f + expf(v1 - v0));
        idx[t * 2] = i0; idx[t * 2 + 1] = i1;
        gate[t * 2] = g0; gate[t * 2 + 1] = 1.f - g0;
    }
}

// ---------------- Attention binning: 32 bins keyed (expert*4 + batch) ----------------
__global__ void abin_zero(int* __restrict__ meta) {
    if (threadIdx.x < 105) meta[threadIdx.x] = 0;
}
__global__ void abin_count(const int* __restrict__ aidx, int* __restrict__ meta) {
    int i = blockIdx.x * 256 + threadIdx.x;
    if (i < NPAIR) {
        int e = aidx[i];
        int b = (i >> 1) >> 10;
        atomicAdd(&meta[e * 4 + b], 1);
    }
}
__global__ void abin_scan(int* __restrict__ meta) {
    if (threadIdx.x == 0 && blockIdx.x == 0) {
        int s = 0;
        for (int bin = 0; bin < 32; bin++) {
            if ((bin & 3) == 0) meta[96 + (bin >> 2)] = s;
            meta[32 + bin] = s; meta[64 + bin] = s; s += meta[bin];
        }
        meta[96 + 8] = s;
    }
}
__global__ void abin_scatter(const int* __restrict__ aidx, int* __restrict__ meta,
                             int* __restrict__ list) {
    int i = blockIdx.x * 256 + threadIdx.x;
    if (i < NPAIR) {
        int e = aidx[i];
        int b = (i >> 1) >> 10;
        int pos = atomicAdd(&meta[64 + e * 4 + b], 1);
        list[pos] = i;
    }
}

// ---------------- FFN binning ----------------
__global__ void bin_zero(int* __restrict__ meta) {
    if (threadIdx.x < 48) meta[threadIdx.x] = 0;
}
__global__ void bin_count(const int* __restrict__ fidx, int* __restrict__ meta) {
    int i = blockIdx.x * 256 + threadIdx.x;
    if (i < NPAIR) atomicAdd(&meta[fidx[i]], 1);
}
__global__ void bin_scan(int* __restrict__ meta) {
    if (threadIdx.x == 0 && blockIdx.x == 0) {
        int s = 0;
        for (int e = 0; e < EF; e++) { meta[16 + e] = s; meta[32 + e] = s; s += meta[e]; }
    }
}
__global__ void bin_scatter(const int* __restrict__ fidx, int* __restrict__ meta,
                            int* __restrict__ list) {
    int i = blockIdx.x * 256 + threadIdx.x;
    if (i < NPAIR) {
        int e = fidx[i];
        int pos = atomicAdd(&meta[32 + e], 1);
        list[pos] = i;
    }
}

// ---------------- transpose-convert [E][R][C] fp32 -> [E][C][R] bf16 ----------------
template <int R, int C>
__global__ void convT_kernel(const float* __restrict__ in, ushort* __restrict__ out) {
    int e = blockIdx.z;
    int r0 = blockIdx.x * 32, c0 = blockIdx.y * 32;
    __shared__ float tile[32][33];
    int tx = threadIdx.x & 31, ty = threadIdx.x >> 5;  // 256 thr
    const float* src = in + (size_t)e * R * C;
#pragma unroll
    for (int i = 0; i < 32; i += 8)
        tile[ty + i][tx] = src[(size_t)(r0 + ty + i) * C + c0 + tx];
    __syncthreads();
    ushort* dst = out + (size_t)e * C * R;
#pragma unroll
    for (int i = 0; i < 32; i += 8)
        dst[(size_t)(c0 + ty + i) * R + r0 + tx] = f2b(tile[tx][ty + i]);
}

__global__ void zero_kernel(float* __restrict__ p) {
    p[(size_t)blockIdx.x * 256 + threadIdx.x] = 0.f;
}

// ---------------- kv: split-K MFMA, z=0:K z=1:V, atomic fp32 out ----------------
__global__ __launch_bounds__(256) void kv_mfma(
    const float* __restrict__ xn, const ushort* __restrict__ kwt,
    const ushort* __restrict__ vwt, float* __restrict__ kbf, float* __restrict__ vbf) {
    const ushort* W = blockIdx.z ? vwt : kwt;
    float* outp = blockIdx.z ? vbf : kbf;
    int m0 = blockIdx.x * 128;
    int kbase = blockIdx.y * 256;
    __shared__ __align__(16) short As[128 * BSTR];
    __shared__ __align__(16) short Bs[128 * BSTR];
    int tid = threadIdx.x, srow = tid >> 2, sq = tid & 3;
    const float* a0 = xn + (size_t)(m0 + srow) * D;
    const float* a1 = a0 + (size_t)64 * D;
    const ushort* b0 = W + (size_t)srow * D;
    const ushort* b1 = W + (size_t)(srow + 64) * D;
    int w = tid >> 6, lid = tid & 63;
    int wr = (w >> 1) * 64, wc = (w & 1) * 64;
    int m16 = lid & 15, q = lid >> 4;
    f32x4 acc[4][4] = {};
    for (int k0 = kbase; k0 < kbase + 256; k0 += 32) {
        float4 va0 = *(const float4*)(a0 + k0 + sq * 8);
        float4 va0b = *(const float4*)(a0 + k0 + sq * 8 + 4);
        float4 va1 = *(const float4*)(a1 + k0 + sq * 8);
        float4 va1b = *(const float4*)(a1 + k0 + sq * 8 + 4);
        float4 vb0 = *(const float4*)(b0 + k0 + sq * 8);
        float4 vb1 = *(const float4*)(b1 + k0 + sq * 8);
        __syncthreads();
        *(u16x8*)&As[srow * BSTR + sq * 8] = cvt8v(va0, va0b);
        *(u16x8*)&As[(srow + 64) * BSTR + sq * 8] = cvt8v(va1, va1b);
        *(float4*)&Bs[srow * BSTR + sq * 8] = vb0;
        *(float4*)&Bs[(srow + 64) * BSTR + sq * 8] = vb1;
        __syncthreads();
        bf16x8 af[4], bfr[4];
#pragma unroll
        for (int i = 0; i < 4; i++) {
            af[i] = *(const bf16x8*)&As[(wr + i * 16 + m16) * BSTR + q * 8];
            bfr[i] = *(const bf16x8*)&Bs[(wc + i * 16 + m16) * BSTR + q * 8];
        }
#pragma unroll
        for (int i = 0; i < 4; i++)
#pragma unroll
            for (int j = 0; j < 4; j++)
                acc[i][j] = __builtin_amdgcn_mfma_f32_16x16x32_bf16(af[i], bfr[j], acc[i][j], 0, 0, 0);
    }
#pragma unroll
    for (int i = 0; i < 4; i++)
#pragma unroll
        for (int r = 0; r < 4; r++) {
            int m = m0 + wr + i * 16 + q * 4 + r;
#pragma unroll
            for (int j = 0; j < 4; j++)
                atomicAdd(outp + (size_t)m * HD + wc + j * 16 + m16, acc[i][j][r]);
        }
}

__global__ void kvbias_kernel(float* __restrict__ kbf, float* __restrict__ vbf,
                              const float* __restrict__ kb, const float* __restrict__ vb) {
    int t = blockIdx.x, tid = threadIdx.x;
    if (tid < HD) kbf[(size_t)t * HD + tid] += kb[tid];
    else vbf[(size_t)t * HD + tid - HD] += vb[tid - HD];
}

// ---------------- q: split-K MFMA, indirect A, atomic fp32 Qf ----------------
__global__ __launch_bounds__(256) void q_mfma(
    const float* __restrict__ xn, const ushort* __restrict__ qwt,
    const int* __restrict__ meta, const int* __restrict__ list, float* __restrict__ Qf) {
    int e = blockIdx.z;
    int o = meta[96 + e], c = meta[97 + e] - o;
    int m0 = blockIdx.x * 128;
    if (m0 >= c) return;
    int kbase = blockIdx.y * 256;
    __shared__ __align__(16) short As[128 * BSTR];
    __shared__ __align__(16) short Bs[128 * BSTR];
    int tid = threadIdx.x, srow = tid >> 2, sq = tid & 3;
    int r0i = o + m0 + srow;      if (r0i > NPAIR - 1) r0i = NPAIR - 1;
    int r1i = o + m0 + srow + 64; if (r1i > NPAIR - 1) r1i = NPAIR - 1;
    const float* a0 = xn + (size_t)(list[r0i] >> 1) * D;
    const float* a1 = xn + (size_t)(list[r1i] >> 1) * D;
    const ushort* b0 = qwt + (size_t)e * HD * D + (size_t)srow * D;
    const ushort* b1 = b0 + (size_t)64 * D;
    int w = tid >> 6, lid = tid & 63;
    int wr = (w >> 1) * 64, wc = (w & 1) * 64;
    int m16 = lid & 15, q = lid >> 4;
    f32x4 acc[4][4] = {};
    for (int k0 = kbase; k0 < kbase + 256; k0 += 32) {
        float4 va0 = *(const float4*)(a0 + k0 + sq * 8);
        float4 va0b = *(const float4*)(a0 + k0 + sq * 8 + 4);
        float4 va1 = *(const float4*)(a1 + k0 + sq * 8);
        float4 va1b = *(const float4*)(a1 + k0 + sq * 8 + 4);
        float4 vb0 = *(const float4*)(b0 + k0 + sq * 8);
        float4 vb1 = *(const float4*)(b1 + k0 + sq * 8);
        __syncthreads();
        *(u16x8*)&As[srow * BSTR + sq * 8] = cvt8v(va0, va0b);
        *(u16x8*)&As[(srow + 64) * BSTR + sq * 8] = cvt8v(va1, va1b);
        *(float4*)&Bs[srow * BSTR + sq * 8] = vb0;
        *(float4*)&Bs[(srow + 64) * BSTR + sq * 8] = vb1;
        __syncthreads();
        bf16x8 af[4], bfr[4];
#pragma unroll
        for (int i = 0; i < 4; i++) {
            af[i] = *(const bf16x8*)&As[(wr + i * 16 + m16) * BSTR + q * 8];
            bfr[i] = *(const bf16x8*)&Bs[(wc + i * 16 + m16) * BSTR + q * 8];
        }
#pragma unroll
        for (int i = 0; i < 4; i++)
#pragma unroll
            for (int j = 0; j < 4; j++)
                acc[i][j] = __builtin_amdgcn_mfma_f32_16x16x32_bf16(af[i], bfr[j], acc[i][j], 0, 0, 0);
    }
#pragma unroll
    for (int i = 0; i < 4; i++)
#pragma unroll
        for (int r = 0; r < 4; r++) {
            int pos = o + m0 + wr + i * 16 + q * 4 + r;
            if (pos < o + c) {
#pragma unroll
                for (int j = 0; j < 4; j++)
                    atomicAdd(Qf + (size_t)pos * HD + wc + j * 16 + m16, acc[i][j][r]);
            }
        }
}

__global__ void qfinal_kernel(const float* __restrict__ Qf, const float* __restrict__ qb,
                              const int* __restrict__ aidx, const int* __restrict__ list,
                              ushort* __restrict__ Qg) {
    int pos = blockIdx.x;
    int e = aidx[list[pos]];
    int h = threadIdx.x;  // 128
    Qg[(size_t)pos * HD + h] = f2b((Qf[(size_t)pos * HD + h] + qb[e * HD + h]) * QSCALE);
}

// ---------------- Rel-pos dots (bf16 Q) ----------------
__global__ void rel_kernel(const ushort* __restrict__ Qg, const float* __restrict__ rel,
                           float* __restrict__ R) {
    int pos = blockIdx.x;
    __shared__ float qsh[HD];
    if (threadIdx.x < HD) qsh[threadIdx.x] = b2f(Qg[(size_t)pos * HD + threadIdx.x]);
    __syncthreads();
    int r = threadIdx.x;
    if (r < RNUM) {
        const float4* rr = (const float4*)(rel + r * HD);
        const float4* qv = (const float4*)qsh;
        float a = 0.f;
#pragma unroll
        for (int h4 = 0; h4 < HD / 4; h4++) {
            float4 rv = rr[h4], qa = qv[h4];
            a += qa.x * rv.x + qa.y * rv.y + qa.z * rv.z + qa.w * rv.w;
        }
        R[(size_t)pos * RSTRIDE + r] = a;
    }
}

// ---------------- s: MFMA QK^T + rel bias, fp32 S out ----------------
__global__ __launch_bounds__(256) void s_mfma(
    const ushort* __restrict__ Qg, const float* __restrict__ kbf,
    const float* __restrict__ R, const int* __restrict__ meta,
    const int* __restrict__ list, float* __restrict__ S) {
    int bin = blockIdx.z;
    int o = meta[32 + bin], c = meta[bin];
    int m0 = blockIdx.x * 128;
    if (m0 >= c) return;
    int b = bin & 3;
    int n0 = blockIdx.y * 128;
    const float* kbase = kbf + (size_t)b * SEQ * HD;
    __shared__ __align__(16) short As[128 * BSTR];
    __shared__ __align__(16) short Bs[128 * BSTR];
    int tid = threadIdx.x, srow = tid >> 2, sq = tid & 3;
    const ushort* a0 = Qg + (size_t)(o + m0 + srow) * HD;
    const ushort* a1 = a0 + (size_t)64 * HD;
    const float* b0 = kbase + (size_t)(n0 + srow) * HD;
    const float* b1 = b0 + (size_t)64 * HD;
    int w = tid >> 6, lid = tid & 63;
    int wr = (w >> 1) * 64, wc = (w & 1) * 64;
    int m16 = lid & 15, q = lid >> 4;
    f32x4 acc[4][4] = {};
    for (int k0 = 0; k0 < HD; k0 += 32) {
        float4 va0 = *(const float4*)(a0 + k0 + sq * 8);
        float4 va1 = *(const float4*)(a1 + k0 + sq * 8);
        float4 vb0 = *(const float4*)(b0 + k0 + sq * 8);
        float4 vb0b = *(const float4*)(b0 + k0 + sq * 8 + 4);
        float4 vb1 = *(const float4*)(b1 + k0 + sq * 8);
        float4 vb1b = *(const float4*)(b1 + k0 + sq * 8 + 4);
        __syncthreads();
        *(float4*)&As[srow * BSTR + sq * 8] = va0;
        *(float4*)&As[(srow + 64) * BSTR + sq * 8] = va1;
        *(u16x8*)&Bs[srow * BSTR + sq * 8] = cvt8v(vb0, vb0b);
        *(u16x8*)&Bs[(srow + 64) * BSTR + sq * 8] = cvt8v(vb1, vb1b);
        __syncthreads();
        bf16x8 af[4], bfr[4];
#pragma unroll
        for (int i = 0; i < 4; i++) {
            af[i] = *(const bf16x8*)&As[(wr + i * 16 + m16) * BSTR + q * 8];
            bfr[i] = *(const bf16x8*)&Bs[(wc + i * 16 + m16) * BSTR + q * 8];
        }
#pragma unroll
        for (int i = 0; i < 4; i++)
#pragma unroll
            for (int j = 0; j < 4; j++)
                acc[i][j] = __builtin_amdgcn_mfma_f32_16x16x32_bf16(af[i], bfr[j], acc[i][j], 0, 0, 0);
    }
#pragma unroll
    for (int i = 0; i < 4; i++)
#pragma unroll
        for (int r = 0; r < 4; r++) {
            int pos = o + m0 + wr + i * 16 + q * 4 + r;
            if (pos < o + c) {
                int qpos = (list[pos] >> 1) & (SEQ - 1);
                const float* Rrow = R + (size_t)pos * RSTRIDE;
                float* sr = S + (size_t)pos * SEQ;
#pragma unroll
                for (int j = 0; j < 4; j++) {
                    int key = n0 + wc + j * 16 + m16;
                    int ri = key - qpos;
                    ri = (ri < -MAXPOS ? -MAXPOS : (ri > MAXPOS ? MAXPOS : ri)) + MAXPOS;
                    sr[key] = acc[i][j][r] + Rrow[ri];
                }
            }
        }
}

// ---------------- Row softmax (fp32 in place) ----------------
__global__ __launch_bounds__(256) void softmax_kernel(float* __restrict__ S) {
    int row = blockIdx.x;
    float4* sr = (float4*)(S + (size_t)row * SEQ);
    float4 v = sr[threadIdx.x];
    float m = fmaxf(fmaxf(v.x, v.y), fmaxf(v.z, v.w));
#pragma unroll
    for (int off = 32; off; off >>= 1) m = fmaxf(m, __shfl_down(m, off));
    __shared__ float red0[4], red1[4];
    int wave = threadIdx.x >> 6, lane = threadIdx.x & 63;
    if (lane == 0) red0[wave] = m;
    __syncthreads();
    m = fmaxf(fmaxf(red0[0], red0[1]), fmaxf(red0[2], red0[3]));
    v.x = __expf(v.x - m); v.y = __expf(v.y - m);
    v.z = __expf(v.z - m); v.w = __expf(v.w - m);
    float s = v.x + v.y + v.z + v.w;
#pragma unroll
    for (int off = 32; off; off >>= 1) s += __shfl_down(s, off);
    if (lane == 0) red1[wave] = s;
    __syncthreads();
    float inv = 1.f / (red1[0] + red1[1] + red1[2] + red1[3]);
    v.x *= inv; v.y *= inv; v.z *= inv; v.w *= inv;
    sr[threadIdx.x] = v;
}

// ---------------- pv: split-K MFMA P@V, atomic fp32 ctxf ----------------
__global__ __launch_bounds__(256) void pv_mfma(
    const float* __restrict__ S, const ushort* __restrict__ vt16,
    const int* __restrict__ meta, const int* __restrict__ list, float* __restrict__ ctxf) {
    int bin = blockIdx.z;
    int o = meta[32 + bin], c = meta[bin];
    int m0 = blockIdx.x * 128;
    if (m0 >= c) return;
    int b = bin & 3;
    int kbase = blockIdx.y * 256;
    __shared__ __align__(16) short As[128 * BSTR];
    __shared__ __align__(16) short Bs[128 * BSTR];
    int tid = threadIdx.x, srow = tid >> 2, sq = tid & 3;
    const float* a0 = S + (size_t)(o + m0 + srow) * SEQ;
    const float* a1 = a0 + (size_t)64 * SEQ;
    const ushort* b0 = vt16 + (size_t)b * HD * SEQ + (size_t)srow * SEQ;
    const ushort* b1 = b0 + (size_t)64 * SEQ;
    int w = tid >> 6, lid = tid & 63;
    int wr = (w >> 1) * 64, wc = (w & 1) * 64;
    int m16 = lid & 15, q = lid >> 4;
    f32x4 acc[4][4] = {};
    for (int k0 = kbase; k0 < kbase + 256; k0 += 32) {
        float4 va0 = *(const float4*)(a0 + k0 + sq * 8);
        float4 va0b = *(const float4*)(a0 + k0 + sq * 8 + 4);
        float4 va1 = *(const float4*)(a1 + k0 + sq * 8);
        float4 va1b = *(const float4*)(a1 + k0 + sq * 8 + 4);
        float4 vb0 = *(const float4*)(b0 + k0 + sq * 8);
        float4 vb1 = *(const float4*)(b1 + k0 + sq * 8);
        __syncthreads();
        *(u16x8*)&As[srow * BSTR + sq * 8] = cvt8v(va0, va0b);
        *(u16x8*)&As[(srow + 64) * BSTR + sq * 8] = cvt8v(va1, va1b);
        *(float4*)&Bs[srow * BSTR + sq * 8] = vb0;
        *(float4*)&Bs[(srow + 64) * BSTR + sq * 8] = vb1;
        __syncthreads();
        bf16x8 af[4], bfr[4];
#pragma unroll
        for (int i = 0; i < 4; i++) {
            af[i] = *(const bf16x8*)&As[(wr + i * 16 + m16) * BSTR + q * 8];
            bfr[i] = *(const bf16x8*)&Bs[(wc + i * 16 + m16) * BSTR + q * 8];
        }
#pragma unroll
        for (int i = 0; i < 4; i++)
#pragma unroll
            for (int j = 0; j < 4; j++)
                acc[i][j] = __builtin_amdgcn_mfma_f32_16x16x32_bf16(af[i], bfr[j], acc[i][j], 0, 0, 0);
    }
#pragma unroll
    for (int i = 0; i < 4; i++)
#pragma unroll
        for (int r = 0; r < 4; r++) {
            int pos = o + m0 + wr + i * 16 + q * 4 + r;
            if (pos < o + c) {
#pragma unroll
                for (int j = 0; j < 4; j++)
                    atomicAdd(ctxf + (size_t)pos * HD + wc + j * 16 + m16, acc[i][j][r]);
            }
        }
}

__global__ void ctxgate_kernel(float* __restrict__ ctxf, const float* __restrict__ aga,
                               const int* __restrict__ list) {
    int pos = blockIdx.x;
    float g = aga[list[pos]];
    ctxf[(size_t)pos * HD + threadIdx.x] *= g;
}

// ---------------- x1 init: src + gated o_b ----------------
__global__ void x1_init_kernel(const float* __restrict__ src, const float* __restrict__ ob,
                               const int* __restrict__ aidx, const float* __restrict__ aga,
                               float* __restrict__ x1) {
    int t = blockIdx.x;
    int tid = threadIdx.x;
    int e0 = aidx[t * 2], e1 = aidx[t * 2 + 1];
    float g0 = aga[t * 2], g1 = aga[t * 2 + 1];
#pragma unroll
    for (int i = 0; i < 4; i++) {
        int d = tid + i * 256;
        x1[(size_t)t * D + d] = src[(size_t)t * D + d]
                              + g0 * ob[e0 * D + d] + g1 * ob[e1 * D + d];
    }
}

// ---------------- o: MFMA ctx@o_w, atomic scatter into x1 ----------------
__global__ __launch_bounds__(256) void o_mfma(
    const float* __restrict__ ctxf, const ushort* __restrict__ owt,
    const int* __restrict__ meta, const int* __restrict__ list, float* __restrict__ x1) {
    int e = blockIdx.z;
    int o = meta[96 + e], c = meta[97 + e] - o;
    int m0 = blockIdx.x * 128;
    if (m0 >= c) return;
    int n0 = blockIdx.y * 128;
    __shared__ __align__(16) short As[128 * BSTR];
    __shared__ __align__(16) short Bs[128 * BSTR];
    int tid = threadIdx.x, srow = tid >> 2, sq = tid & 3;
    const float* a0 = ctxf + (size_t)(o + m0 + srow) * HD;
    const float* a1 = a0 + (size_t)64 * HD;
    const ushort* b0 = owt + (size_t)e * D * HD + (size_t)(n0 + srow) * HD;
    const ushort* b1 = b0 + (size_t)64 * HD;
    int w = tid >> 6, lid = tid & 63;
    int wr = (w >> 1) * 64, wc = (w & 1) * 64;
    int m16 = lid & 15, q = lid >> 4;
    f32x4 acc[4][4] = {};
    for (int k0 = 0; k0 < HD; k0 += 32) {
        float4 va0 = *(const float4*)(a0 + k0 + sq * 8);
        float4 va0b = *(const float4*)(a0 + k0 + sq * 8 + 4);
        float4 va1 = *(const float4*)(a1 + k0 + sq * 8);
        float4 va1b = *(const float4*)(a1 + k0 + sq * 8 + 4);
        float4 vb0 = *(const float4*)(b0 + k0 + sq * 8);
        float4 vb1 = *(const float4*)(b1 + k0 + sq * 8);
        __syncthreads();
        *(u16x8*)&As[srow * BSTR + sq * 8] = cvt8v(va0, va0b);
        *(u16x8*)&As[(srow + 64) * BSTR + sq * 8] = cvt8v(va1, va1b);
        *(float4*)&Bs[srow * BSTR + sq * 8] = vb0;
        *(float4*)&Bs[(srow + 64) * BSTR + sq * 8] = vb1;
        __syncthreads();
        bf16x8 af[4], bfr[4];
#pragma unroll
        for (int i = 0; i < 4; i++) {
            af[i] = *(const bf16x8*)&As[(wr + i * 16 + m16) * BSTR + q * 8];
            bfr[i] = *(const bf16x8*)&Bs[(wc + i * 16 + m16) * BSTR + q * 8];
        }
#pragma unroll
        for (int i = 0; i < 4; i++)
#pragma unroll
            for (int j = 0; j < 4; j++)
                acc[i][j] = __builtin_amdgcn_mfma_f32_16x16x32_bf16(af[i], bfr[j], acc[i][j], 0, 0, 0);
    }
#pragma unroll
    for (int i = 0; i < 4; i++)
#pragma unroll
        for (int r = 0; r < 4; r++) {
            int pos = o + m0 + wr + i * 16 + q * 4 + r;
            if (pos < o + c) {
                int t = list[pos] >> 1;
#pragma unroll
                for (int j = 0; j < 4; j++)
                    atomicAdd(x1 + (size_t)t * D + n0 + wc + j * 16 + m16, acc[i][j][r]);
            }
        }
}

__global__ void out_init_kernel(const float* __restrict__ x1, const float* __restrict__ b2,
                                const int* __restrict__ fidx, const float* __restrict__ fga,
                                float* __restrict__ out) {
    int t = blockIdx.x;
    int tid = threadIdx.x;
    int e0 = fidx[t * 2], e1 = fidx[t * 2 + 1];
    float g0 = fga[t * 2], g1 = fga[t * 2 + 1];
#pragma unroll
    for (int i = 0; i < 4; i++) {
        int d = tid + i * 256;
        out[(size_t)t * D + d] = x1[(size_t)t * D + d]
                               + g0 * b2[e0 * D + d] + g1 * b2[e1 * D + d];
    }
}

// ---------------- FFN GEMM1: Hb = g*relu(xn2 @ W1 + b1), stage-convert A ----------------
__global__ __launch_bounds__(256) void ffn_mfma1(
    const float* __restrict__ xn2, const ushort* __restrict__ w1t,
    const float* __restrict__ b1, const int* __restrict__ meta,
    const int* __restrict__ list, const float* __restrict__ fga,
    ushort* __restrict__ Hb) {
    int e = blockIdx.z;
    int o = meta[16 + e], c = meta[e];
    int m0 = blockIdx.x * 128;
    if (m0 >= c) return;
    int n0 = blockIdx.y * 128;
    __shared__ __align__(16) short As[128 * BSTR];
    __shared__ __align__(16) short Bs[128 * BSTR];
    int tid = threadIdx.x, srow = tid >> 2, sq = tid & 3;
    int r0i = o + m0 + srow;      if (r0i > NPAIR - 1) r0i = NPAIR - 1;
    int r1i = o + m0 + srow + 64; if (r1i > NPAIR - 1) r1i = NPAIR - 1;
    const float* a0 = xn2 + (size_t)(list[r0i] >> 1) * D;
    const float* a1 = xn2 + (size_t)(list[r1i] >> 1) * D;
    const ushort* b0 = w1t + ((size_t)e * FH + n0 + srow) * D;
    const ushort* b1p = w1t + ((size_t)e * FH + n0 + srow + 64) * D;
    int w = tid >> 6, lid = tid & 63;
    int wr = (w >> 1) * 64, wc = (w & 1) * 64;
    int m16 = lid & 15, q = lid >> 4;
    f32x4 acc[4][4] = {};
    for (int k0 = 0; k0 < D; k0 += 32) {
        float4 va0 = *(const float4*)(a0 + k0 + sq * 8);
        float4 va0b = *(const float4*)(a0 + k0 + sq * 8 + 4);
        float4 va1 = *(const float4*)(a1 + k0 + sq * 8);
        float4 va1b = *(const float4*)(a1 + k0 + sq * 8 + 4);
        float4 vb0 = *(const float4*)(b0 + k0 + sq * 8);
        float4 vb1 = *(const float4*)(b1p + k0 + sq * 8);
        __syncthreads();
        *(u16x8*)&As[srow * BSTR + sq * 8] = cvt8v(va0, va0b);
        *(u16x8*)&As[(srow + 64) * BSTR + sq * 8] = cvt8v(va1, va1b);
        *(float4*)&Bs[srow * BSTR + sq * 8] = vb0;
        *(float4*)&Bs[(srow + 64) * BSTR + sq * 8] = vb1;
        __syncthreads();
        bf16x8 af[4], bfr[4];
#pragma unroll
        for (int i = 0; i < 4; i++) {
            af[i] = *(const bf16x8*)&As[(wr + i * 16 + m16) * BSTR + q * 8];
            bfr[i] = *(const bf16x8*)&Bs[(wc + i * 16 + m16) * BSTR + q * 8];
        }
#pragma unroll
        for (int i = 0; i < 4; i++)
#pragma unroll
            for (int j = 0; j < 4; j++)
                acc[i][j] = __builtin_amdgcn_mfma_f32_16x16x32_bf16(af[i], bfr[j], acc[i][j], 0, 0, 0);
    }
#pragma unroll
    for (int i = 0; i < 4; i++)
#pragma unroll
        for (int r = 0; r < 4; r++) {
            int pos = o + m0 + wr + i * 16 + q * 4 + r;
            if (pos < o + c) {
                float g = fga[list[pos]];
#pragma unroll
                for (int j = 0; j < 4; j++) {
                    int n = n0 + wc + j * 16 + m16;
                    Hb[(size_t)pos * FH + n] = f2b(g * fmaxf(acc[i][j][r] + b1[e * FH + n], 0.f));
                }
            }
        }
}

// ---------------- FFN GEMM2: out += Hb @ W2 (atomic scatter) ----------------
__global__ __launch_bounds__(256) void ffn_mfma2(
    const ushort* __restrict__ Hb, const ushort* __restrict__ w2t,
    const int* __restrict__ meta, const int* __restrict__ list,
    float* __restrict__ out) {
    int e = blockIdx.z;
    int o = meta[16 + e], c = meta[e];
    int m0 = blockIdx.x * 128;
    if (m0 >= c) return;
    int n0 = blockIdx.y * 128;
    __shared__ __align__(16) short As[128 * BSTR];
    __shared__ __align__(16) short Bs[128 * BSTR];
    int tid = threadIdx.x, srow = tid >> 2, sq = tid & 3;
    const ushort* a0 = Hb + (size_t)(o + m0 + srow) * FH;
    const ushort* a1 = a0 + (size_t)64 * FH;
    const ushort* b0 = w2t + ((size_t)e * D + n0 + srow) * FH;
    const ushort* b1 = w2t + ((size_t)e * D + n0 + srow + 64) * FH;
    int w = tid >> 6, lid = tid & 63;
    int wr = (w >> 1) * 64, wc = (w & 1) * 64;
    int m16 = lid & 15, q = lid >> 4;
    f32x4 acc[4][4] = {};
    for (int k0 = 0; k0 < FH; k0 += 32) {
        float4 va0 = *(const float4*)(a0 + k0 + sq * 8);
        float4 va1 = *(const float4*)(a1 + k0 + sq * 8);
        float4 vb0 = *(const float4*)(b0 + k0 + sq * 8);
        float4 vb1 = *(const float4*)(b1 + k0 + sq * 8);
        __syncthreads();
        *(float4*)&As[srow * BSTR + sq * 8] = va0;
        *(float4*)&As[(srow + 64) * BSTR + sq * 8] = va1;
        *(float4*)&Bs[srow * BSTR + sq * 8] = vb0;
        *(float4*)&Bs[(srow + 64) * BSTR + sq * 8] = vb1;
        __syncthreads();
        bf16x8 af[4], bfr[4];
#pragma unroll
        for (int i = 0; i < 4; i++) {
            af[i] = *(const bf16x8*)&As[(wr + i * 16 + m16) * BSTR + q * 8];
            bfr[i] = *(const bf16x8*)&Bs[(wc + i * 16 + m16) * BSTR + q * 8];
        }
#pragma unroll
        for (int i = 0; i < 4; i++)
#pragma unroll
            for (int j = 0; j < 4; j++)
                acc[i][j] = __builtin_amdgcn_mfma_f32_16x16x32_bf16(af[i], bfr[j], acc[i][j], 0, 0, 0);
    }
#pragma unroll
    for (int i = 0; i < 4; i++)
#pragma unroll
        for (int r = 0; r < 4; r++) {
            int pos = o + m0 + wr + i * 16 + q * 4 + r;
            if (pos < o + c) {
                int t = list[pos] >> 1;
#pragma unroll
                for (int j = 0; j < 4; j++)
                    atomicAdd(out + (size_t)t * D + n0 + wc + j * 16 + m16, acc[i][j][r]);
            }
        }
}

extern "C" void kernel_launch(void* const* d_in, const int* in_sizes, int n_in,
                              void* d_out, int out_size, void* d_ws, size_t ws_size,
                              hipStream_t stream) {
    const float* src   = (const float*)d_in[0];
    const float* ln1_w = (const float*)d_in[1];
    const float* ln1_b = (const float*)d_in[2];
    const float* ln2_w = (const float*)d_in[3];
    const float* ln2_b = (const float*)d_in[4];
    const float* agw   = (const float*)d_in[5];
    const float* qw    = (const float*)d_in[6];
    const float* qb    = (const float*)d_in[7];
    const float* kw    = (const float*)d_in[8];
    const float* kb    = (const float*)d_in[9];
    const float* vw    = (const float*)d_in[10];
    const float* vb    = (const float*)d_in[11];
    const float* ow    = (const float*)d_in[12];
    const float* ob    = (const float*)d_in[13];
    const float* rel   = (const float*)d_in[14];
    const float* fgw   = (const float*)d_in[15];
    const float* w1    = (const float*)d_in[16];
    const float* b1    = (const float*)d_in[17];
    const float* w2    = (const float*)d_in[18];
    const float* b2    = (const float*)d_in[19];
    float* out = (float*)d_out;

    char* p = (char*)d_ws;
    float* xn1  = (float*)p; p += (size_t)NTOK * D * 4;               // LN out (both LNs)
    float* x1   = (float*)p; p += (size_t)NTOK * D * 4;
    float* Sbuf = (float*)p; p += (size_t)(NPAIR + 128) * SEQ * 4;    // S; FFN: w1t|w2t
    char*  reg  = p;
    float*  pf   = (float*)reg;                                        // Qf then ctxf (8320*128 f32)
    ushort* Qg   = (ushort*)(reg + (size_t)8320 * 128 * 4);            // bf16 Q
    float*  Rbuf = (float*)(reg + (size_t)8320 * 128 * 6);             // rel dots
    ushort* Hb   = (ushort*)reg;                                       // FFN hidden (8320*512 bf16)
    p = reg + (size_t)8320 * 128 * 6 + (size_t)NPAIR * RSTRIDE * 4;
    float* kbf  = (float*)p; p += (size_t)NTOK * HD * 4;
    float* vbf  = (float*)p; p += (size_t)NTOK * HD * 4;
    ushort* vt16 = (ushort*)p; p += (size_t)NTOK * HD * 2;
    ushort* kwt = (ushort*)p; p += (size_t)HD * D * 2;
    ushort* vwt = (ushort*)p; p += (size_t)HD * D * 2;
    ushort* qwt = (ushort*)p; p += (size_t)EA * HD * D * 2;
    ushort* owt = (ushort*)p; p += (size_t)EA * D * HD * 2;
    int*   aidx = (int*)p;   p += NPAIR * 4;
    float* aga  = (float*)p; p += NPAIR * 4;
    int*   fidx = (int*)p;   p += NPAIR * 4;
    float* fga  = (float*)p; p += NPAIR * 4;
    int*   ameta = (int*)p;  p += 128 * 4;
    int*   alist = (int*)p;  p += NPAIR * 4;
    int*   fmeta = (int*)p;  p += 64 * 4;
    int*   flist = (int*)p;  p += NPAIR * 4;
    ushort* w1t = (ushort*)Sbuf;
    ushort* w2t = (ushort*)((char*)Sbuf + (size_t)16777216);
    float* xn2 = xn1;

    // ---- attention ----
    ln_kernel<<<NTOK, 256, 0, stream>>>(src, ln1_w, ln1_b, xn1);
    router_kernel<EA><<<NTOK, 64, 0, stream>>>(xn1, agw, aidx, aga);
    abin_zero<<<1, 128, 0, stream>>>(ameta);
    abin_count<<<NPAIR / 256, 256, 0, stream>>>(aidx, ameta);
    abin_scan<<<1, 64, 0, stream>>>(ameta);
    abin_scatter<<<NPAIR / 256, 256, 0, stream>>>(aidx, ameta, alist);
    convT_kernel<1024, 128><<<dim3(32, 4, 1), 256, 0, stream>>>(kw, kwt);
    convT_kernel<1024, 128><<<dim3(32, 4, 1), 256, 0, stream>>>(vw, vwt);
    convT_kernel<1024, 128><<<dim3(32, 4, EA), 256, 0, stream>>>(qw, qwt);
    convT_kernel<128, 1024><<<dim3(4, 32, EA), 256, 0, stream>>>(ow, owt);
    zero_kernel<<<NTOK * HD / 256, 256, 0, stream>>>(kbf);
    zero_kernel<<<NTOK * HD / 256, 256, 0, stream>>>(vbf);
    kv_mfma<<<dim3(NTOK / 128, 4, 2), 256, 0, stream>>>(xn1, kwt, vwt, kbf, vbf);
    kvbias_kernel<<<NTOK, 256, 0, stream>>>(kbf, vbf, kb, vb);
    convT_kernel<1024, 128><<<dim3(32, 4, 4), 256, 0, stream>>>(vbf, vt16);
    zero_kernel<<<8320 * 128 / 256, 256, 0, stream>>>(pf);             // Qf
    q_mfma<<<dim3(32, 4, EA), 256, 0, stream>>>(xn1, qwt, ameta, alist, pf);
    qfinal_kernel<<<NPAIR, 128, 0, stream>>>(pf, qb, aidx, alist, Qg);
    rel_kernel<<<NPAIR, 192, 0, stream>>>(Qg, rel, Rbuf);
    zero_kernel<<<8320 * 128 / 256, 256, 0, stream>>>(pf);             // ctxf
    s_mfma<<<dim3(8, 8, 32), 256, 0, stream>>>(Qg, kbf, Rbuf, ameta, alist, Sbuf);
    softmax_kernel<<<NPAIR, 256, 0, stream>>>(Sbuf);
    pv_mfma<<<dim3(8, 4, 32), 256, 0, stream>>>(Sbuf, vt16, ameta, alist, pf);
    ctxgate_kernel<<<NPAIR, 128, 0, stream>>>(pf, aga, alist);
    x1_init_kernel<<<NTOK, 256, 0, stream>>>(src, ob, aidx, aga, x1);
    o_mfma<<<dim3(32, 8, EA), 256, 0, stream>>>(pf, owt, ameta, alist, x1);

    // ---- FFN ----
    ln_kernel<<<NTOK, 256, 0, stream>>>(x1, ln2_w, ln2_b, xn2);
    router_kernel<EF><<<NTOK, 64, 0, stream>>>(xn2, fgw, fidx, fga);
    bin_zero<<<1, 64, 0, stream>>>(fmeta);
    bin_count<<<NPAIR / 256, 256, 0, stream>>>(fidx, fmeta);
    bin_scan<<<1, 64, 0, stream>>>(fmeta);
    bin_scatter<<<NPAIR / 256, 256, 0, stream>>>(fidx, fmeta, flist);
    convT_kernel<1024, 512><<<dim3(32, 16, EF), 256, 0, stream>>>(w1, w1t);
    convT_kernel<512, 1024><<<dim3(16, 32, EF), 256, 0, stream>>>(w2, w2t);
    out_init_kernel<<<NTOK, 256, 0, stream>>>(x1, b2, fidx, fga, out);
    ffn_mfma1<<<dim3(32, FH / 128, EF), 256, 0, stream>>>(xn2, w1t, b1, fmeta, flist, fga, Hb);
    ffn_mfma2<<<dim3(32, D / 128, EF), 256, 0, stream>>>(Hb, w2t, fmeta, flist, out);
}

// Round 6
// 778.210 us; speedup vs baseline: 6.6523x; 1.1135x over previous
//
#include <hip/hip_runtime.h>

#define D 1024
#define HD 128
#define EA 8
#define EF 16
#define FH 512
#define MAXPOS 64
#define RNUM 129
#define RSTRIDE 132
#define SEQ 1024
#define NTOK 4096
#define NPAIR (NTOK * 2)
#define NPAD 8320          // NPAIR + 128 slack
#define LN_EPS 1e-5f
#define QSCALE 0.08838834764831845f
#define BSTR 40            // LDS row stride in bf16 elems

typedef __attribute__((ext_vector_type(8))) short bf16x8;
typedef __attribute__((ext_vector_type(4))) float f32x4;
typedef __attribute__((ext_vector_type(8))) unsigned short u16x8;

__device__ inline ushort f2b(float f) {
    union { float f; unsigned u; } v; v.f = f;
    unsigned r = (v.u + 0x7fffu + ((v.u >> 16) & 1u)) >> 16;
    return (ushort)r;
}
__device__ inline float b2f(ushort u) {
    union { unsigned u; float f; } v; v.u = (unsigned)u << 16; return v.f;
}
__device__ inline u16x8 cvt8v(float4 a, float4 b) {
    u16x8 r;
    r[0] = f2b(a.x); r[1] = f2b(a.y); r[2] = f2b(a.z); r[3] = f2b(a.w);
    r[4] = f2b(b.x); r[5] = f2b(b.y); r[6] = f2b(b.z); r[7] = f2b(b.w);
    return r;
}

// ---------------- LayerNorm ----------------
__global__ void ln_kernel(const float* __restrict__ x, const float* __restrict__ w,
                          const float* __restrict__ b, float* __restrict__ y) {
    int row = blockIdx.x;
    const float* xr = x + (size_t)row * D;
    float v[4];
    float s = 0.f, s2 = 0.f;
#pragma unroll
    for (int i = 0; i < 4; i++) {
        v[i] = xr[threadIdx.x + i * 256];
        s += v[i]; s2 += v[i] * v[i];
    }
#pragma unroll
    for (int off = 32; off; off >>= 1) { s += __shfl_down(s, off); s2 += __shfl_down(s2, off); }
    __shared__ float red0[4], red1[4];
    int wave = threadIdx.x >> 6, lane = threadIdx.x & 63;
    if (lane == 0) { red0[wave] = s; red1[wave] = s2; }
    __syncthreads();
    float ts = red0[0] + red0[1] + red0[2] + red0[3];
    float ts2 = red1[0] + red1[1] + red1[2] + red1[3];
    float mu = ts * (1.f / D);
    float var = ts2 * (1.f / D) - mu * mu;
    float inv = rsqrtf(var + LN_EPS);
#pragma unroll
    for (int i = 0; i < 4; i++) {
        int d = threadIdx.x + i * 256;
        y[(size_t)row * D + d] = (v[i] - mu) * inv * w[d] + b[d];
    }
}

// ---------------- Router ----------------
template <int E>
__global__ void router_kernel(const float* __restrict__ xn, const float* __restrict__ gw,
                              int* __restrict__ idx, float* __restrict__ gate) {
    int t = blockIdx.x;
    int lane = threadIdx.x;  // block=64
    float acc[E];
#pragma unroll
    for (int e = 0; e < E; e++) acc[e] = 0.f;
    const float* xr = xn + (size_t)t * D;
    for (int d = lane; d < D; d += 64) {
        float xv = xr[d];
#pragma unroll
        for (int e = 0; e < E; e++) acc[e] += xv * gw[d * E + e];
    }
#pragma unroll
    for (int e = 0; e < E; e++) {
#pragma unroll
        for (int off = 32; off; off >>= 1) acc[e] += __shfl_down(acc[e], off);
    }
    if (lane == 0) {
        float v0 = -1e30f, v1 = -1e30f;
        int i0 = 0, i1 = 0;
#pragma unroll
        for (int e = 0; e < E; e++) {
            float a = acc[e];
            if (a > v0) { v1 = v0; i1 = i0; v0 = a; i0 = e; }
            else if (a > v1) { v1 = a; i1 = e; }
        }
        float g0 = 1.f / (1.f + expf(v1 - v0));
        idx[t * 2] = i0; idx[t * 2 + 1] = i1;
        gate[t * 2] = g0; gate[t * 2 + 1] = 1.f - g0;
    }
}

// ---------------- Attention binning: 32 bins keyed (expert*4 + batch) ----------------
__global__ void abin_zero(int* __restrict__ meta) {
    if (threadIdx.x < 105) meta[threadIdx.x] = 0;
}
__global__ void abin_count(const int* __restrict__ aidx, int* __restrict__ meta) {
    int i = blockIdx.x * 256 + threadIdx.x;
    if (i < NPAIR) {
        int e = aidx[i];
        int b = (i >> 1) >> 10;
        atomicAdd(&meta[e * 4 + b], 1);
    }
}
__global__ void abin_scan(int* __restrict__ meta) {
    if (threadIdx.x == 0 && blockIdx.x == 0) {
        int s = 0;
        for (int bin = 0; bin < 32; bin++) {
            if ((bin & 3) == 0) meta[96 + (bin >> 2)] = s;
            meta[32 + bin] = s; meta[64 + bin] = s; s += meta[bin];
        }
        meta[96 + 8] = s;
    }
}
__global__ void abin_scatter(const int* __restrict__ aidx, int* __restrict__ meta,
                             int* __restrict__ list, int* __restrict__ inv) {
    int i = blockIdx.x * 256 + threadIdx.x;
    if (i < NPAIR) {
        int e = aidx[i];
        int b = (i >> 1) >> 10;
        int pos = atomicAdd(&meta[64 + e * 4 + b], 1);
        list[pos] = i;
        inv[i] = pos;
    }
}

// ---------------- FFN binning ----------------
__global__ void bin_zero(int* __restrict__ meta) {
    if (threadIdx.x < 48) meta[threadIdx.x] = 0;
}
__global__ void bin_count(const int* __restrict__ fidx, int* __restrict__ meta) {
    int i = blockIdx.x * 256 + threadIdx.x;
    if (i < NPAIR) atomicAdd(&meta[fidx[i]], 1);
}
__global__ void bin_scan(int* __restrict__ meta) {
    if (threadIdx.x == 0 && blockIdx.x == 0) {
        int s = 0;
        for (int e = 0; e < EF; e++) { meta[16 + e] = s; meta[32 + e] = s; s += meta[e]; }
    }
}
__global__ void bin_scatter(const int* __restrict__ fidx, int* __restrict__ meta,
                            int* __restrict__ list, int* __restrict__ inv) {
    int i = blockIdx.x * 256 + threadIdx.x;
    if (i < NPAIR) {
        int e = fidx[i];
        int pos = atomicAdd(&meta[32 + e], 1);
        list[pos] = i;
        inv[i] = pos;
    }
}

// ---------------- transpose-convert [E][R][C] fp32 -> [E][C][R] bf16 ----------------
template <int R, int C>
__global__ void convT_kernel(const float* __restrict__ in, ushort* __restrict__ out) {
    int e = blockIdx.z;
    int r0 = blockIdx.x * 32, c0 = blockIdx.y * 32;
    __shared__ float tile[32][33];
    int tx = threadIdx.x & 31, ty = threadIdx.x >> 5;  // 256 thr
    const float* src = in + (size_t)e * R * C;
#pragma unroll
    for (int i = 0; i < 32; i += 8)
        tile[ty + i][tx] = src[(size_t)(r0 + ty + i) * C + c0 + tx];
    __syncthreads();
    ushort* dst = out + (size_t)e * C * R;
#pragma unroll
    for (int i = 0; i < 32; i += 8)
        dst[(size_t)(c0 + ty + i) * R + r0 + tx] = f2b(tile[tx][ty + i]);
}

// ---------------- kv: split-K MFMA, dense per-split partials ----------------
__global__ __launch_bounds__(256) void kv_mfma(
    const float* __restrict__ xn, const ushort* __restrict__ kwt,
    const ushort* __restrict__ vwt, float* __restrict__ kpart, float* __restrict__ vpart) {
    const ushort* W = blockIdx.z ? vwt : kwt;
    float* outp = blockIdx.z ? vpart : kpart;
    int m0 = blockIdx.x * 128;
    int s = blockIdx.y;
    int kbase = s * 256;
    __shared__ __align__(16) short As[128 * BSTR];
    __shared__ __align__(16) short Bs[128 * BSTR];
    int tid = threadIdx.x, srow = tid >> 2, sq = tid & 3;
    const float* a0 = xn + (size_t)(m0 + srow) * D;
    const float* a1 = a0 + (size_t)64 * D;
    const ushort* b0 = W + (size_t)srow * D;
    const ushort* b1 = W + (size_t)(srow + 64) * D;
    int w = tid >> 6, lid = tid & 63;
    int wr = (w >> 1) * 64, wc = (w & 1) * 64;
    int m16 = lid & 15, q = lid >> 4;
    f32x4 acc[4][4] = {};
    for (int k0 = kbase; k0 < kbase + 256; k0 += 32) {
        float4 va0 = *(const float4*)(a0 + k0 + sq * 8);
        float4 va0b = *(const float4*)(a0 + k0 + sq * 8 + 4);
        float4 va1 = *(const float4*)(a1 + k0 + sq * 8);
        float4 va1b = *(const float4*)(a1 + k0 + sq * 8 + 4);
        float4 vb0 = *(const float4*)(b0 + k0 + sq * 8);
        float4 vb1 = *(const float4*)(b1 + k0 + sq * 8);
        __syncthreads();
        *(u16x8*)&As[srow * BSTR + sq * 8] = cvt8v(va0, va0b);
        *(u16x8*)&As[(srow + 64) * BSTR + sq * 8] = cvt8v(va1, va1b);
        *(float4*)&Bs[srow * BSTR + sq * 8] = vb0;
        *(float4*)&Bs[(srow + 64) * BSTR + sq * 8] = vb1;
        __syncthreads();
        bf16x8 af[4], bfr[4];
#pragma unroll
        for (int i = 0; i < 4; i++) {
            af[i] = *(const bf16x8*)&As[(wr + i * 16 + m16) * BSTR + q * 8];
            bfr[i] = *(const bf16x8*)&Bs[(wc + i * 16 + m16) * BSTR + q * 8];
        }
#pragma unroll
        for (int i = 0; i < 4; i++)
#pragma unroll
            for (int j = 0; j < 4; j++)
                acc[i][j] = __builtin_amdgcn_mfma_f32_16x16x32_bf16(af[i], bfr[j], acc[i][j], 0, 0, 0);
    }
#pragma unroll
    for (int i = 0; i < 4; i++)
#pragma unroll
        for (int r = 0; r < 4; r++) {
            int m = m0 + wr + i * 16 + q * 4 + r;
#pragma unroll
            for (int j = 0; j < 4; j++)
                outp[((size_t)s * NTOK + m) * HD + wc + j * 16 + m16] = acc[i][j][r];
        }
}

__global__ void kv_reduce(const float* __restrict__ kpart, const float* __restrict__ vpart,
                          const float* __restrict__ kb, const float* __restrict__ vb,
                          float* __restrict__ kbf, float* __restrict__ vbf) {
    int t = blockIdx.x, h = threadIdx.x;  // 128
    float ka = kb[h], va = vb[h];
#pragma unroll
    for (int s = 0; s < 4; s++) {
        ka += kpart[((size_t)s * NTOK + t) * HD + h];
        va += vpart[((size_t)s * NTOK + t) * HD + h];
    }
    kbf[(size_t)t * HD + h] = ka;
    vbf[(size_t)t * HD + h] = va;
}

// ---------------- q: split-K MFMA, indirect A, dense partials ----------------
__global__ __launch_bounds__(256) void q_mfma(
    const float* __restrict__ xn, const ushort* __restrict__ qwt,
    const int* __restrict__ meta, const int* __restrict__ list, float* __restrict__ qpart) {
    int e = blockIdx.z;
    int o = meta[96 + e], c = meta[97 + e] - o;
    int m0 = blockIdx.x * 128;
    if (m0 >= c) return;
    int s = blockIdx.y;
    int kbase = s * 256;
    __shared__ __align__(16) short As[128 * BSTR];
    __shared__ __align__(16) short Bs[128 * BSTR];
    int tid = threadIdx.x, srow = tid >> 2, sq = tid & 3;
    int r0i = o + m0 + srow;      if (r0i > NPAIR - 1) r0i = NPAIR - 1;
    int r1i = o + m0 + srow + 64; if (r1i > NPAIR - 1) r1i = NPAIR - 1;
    const float* a0 = xn + (size_t)(list[r0i] >> 1) * D;
    const float* a1 = xn + (size_t)(list[r1i] >> 1) * D;
    const ushort* b0 = qwt + (size_t)e * HD * D + (size_t)srow * D;
    const ushort* b1 = b0 + (size_t)64 * D;
    int w = tid >> 6, lid = tid & 63;
    int wr = (w >> 1) * 64, wc = (w & 1) * 64;
    int m16 = lid & 15, q = lid >> 4;
    f32x4 acc[4][4] = {};
    for (int k0 = kbase; k0 < kbase + 256; k0 += 32) {
        float4 va0 = *(const float4*)(a0 + k0 + sq * 8);
        float4 va0b = *(const float4*)(a0 + k0 + sq * 8 + 4);
        float4 va1 = *(const float4*)(a1 + k0 + sq * 8);
        float4 va1b = *(const float4*)(a1 + k0 + sq * 8 + 4);
        float4 vb0 = *(const float4*)(b0 + k0 + sq * 8);
        float4 vb1 = *(const float4*)(b1 + k0 + sq * 8);
        __syncthreads();
        *(u16x8*)&As[srow * BSTR + sq * 8] = cvt8v(va0, va0b);
        *(u16x8*)&As[(srow + 64) * BSTR + sq * 8] = cvt8v(va1, va1b);
        *(float4*)&Bs[srow * BSTR + sq * 8] = vb0;
        *(float4*)&Bs[(srow + 64) * BSTR + sq * 8] = vb1;
        __syncthreads();
        bf16x8 af[4], bfr[4];
#pragma unroll
        for (int i = 0; i < 4; i++) {
            af[i] = *(const bf16x8*)&As[(wr + i * 16 + m16) * BSTR + q * 8];
            bfr[i] = *(const bf16x8*)&Bs[(wc + i * 16 + m16) * BSTR + q * 8];
        }
#pragma unroll
        for (int i = 0; i < 4; i++)
#pragma unroll
            for (int j = 0; j < 4; j++)
                acc[i][j] = __builtin_amdgcn_mfma_f32_16x16x32_bf16(af[i], bfr[j], acc[i][j], 0, 0, 0);
    }
#pragma unroll
    for (int i = 0; i < 4; i++)
#pragma unroll
        for (int r = 0; r < 4; r++) {
            int pos = o + m0 + wr + i * 16 + q * 4 + r;
            if (pos < o + c) {
#pragma unroll
                for (int j = 0; j < 4; j++)
                    qpart[((size_t)s * NPAD + pos) * HD + wc + j * 16 + m16] = acc[i][j][r];
            }
        }
}

__global__ void q_reduce(const float* __restrict__ qpart, const float* __restrict__ qb,
                         const int* __restrict__ aidx, const int* __restrict__ list,
                         ushort* __restrict__ Qg) {
    int pos = blockIdx.x, h = threadIdx.x;  // 128
    int e = aidx[list[pos]];
    float a = qb[e * HD + h];
#pragma unroll
    for (int s = 0; s < 4; s++) a += qpart[((size_t)s * NPAD + pos) * HD + h];
    Qg[(size_t)pos * HD + h] = f2b(a * QSCALE);
}

// ---------------- Rel-pos dots (bf16 Q) ----------------
__global__ void rel_kernel(const ushort* __restrict__ Qg, const float* __restrict__ rel,
                           float* __restrict__ R) {
    int pos = blockIdx.x;
    __shared__ float qsh[HD];
    if (threadIdx.x < HD) qsh[threadIdx.x] = b2f(Qg[(size_t)pos * HD + threadIdx.x]);
    __syncthreads();
    int r = threadIdx.x;
    if (r < RNUM) {
        const float4* rr = (const float4*)(rel + r * HD);
        const float4* qv = (const float4*)qsh;
        float a = 0.f;
#pragma unroll
        for (int h4 = 0; h4 < HD / 4; h4++) {
            float4 rv = rr[h4], qa = qv[h4];
            a += qa.x * rv.x + qa.y * rv.y + qa.z * rv.z + qa.w * rv.w;
        }
        R[(size_t)pos * RSTRIDE + r] = a;
    }
}

// ---------------- s: MFMA QK^T + rel bias, fp32 S out ----------------
__global__ __launch_bounds__(256) void s_mfma(
    const ushort* __restrict__ Qg, const float* __restrict__ kbf,
    const float* __restrict__ R, const int* __restrict__ meta,
    const int* __restrict__ list, float* __restrict__ S) {
    int bin = blockIdx.z;
    int o = meta[32 + bin], c = meta[bin];
    int m0 = blockIdx.x * 128;
    if (m0 >= c) return;
    int b = bin & 3;
    int n0 = blockIdx.y * 128;
    const float* kbase = kbf + (size_t)b * SEQ * HD;
    __shared__ __align__(16) short As[128 * BSTR];
    __shared__ __align__(16) short Bs[128 * BSTR];
    int tid = threadIdx.x, srow = tid >> 2, sq = tid & 3;
    const ushort* a0 = Qg + (size_t)(o + m0 + srow) * HD;
    const ushort* a1 = a0 + (size_t)64 * HD;
    const float* b0 = kbase + (size_t)(n0 + srow) * HD;
    const float* b1 = b0 + (size_t)64 * HD;
    int w = tid >> 6, lid = tid & 63;
    int wr = (w >> 1) * 64, wc = (w & 1) * 64;
    int m16 = lid & 15, q = lid >> 4;
    f32x4 acc[4][4] = {};
    for (int k0 = 0; k0 < HD; k0 += 32) {
        float4 va0 = *(const float4*)(a0 + k0 + sq * 8);
        float4 va1 = *(const float4*)(a1 + k0 + sq * 8);
        float4 vb0 = *(const float4*)(b0 + k0 + sq * 8);
        float4 vb0b = *(const float4*)(b0 + k0 + sq * 8 + 4);
        float4 vb1 = *(const float4*)(b1 + k0 + sq * 8);
        float4 vb1b = *(const float4*)(b1 + k0 + sq * 8 + 4);
        __syncthreads();
        *(float4*)&As[srow * BSTR + sq * 8] = va0;
        *(float4*)&As[(srow + 64) * BSTR + sq * 8] = va1;
        *(u16x8*)&Bs[srow * BSTR + sq * 8] = cvt8v(vb0, vb0b);
        *(u16x8*)&Bs[(srow + 64) * BSTR + sq * 8] = cvt8v(vb1, vb1b);
        __syncthreads();
        bf16x8 af[4], bfr[4];
#pragma unroll
        for (int i = 0; i < 4; i++) {
            af[i] = *(const bf16x8*)&As[(wr + i * 16 + m16) * BSTR + q * 8];
            bfr[i] = *(const bf16x8*)&Bs[(wc + i * 16 + m16) * BSTR + q * 8];
        }
#pragma unroll
        for (int i = 0; i < 4; i++)
#pragma unroll
            for (int j = 0; j < 4; j++)
                acc[i][j] = __builtin_amdgcn_mfma_f32_16x16x32_bf16(af[i], bfr[j], acc[i][j], 0, 0, 0);
    }
#pragma unroll
    for (int i = 0; i < 4; i++)
#pragma unroll
        for (int r = 0; r < 4; r++) {
            int pos = o + m0 + wr + i * 16 + q * 4 + r;
            if (pos < o + c) {
                int qpos = (list[pos] >> 1) & (SEQ - 1);
                const float* Rrow = R + (size_t)pos * RSTRIDE;
                float* sr = S + (size_t)pos * SEQ;
#pragma unroll
                for (int j = 0; j < 4; j++) {
                    int key = n0 + wc + j * 16 + m16;
                    int ri = key - qpos;
                    ri = (ri < -MAXPOS ? -MAXPOS : (ri > MAXPOS ? MAXPOS : ri)) + MAXPOS;
                    sr[key] = acc[i][j][r] + Rrow[ri];
                }
            }
        }
}

// ---------------- Row softmax (fp32 in place) ----------------
__global__ __launch_bounds__(256) void softmax_kernel(float* __restrict__ S) {
    int row = blockIdx.x;
    float4* sr = (float4*)(S + (size_t)row * SEQ);
    float4 v = sr[threadIdx.x];
    float m = fmaxf(fmaxf(v.x, v.y), fmaxf(v.z, v.w));
#pragma unroll
    for (int off = 32; off; off >>= 1) m = fmaxf(m, __shfl_down(m, off));
    __shared__ float red0[4], red1[4];
    int wave = threadIdx.x >> 6, lane = threadIdx.x & 63;
    if (lane == 0) red0[wave] = m;
    __syncthreads();
    m = fmaxf(fmaxf(red0[0], red0[1]), fmaxf(red0[2], red0[3]));
    v.x = __expf(v.x - m); v.y = __expf(v.y - m);
    v.z = __expf(v.z - m); v.w = __expf(v.w - m);
    float s = v.x + v.y + v.z + v.w;
#pragma unroll
    for (int off = 32; off; off >>= 1) s += __shfl_down(s, off);
    if (lane == 0) red1[wave] = s;
    __syncthreads();
    float inv = 1.f / (red1[0] + red1[1] + red1[2] + red1[3]);
    v.x *= inv; v.y *= inv; v.z *= inv; v.w *= inv;
    sr[threadIdx.x] = v;
}

// ---------------- pv: split-K MFMA P@V, dense partials ----------------
__global__ __launch_bounds__(256) void pv_mfma(
    const float* __restrict__ S, const ushort* __restrict__ vt16,
    const int* __restrict__ meta, float* __restrict__ ppart) {
    int bin = blockIdx.z;
    int o = meta[32 + bin], c = meta[bin];
    int m0 = blockIdx.x * 128;
    if (m0 >= c) return;
    int b = bin & 3;
    int s = blockIdx.y;
    int kbase = s * 256;
    __shared__ __align__(16) short As[128 * BSTR];
    __shared__ __align__(16) short Bs[128 * BSTR];
    int tid = threadIdx.x, srow = tid >> 2, sq = tid & 3;
    const float* a0 = S + (size_t)(o + m0 + srow) * SEQ;
    const float* a1 = a0 + (size_t)64 * SEQ;
    const ushort* b0 = vt16 + (size_t)b * HD * SEQ + (size_t)srow * SEQ;
    const ushort* b1 = b0 + (size_t)64 * SEQ;
    int w = tid >> 6, lid = tid & 63;
    int wr = (w >> 1) * 64, wc = (w & 1) * 64;
    int m16 = lid & 15, q = lid >> 4;
    f32x4 acc[4][4] = {};
    for (int k0 = kbase; k0 < kbase + 256; k0 += 32) {
        float4 va0 = *(const float4*)(a0 + k0 + sq * 8);
        float4 va0b = *(const float4*)(a0 + k0 + sq * 8 + 4);
        float4 va1 = *(const float4*)(a1 + k0 + sq * 8);
        float4 va1b = *(const float4*)(a1 + k0 + sq * 8 + 4);
        float4 vb0 = *(const float4*)(b0 + k0 + sq * 8);
        float4 vb1 = *(const float4*)(b1 + k0 + sq * 8);
        __syncthreads();
        *(u16x8*)&As[srow * BSTR + sq * 8] = cvt8v(va0, va0b);
        *(u16x8*)&As[(srow + 64) * BSTR + sq * 8] = cvt8v(va1, va1b);
        *(float4*)&Bs[srow * BSTR + sq * 8] = vb0;
        *(float4*)&Bs[(srow + 64) * BSTR + sq * 8] = vb1;
        __syncthreads();
        bf16x8 af[4], bfr[4];
#pragma unroll
        for (int i = 0; i < 4; i++) {
            af[i] = *(const bf16x8*)&As[(wr + i * 16 + m16) * BSTR + q * 8];
            bfr[i] = *(const bf16x8*)&Bs[(wc + i * 16 + m16) * BSTR + q * 8];
        }
#pragma unroll
        for (int i = 0; i < 4; i++)
#pragma unroll
            for (int j = 0; j < 4; j++)
                acc[i][j] = __builtin_amdgcn_mfma_f32_16x16x32_bf16(af[i], bfr[j], acc[i][j], 0, 0, 0);
    }
#pragma unroll
    for (int i = 0; i < 4; i++)
#pragma unroll
        for (int r = 0; r < 4; r++) {
            int pos = o + m0 + wr + i * 16 + q * 4 + r;
            if (pos < o + c) {
#pragma unroll
                for (int j = 0; j < 4; j++)
                    ppart[((size_t)s * NPAD + pos) * HD + wc + j * 16 + m16] = acc[i][j][r];
            }
        }
}

__global__ void pv_reduce(const float* __restrict__ ppart, const float* __restrict__ aga,
                          const int* __restrict__ list, float* __restrict__ ctxf) {
    int pos = blockIdx.x, h = threadIdx.x;  // 128
    float g = aga[list[pos]];
    float a = 0.f;
#pragma unroll
    for (int s = 0; s < 4; s++) a += ppart[((size_t)s * NPAD + pos) * HD + h];
    ctxf[(size_t)pos * HD + h] = a * g;
}

// ---------------- o: MFMA ctx@o_w, dense bf16 per-pair rows ----------------
__global__ __launch_bounds__(256) void o_mfma(
    const float* __restrict__ ctxf, const ushort* __restrict__ owt,
    const int* __restrict__ meta, ushort* __restrict__ Ofb) {
    int e = blockIdx.z;
    int o = meta[96 + e], c = meta[97 + e] - o;
    int m0 = blockIdx.x * 128;
    if (m0 >= c) return;
    int n0 = blockIdx.y * 128;
    __shared__ __align__(16) short As[128 * BSTR];
    __shared__ __align__(16) short Bs[128 * BSTR];
    int tid = threadIdx.x, srow = tid >> 2, sq = tid & 3;
    const float* a0 = ctxf + (size_t)(o + m0 + srow) * HD;
    const float* a1 = a0 + (size_t)64 * HD;
    const ushort* b0 = owt + (size_t)e * D * HD + (size_t)(n0 + srow) * HD;
    const ushort* b1 = b0 + (size_t)64 * HD;
    int w = tid >> 6, lid = tid & 63;
    int wr = (w >> 1) * 64, wc = (w & 1) * 64;
    int m16 = lid & 15, q = lid >> 4;
    f32x4 acc[4][4] = {};
    for (int k0 = 0; k0 < HD; k0 += 32) {
        float4 va0 = *(const float4*)(a0 + k0 + sq * 8);
        float4 va0b = *(const float4*)(a0 + k0 + sq * 8 + 4);
        float4 va1 = *(const float4*)(a1 + k0 + sq * 8);
        float4 va1b = *(const float4*)(a1 + k0 + sq * 8 + 4);
        float4 vb0 = *(const float4*)(b0 + k0 + sq * 8);
        float4 vb1 = *(const float4*)(b1 + k0 + sq * 8);
        __syncthreads();
        *(u16x8*)&As[srow * BSTR + sq * 8] = cvt8v(va0, va0b);
        *(u16x8*)&As[(srow + 64) * BSTR + sq * 8] = cvt8v(va1, va1b);
        *(float4*)&Bs[srow * BSTR + sq * 8] = vb0;
        *(float4*)&Bs[(srow + 64) * BSTR + sq * 8] = vb1;
        __syncthreads();
        bf16x8 af[4], bfr[4];
#pragma unroll
        for (int i = 0; i < 4; i++) {
            af[i] = *(const bf16x8*)&As[(wr + i * 16 + m16) * BSTR + q * 8];
            bfr[i] = *(const bf16x8*)&Bs[(wc + i * 16 + m16) * BSTR + q * 8];
        }
#pragma unroll
        for (int i = 0; i < 4; i++)
#pragma unroll
            for (int j = 0; j < 4; j++)
                acc[i][j] = __builtin_amdgcn_mfma_f32_16x16x32_bf16(af[i], bfr[j], acc[i][j], 0, 0, 0);
    }
#pragma unroll
    for (int i = 0; i < 4; i++)
#pragma unroll
        for (int r = 0; r < 4; r++) {
            int pos = o + m0 + wr + i * 16 + q * 4 + r;
            if (pos < o + c) {
#pragma unroll
                for (int j = 0; j < 4; j++)
                    Ofb[(size_t)pos * D + n0 + wc + j * 16 + m16] = f2b(acc[i][j][r]);
            }
        }
}

// ---------------- attn combine: x1 = src + gated ob + two pair rows ----------------
__global__ void attn_combine(const float* __restrict__ src, const float* __restrict__ ob,
                             const int* __restrict__ aidx, const float* __restrict__ aga,
                             const int* __restrict__ ainv, const ushort* __restrict__ Ofb,
                             float* __restrict__ x1) {
    int t = blockIdx.x, tid = threadIdx.x;
    int e0 = aidx[t * 2], e1 = aidx[t * 2 + 1];
    float g0 = aga[t * 2], g1 = aga[t * 2 + 1];
    int p0 = ainv[t * 2], p1 = ainv[t * 2 + 1];
#pragma unroll
    for (int i = 0; i < 4; i++) {
        int d = tid + i * 256;
        x1[(size_t)t * D + d] = src[(size_t)t * D + d]
                              + g0 * ob[e0 * D + d] + g1 * ob[e1 * D + d]
                              + b2f(Ofb[(size_t)p0 * D + d]) + b2f(Ofb[(size_t)p1 * D + d]);
    }
}

// ---------------- FFN GEMM1: Hb = g*relu(xn2 @ W1 + b1) ----------------
__global__ __launch_bounds__(256) void ffn_mfma1(
    const float* __restrict__ xn2, const ushort* __restrict__ w1t,
    const float* __restrict__ b1, const int* __restrict__ meta,
    const int* __restrict__ list, const float* __restrict__ fga,
    ushort* __restrict__ Hb) {
    int e = blockIdx.z;
    int o = meta[16 + e], c = meta[e];
    int m0 = blockIdx.x * 128;
    if (m0 >= c) return;
    int n0 = blockIdx.y * 128;
    __shared__ __align__(16) short As[128 * BSTR];
    __shared__ __align__(16) short Bs[128 * BSTR];
    int tid = threadIdx.x, srow = tid >> 2, sq = tid & 3;
    int r0i = o + m0 + srow;      if (r0i > NPAIR - 1) r0i = NPAIR - 1;
    int r1i = o + m0 + srow + 64; if (r1i > NPAIR - 1) r1i = NPAIR - 1;
    const float* a0 = xn2 + (size_t)(list[r0i] >> 1) * D;
    const float* a1 = xn2 + (size_t)(list[r1i] >> 1) * D;
    const ushort* b0 = w1t + ((size_t)e * FH + n0 + srow) * D;
    const ushort* b1p = w1t + ((size_t)e * FH + n0 + srow + 64) * D;
    int w = tid >> 6, lid = tid & 63;
    int wr = (w >> 1) * 64, wc = (w & 1) * 64;
    int m16 = lid & 15, q = lid >> 4;
    f32x4 acc[4][4] = {};
    for (int k0 = 0; k0 < D; k0 += 32) {
        float4 va0 = *(const float4*)(a0 + k0 + sq * 8);
        float4 va0b = *(const float4*)(a0 + k0 + sq * 8 + 4);
        float4 va1 = *(const float4*)(a1 + k0 + sq * 8);
        float4 va1b = *(const float4*)(a1 + k0 + sq * 8 + 4);
        float4 vb0 = *(const float4*)(b0 + k0 + sq * 8);
        float4 vb1 = *(const float4*)(b1p + k0 + sq * 8);
        __syncthreads();
        *(u16x8*)&As[srow * BSTR + sq * 8] = cvt8v(va0, va0b);
        *(u16x8*)&As[(srow + 64) * BSTR + sq * 8] = cvt8v(va1, va1b);
        *(float4*)&Bs[srow * BSTR + sq * 8] = vb0;
        *(float4*)&Bs[(srow + 64) * BSTR + sq * 8] = vb1;
        __syncthreads();
        bf16x8 af[4], bfr[4];
#pragma unroll
        for (int i = 0; i < 4; i++) {
            af[i] = *(const bf16x8*)&As[(wr + i * 16 + m16) * BSTR + q * 8];
            bfr[i] = *(const bf16x8*)&Bs[(wc + i * 16 + m16) * BSTR + q * 8];
        }
#pragma unroll
        for (int i = 0; i < 4; i++)
#pragma unroll
            for (int j = 0; j < 4; j++)
                acc[i][j] = __builtin_amdgcn_mfma_f32_16x16x32_bf16(af[i], bfr[j], acc[i][j], 0, 0, 0);
    }
#pragma unroll
    for (int i = 0; i < 4; i++)
#pragma unroll
        for (int r = 0; r < 4; r++) {
            int pos = o + m0 + wr + i * 16 + q * 4 + r;
            if (pos < o + c) {
                float g = fga[list[pos]];
#pragma unroll
                for (int j = 0; j < 4; j++) {
                    int n = n0 + wc + j * 16 + m16;
                    Hb[(size_t)pos * FH + n] = f2b(g * fmaxf(acc[i][j][r] + b1[e * FH + n], 0.f));
                }
            }
        }
}

// ---------------- FFN GEMM2: Of2b[pos] = Hb @ W2 (dense bf16 rows) ----------------
__global__ __launch_bounds__(256) void ffn_mfma2(
    const ushort* __restrict__ Hb, const ushort* __restrict__ w2t,
    const int* __restrict__ meta, ushort* __restrict__ Of2b) {
    int e = blockIdx.z;
    int o = meta[16 + e], c = meta[e];
    int m0 = blockIdx.x * 128;
    if (m0 >= c) return;
    int n0 = blockIdx.y * 128;
    __shared__ __align__(16) short As[128 * BSTR];
    __shared__ __align__(16) short Bs[128 * BSTR];
    int tid = threadIdx.x, srow = tid >> 2, sq = tid & 3;
    const ushort* a0 = Hb + (size_t)(o + m0 + srow) * FH;
    const ushort* a1 = a0 + (size_t)64 * FH;
    const ushort* b0 = w2t + ((size_t)e * D + n0 + srow) * FH;
    const ushort* b1 = w2t + ((size_t)e * D + n0 + srow + 64) * FH;
    int w = tid >> 6, lid = tid & 63;
    int wr = (w >> 1) * 64, wc = (w & 1) * 64;
    int m16 = lid & 15, q = lid >> 4;
    f32x4 acc[4][4] = {};
    for (int k0 = 0; k0 < FH; k0 += 32) {
        float4 va0 = *(const float4*)(a0 + k0 + sq * 8);
        float4 va1 = *(const float4*)(a1 + k0 + sq * 8);
        float4 vb0 = *(const float4*)(b0 + k0 + sq * 8);
        float4 vb1 = *(const float4*)(b1 + k0 + sq * 8);
        __syncthreads();
        *(float4*)&As[srow * BSTR + sq * 8] = va0;
        *(float4*)&As[(srow + 64) * BSTR + sq * 8] = va1;
        *(float4*)&Bs[srow * BSTR + sq * 8] = vb0;
        *(float4*)&Bs[(srow + 64) * BSTR + sq * 8] = vb1;
        __syncthreads();
        bf16x8 af[4], bfr[4];
#pragma unroll
        for (int i = 0; i < 4; i++) {
            af[i] = *(const bf16x8*)&As[(wr + i * 16 + m16) * BSTR + q * 8];
            bfr[i] = *(const bf16x8*)&Bs[(wc + i * 16 + m16) * BSTR + q * 8];
        }
#pragma unroll
        for (int i = 0; i < 4; i++)
#pragma unroll
            for (int j = 0; j < 4; j++)
                acc[i][j] = __builtin_amdgcn_mfma_f32_16x16x32_bf16(af[i], bfr[j], acc[i][j], 0, 0, 0);
    }
#pragma unroll
    for (int i = 0; i < 4; i++)
#pragma unroll
        for (int r = 0; r < 4; r++) {
            int pos = o + m0 + wr + i * 16 + q * 4 + r;
            if (pos < o + c) {
#pragma unroll
                for (int j = 0; j < 4; j++)
                    Of2b[(size_t)pos * D + n0 + wc + j * 16 + m16] = f2b(acc[i][j][r]);
            }
        }
}

// ---------------- FFN combine: out = x1 + gated b2 + two pair rows ----------------
__global__ void ffn_combine(const float* __restrict__ x1, const float* __restrict__ b2,
                            const int* __restrict__ fidx, const float* __restrict__ fga,
                            const int* __restrict__ finv, const ushort* __restrict__ Of2b,
                            float* __restrict__ out) {
    int t = blockIdx.x, tid = threadIdx.x;
    int e0 = fidx[t * 2], e1 = fidx[t * 2 + 1];
    float g0 = fga[t * 2], g1 = fga[t * 2 + 1];
    int p0 = finv[t * 2], p1 = finv[t * 2 + 1];
#pragma unroll
    for (int i = 0; i < 4; i++) {
        int d = tid + i * 256;
        out[(size_t)t * D + d] = x1[(size_t)t * D + d]
                               + g0 * b2[e0 * D + d] + g1 * b2[e1 * D + d]
                               + b2f(Of2b[(size_t)p0 * D + d]) + b2f(Of2b[(size_t)p1 * D + d]);
    }
}

extern "C" void kernel_launch(void* const* d_in, const int* in_sizes, int n_in,
                              void* d_out, int out_size, void* d_ws, size_t ws_size,
                              hipStream_t stream) {
    const float* src   = (const float*)d_in[0];
    const float* ln1_w = (const float*)d_in[1];
    const float* ln1_b = (const float*)d_in[2];
    const float* ln2_w = (const float*)d_in[3];
    const float* ln2_b = (const float*)d_in[4];
    const float* agw   = (const float*)d_in[5];
    const float* qw    = (const float*)d_in[6];
    const float* qb    = (const float*)d_in[7];
    const float* kw    = (const float*)d_in[8];
    const float* kb    = (const float*)d_in[9];
    const float* vw    = (const float*)d_in[10];
    const float* vb    = (const float*)d_in[11];
    const float* ow    = (const float*)d_in[12];
    const float* ob    = (const float*)d_in[13];
    const float* rel   = (const float*)d_in[14];
    const float* fgw   = (const float*)d_in[15];
    const float* w1    = (const float*)d_in[16];
    const float* b1    = (const float*)d_in[17];
    const float* w2    = (const float*)d_in[18];
    const float* b2    = (const float*)d_in[19];
    float* out = (float*)d_out;

    char* p = (char*)d_ws;
    float* xn1  = (float*)p; p += (size_t)NTOK * D * 4;               // LN out (both LNs)
    float* x1   = (float*)p; p += (size_t)NTOK * D * 4;
    char*  sreg = p;         p += (size_t)NPAD * SEQ * 4;             // 34.1 MB
    float*  Sbuf = (float*)sreg;                                      // attn: scores/P
    ushort* Ofb  = (ushort*)sreg;                                     // attn: o rows (17 MB)
    ushort* w1t  = (ushort*)sreg;                                     // FFN: 16.78 MB
    ushort* w2t  = (ushort*)(sreg + (size_t)16777216);                // FFN: 16.78 MB
    char*  reg  = p;         p += (size_t)NPAD * 128 * 6 + (size_t)NPAIR * RSTRIDE * 4;
    float*  ctxf = (float*)reg;                                       // 4.26 MB
    ushort* Qg   = (ushort*)(reg + (size_t)NPAD * 128 * 4);           // 2.13 MB
    float*  Rbuf = (float*)(reg + (size_t)NPAD * 128 * 6);            // 4.33 MB
    ushort* Hb   = (ushort*)reg;                                      // FFN hidden (8.52 MB)
    char*  arena = p;        p += (size_t)4 * NPAD * 128 * 4;         // 17.04 MB
    float*  kpart = (float*)arena;                                    // 4*NTOK*HD*4 = 8.39
    float*  vpart = (float*)(arena + (size_t)4 * NTOK * HD * 4);      // 8.39
    float*  qpart = (float*)arena;                                    // 17.04 (reuse)
    float*  ppart = (float*)arena;                                    // 17.04 (reuse)
    ushort* Of2b  = (ushort*)arena;                                   // 17.04 (reuse)
    float* kbf  = (float*)p; p += (size_t)NTOK * HD * 4;
    float* vbf  = (float*)p; p += (size_t)NTOK * HD * 4;
    ushort* vt16 = (ushort*)p; p += (size_t)NTOK * HD * 2;
    ushort* kwt = (ushort*)p; p += (size_t)HD * D * 2;
    ushort* vwt = (ushort*)p; p += (size_t)HD * D * 2;
    ushort* qwt = (ushort*)p; p += (size_t)EA * HD * D * 2;
    ushort* owt = (ushort*)p; p += (size_t)EA * D * HD * 2;
    int*   aidx = (int*)p;   p += NPAIR * 4;
    float* aga  = (float*)p; p += NPAIR * 4;
    int*   fidx = (int*)p;   p += NPAIR * 4;
    float* fga  = (float*)p; p += NPAIR * 4;
    int*   ameta = (int*)p;  p += 128 * 4;
    int*   alist = (int*)p;  p += NPAIR * 4;
    int*   ainv = (int*)p;   p += NPAIR * 4;
    int*   fmeta = (int*)p;  p += 64 * 4;
    int*   flist = (int*)p;  p += NPAIR * 4;
    int*   finv = (int*)p;   p += NPAIR * 4;
    float* xn2 = xn1;

    // ---- attention ----
    ln_kernel<<<NTOK, 256, 0, stream>>>(src, ln1_w, ln1_b, xn1);
    router_kernel<EA><<<NTOK, 64, 0, stream>>>(xn1, agw, aidx, aga);
    abin_zero<<<1, 128, 0, stream>>>(ameta);
    abin_count<<<NPAIR / 256, 256, 0, stream>>>(aidx, ameta);
    abin_scan<<<1, 64, 0, stream>>>(ameta);
    abin_scatter<<<NPAIR / 256, 256, 0, stream>>>(aidx, ameta, alist, ainv);
    convT_kernel<1024, 128><<<dim3(32, 4, 1), 256, 0, stream>>>(kw, kwt);
    convT_kernel<1024, 128><<<dim3(32, 4, 1), 256, 0, stream>>>(vw, vwt);
    convT_kernel<1024, 128><<<dim3(32, 4, EA), 256, 0, stream>>>(qw, qwt);
    convT_kernel<128, 1024><<<dim3(4, 32, EA), 256, 0, stream>>>(ow, owt);
    kv_mfma<<<dim3(NTOK / 128, 4, 2), 256, 0, stream>>>(xn1, kwt, vwt, kpart, vpart);
    kv_reduce<<<NTOK, 128, 0, stream>>>(kpart, vpart, kb, vb, kbf, vbf);
    convT_kernel<1024, 128><<<dim3(32, 4, 4), 256, 0, stream>>>(vbf, vt16);
    q_mfma<<<dim3(32, 4, EA), 256, 0, stream>>>(xn1, qwt, ameta, alist, qpart);
    q_reduce<<<NPAIR, 128, 0, stream>>>(qpart, qb, aidx, alist, Qg);
    rel_kernel<<<NPAIR, 192, 0, stream>>>(Qg, rel, Rbuf);
    s_mfma<<<dim3(8, 8, 32), 256, 0, stream>>>(Qg, kbf, Rbuf, ameta, alist, Sbuf);
    softmax_kernel<<<NPAIR, 256, 0, stream>>>(Sbuf);
    pv_mfma<<<dim3(8, 4, 32), 256, 0, stream>>>(Sbuf, vt16, ameta, ppart);
    pv_reduce<<<NPAIR, 128, 0, stream>>>(ppart, aga, alist, ctxf);
    o_mfma<<<dim3(32, 8, EA), 256, 0, stream>>>(ctxf, owt, ameta, Ofb);
    attn_combine<<<NTOK, 256, 0, stream>>>(src, ob, aidx, aga, ainv, Ofb, x1);

    // ---- FFN ----
    ln_kernel<<<NTOK, 256, 0, stream>>>(x1, ln2_w, ln2_b, xn2);
    router_kernel<EF><<<NTOK, 64, 0, stream>>>(xn2, fgw, fidx, fga);
    bin_zero<<<1, 64, 0, stream>>>(fmeta);
    bin_count<<<NPAIR / 256, 256, 0, stream>>>(fidx, fmeta);
    bin_scan<<<1, 64, 0, stream>>>(fmeta);
    bin_scatter<<<NPAIR / 256, 256, 0, stream>>>(fidx, fmeta, flist, finv);
    convT_kernel<1024, 512><<<dim3(32, 16, EF), 256, 0, stream>>>(w1, w1t);
    convT_kernel<512, 1024><<<dim3(16, 32, EF), 256, 0, stream>>>(w2, w2t);
    ffn_mfma1<<<dim3(32, FH / 128, EF), 256, 0, stream>>>(xn2, w1t, b1, fmeta, flist, fga, Hb);
    ffn_mfma2<<<dim3(32, D / 128, EF), 256, 0, stream>>>(Hb, w2t, fmeta, Of2b);
    ffn_combine<<<NTOK, 256, 0, stream>>>(x1, b2, fidx, fga, finv, Of2b, out);
}

// Round 7
// 583.725 us; speedup vs baseline: 8.8687x; 1.3332x over previous
//
#include <hip/hip_runtime.h>

#define D 1024
#define HD 128
#define EA 8
#define EF 16
#define FH 512
#define MAXPOS 64
#define RNUM 129
#define RSTRIDE 132
#define SEQ 1024
#define NTOK 4096
#define NPAIR (NTOK * 2)
#define NPAD 8320          // NPAIR + 128 slack
#define LN_EPS 1e-5f
#define QSCALE 0.08838834764831845f
#define BSTR 40            // LDS row stride in bf16 elems

typedef __attribute__((ext_vector_type(8))) short bf16x8;
typedef __attribute__((ext_vector_type(4))) float f32x4;
typedef __attribute__((ext_vector_type(8))) unsigned short u16x8;

__device__ inline ushort f2b(float f) {
    union { float f; unsigned u; } v; v.f = f;
    unsigned r = (v.u + 0x7fffu + ((v.u >> 16) & 1u)) >> 16;
    return (ushort)r;
}
__device__ inline float b2f(ushort u) {
    union { unsigned u; float f; } v; v.u = (unsigned)u << 16; return v.f;
}
__device__ inline u16x8 cvt8v(float4 a, float4 b) {
    u16x8 r;
    r[0] = f2b(a.x); r[1] = f2b(a.y); r[2] = f2b(a.z); r[3] = f2b(a.w);
    r[4] = f2b(b.x); r[5] = f2b(b.y); r[6] = f2b(b.z); r[7] = f2b(b.w);
    return r;
}

// one double-buffer compute step: 64x128 tile, wave = 32x64
__device__ inline void mfma_step(const short* Asb, const short* Bsb,
                                 int wr, int wc, int m16, int q, f32x4 (&acc)[2][4]) {
    bf16x8 af[2], bfr[4];
#pragma unroll
    for (int i = 0; i < 2; i++) af[i] = *(const bf16x8*)&Asb[(wr + i * 16 + m16) * BSTR + q * 8];
#pragma unroll
    for (int j = 0; j < 4; j++) bfr[j] = *(const bf16x8*)&Bsb[(wc + j * 16 + m16) * BSTR + q * 8];
#pragma unroll
    for (int i = 0; i < 2; i++)
#pragma unroll
        for (int j = 0; j < 4; j++)
            acc[i][j] = __builtin_amdgcn_mfma_f32_16x16x32_bf16(af[i], bfr[j], acc[i][j], 0, 0, 0);
}

// ---------------- LayerNorm ----------------
__global__ void ln_kernel(const float* __restrict__ x, const float* __restrict__ w,
                          const float* __restrict__ b, float* __restrict__ y) {
    int row = blockIdx.x;
    const float* xr = x + (size_t)row * D;
    float v[4];
    float s = 0.f, s2 = 0.f;
#pragma unroll
    for (int i = 0; i < 4; i++) {
        v[i] = xr[threadIdx.x + i * 256];
        s += v[i]; s2 += v[i] * v[i];
    }
#pragma unroll
    for (int off = 32; off; off >>= 1) { s += __shfl_down(s, off); s2 += __shfl_down(s2, off); }
    __shared__ float red0[4], red1[4];
    int wave = threadIdx.x >> 6, lane = threadIdx.x & 63;
    if (lane == 0) { red0[wave] = s; red1[wave] = s2; }
    __syncthreads();
    float ts = red0[0] + red0[1] + red0[2] + red0[3];
    float ts2 = red1[0] + red1[1] + red1[2] + red1[3];
    float mu = ts * (1.f / D);
    float var = ts2 * (1.f / D) - mu * mu;
    float inv = rsqrtf(var + LN_EPS);
#pragma unroll
    for (int i = 0; i < 4; i++) {
        int d = threadIdx.x + i * 256;
        y[(size_t)row * D + d] = (v[i] - mu) * inv * w[d] + b[d];
    }
}

// ---------------- Router ----------------
template <int E>
__global__ void router_kernel(const float* __restrict__ xn, const float* __restrict__ gw,
                              int* __restrict__ idx, float* __restrict__ gate) {
    int t = blockIdx.x;
    int lane = threadIdx.x;  // block=64
    float acc[E];
#pragma unroll
    for (int e = 0; e < E; e++) acc[e] = 0.f;
    const float* xr = xn + (size_t)t * D;
    for (int d = lane; d < D; d += 64) {
        float xv = xr[d];
#pragma unroll
        for (int e = 0; e < E; e++) acc[e] += xv * gw[d * E + e];
    }
#pragma unroll
    for (int e = 0; e < E; e++) {
#pragma unroll
        for (int off = 32; off; off >>= 1) acc[e] += __shfl_down(acc[e], off);
    }
    if (lane == 0) {
        float v0 = -1e30f, v1 = -1e30f;
        int i0 = 0, i1 = 0;
#pragma unroll
        for (int e = 0; e < E; e++) {
            float a = acc[e];
            if (a > v0) { v1 = v0; i1 = i0; v0 = a; i0 = e; }
            else if (a > v1) { v1 = a; i1 = e; }
        }
        float g0 = 1.f / (1.f + expf(v1 - v0));
        idx[t * 2] = i0; idx[t * 2 + 1] = i1;
        gate[t * 2] = g0; gate[t * 2 + 1] = 1.f - g0;
    }
}

// ---------------- Attention binning: 32 bins keyed (expert*4 + batch) ----------------
__global__ void abin_zero(int* __restrict__ meta) {
    if (threadIdx.x < 105) meta[threadIdx.x] = 0;
}
__global__ void abin_count(const int* __restrict__ aidx, int* __restrict__ meta) {
    int i = blockIdx.x * 256 + threadIdx.x;
    if (i < NPAIR) {
        int e = aidx[i];
        int b = (i >> 1) >> 10;
        atomicAdd(&meta[e * 4 + b], 1);
    }
}
__global__ void abin_scan(int* __restrict__ meta) {
    if (threadIdx.x == 0 && blockIdx.x == 0) {
        int s = 0;
        for (int bin = 0; bin < 32; bin++) {
            if ((bin & 3) == 0) meta[96 + (bin >> 2)] = s;
            meta[32 + bin] = s; meta[64 + bin] = s; s += meta[bin];
        }
        meta[96 + 8] = s;
    }
}
__global__ void abin_scatter(const int* __restrict__ aidx, int* __restrict__ meta,
                             int* __restrict__ list, int* __restrict__ inv) {
    int i = blockIdx.x * 256 + threadIdx.x;
    if (i < NPAIR) {
        int e = aidx[i];
        int b = (i >> 1) >> 10;
        int pos = atomicAdd(&meta[64 + e * 4 + b], 1);
        list[pos] = i;
        inv[i] = pos;
    }
}

// ---------------- FFN binning ----------------
__global__ void bin_zero(int* __restrict__ meta) {
    if (threadIdx.x < 48) meta[threadIdx.x] = 0;
}
__global__ void bin_count(const int* __restrict__ fidx, int* __restrict__ meta) {
    int i = blockIdx.x * 256 + threadIdx.x;
    if (i < NPAIR) atomicAdd(&meta[fidx[i]], 1);
}
__global__ void bin_scan(int* __restrict__ meta) {
    if (threadIdx.x == 0 && blockIdx.x == 0) {
        int s = 0;
        for (int e = 0; e < EF; e++) { meta[16 + e] = s; meta[32 + e] = s; s += meta[e]; }
    }
}
__global__ void bin_scatter(const int* __restrict__ fidx, int* __restrict__ meta,
                            int* __restrict__ list, int* __restrict__ inv) {
    int i = blockIdx.x * 256 + threadIdx.x;
    if (i < NPAIR) {
        int e = fidx[i];
        int pos = atomicAdd(&meta[32 + e], 1);
        list[pos] = i;
        inv[i] = pos;
    }
}

// ---------------- transpose-convert [E][R][C] fp32 -> [E][C][R] bf16 ----------------
template <int R, int C>
__global__ void convT_kernel(const float* __restrict__ in, ushort* __restrict__ out) {
    int e = blockIdx.z;
    int r0 = blockIdx.x * 32, c0 = blockIdx.y * 32;
    __shared__ float tile[32][33];
    int tx = threadIdx.x & 31, ty = threadIdx.x >> 5;  // 256 thr
    const float* src = in + (size_t)e * R * C;
#pragma unroll
    for (int i = 0; i < 32; i += 8)
        tile[ty + i][tx] = src[(size_t)(r0 + ty + i) * C + c0 + tx];
    __syncthreads();
    ushort* dst = out + (size_t)e * C * R;
#pragma unroll
    for (int i = 0; i < 32; i += 8)
        dst[(size_t)(c0 + ty + i) * R + r0 + tx] = f2b(tile[tx][ty + i]);
}

// ---------------- kv: split-K MFMA, dense per-split partials ----------------
__global__ __launch_bounds__(256) void kv_mfma(
    const float* __restrict__ xn, const ushort* __restrict__ kwt,
    const ushort* __restrict__ vwt, float* __restrict__ kpart, float* __restrict__ vpart) {
    const ushort* W = blockIdx.z ? vwt : kwt;
    float* outp = blockIdx.z ? vpart : kpart;
    int m0 = blockIdx.x * 64;
    int s = blockIdx.y;
    int kbase = s * 256;
    __shared__ __align__(16) short As[2][64 * BSTR];
    __shared__ __align__(16) short Bs[2][128 * BSTR];
    int tid = threadIdx.x, aRow = tid >> 2, aOff = (tid & 3) * 8;
    const float* ap = xn + (size_t)(m0 + aRow) * D + kbase + aOff;
    const ushort* bp0 = W + (size_t)aRow * D + kbase + aOff;
    const ushort* bp1 = bp0 + (size_t)64 * D;
    int w = tid >> 6, lid = tid & 63;
    int wr = (w >> 1) * 32, wc = (w & 1) * 64;
    int m16 = lid & 15, q = lid >> 4;
    f32x4 acc[2][4] = {};
    float4 ra0 = *(const float4*)ap, ra1 = *(const float4*)(ap + 4);
    u16x8 rb0 = *(const u16x8*)bp0, rb1 = *(const u16x8*)bp1;
    *(u16x8*)&As[0][aRow * BSTR + aOff] = cvt8v(ra0, ra1);
    *(u16x8*)&Bs[0][aRow * BSTR + aOff] = rb0;
    *(u16x8*)&Bs[0][(aRow + 64) * BSTR + aOff] = rb1;
    __syncthreads();
    int cur = 0;
    for (int k = 1; k < 8; k++) {
        ra0 = *(const float4*)(ap + k * 32); ra1 = *(const float4*)(ap + k * 32 + 4);
        rb0 = *(const u16x8*)(bp0 + k * 32); rb1 = *(const u16x8*)(bp1 + k * 32);
        mfma_step(As[cur], Bs[cur], wr, wc, m16, q, acc);
        int nxt = cur ^ 1;
        *(u16x8*)&As[nxt][aRow * BSTR + aOff] = cvt8v(ra0, ra1);
        *(u16x8*)&Bs[nxt][aRow * BSTR + aOff] = rb0;
        *(u16x8*)&Bs[nxt][(aRow + 64) * BSTR + aOff] = rb1;
        __syncthreads();
        cur = nxt;
    }
    mfma_step(As[cur], Bs[cur], wr, wc, m16, q, acc);
#pragma unroll
    for (int i = 0; i < 2; i++)
#pragma unroll
        for (int r = 0; r < 4; r++) {
            int m = m0 + wr + i * 16 + q * 4 + r;
#pragma unroll
            for (int j = 0; j < 4; j++)
                outp[((size_t)s * NTOK + m) * HD + wc + j * 16 + m16] = acc[i][j][r];
        }
}

__global__ void kv_reduce(const float* __restrict__ kpart, const float* __restrict__ vpart,
                          const float* __restrict__ kb, const float* __restrict__ vb,
                          float* __restrict__ kbf, float* __restrict__ vbf) {
    int t = blockIdx.x, h = threadIdx.x;  // 128
    float ka = kb[h], va = vb[h];
#pragma unroll
    for (int s = 0; s < 4; s++) {
        ka += kpart[((size_t)s * NTOK + t) * HD + h];
        va += vpart[((size_t)s * NTOK + t) * HD + h];
    }
    kbf[(size_t)t * HD + h] = ka;
    vbf[(size_t)t * HD + h] = va;
}

// ---------------- q: split-K MFMA, indirect A, dense partials ----------------
__global__ __launch_bounds__(256) void q_mfma(
    const float* __restrict__ xn, const ushort* __restrict__ qwt,
    const int* __restrict__ meta, const int* __restrict__ list, float* __restrict__ qpart) {
    int e = blockIdx.z;
    int o = meta[96 + e], c = meta[97 + e] - o;
    int m0 = blockIdx.x * 64;
    if (m0 >= c) return;
    int s = blockIdx.y;
    int kbase = s * 256;
    __shared__ __align__(16) short As[2][64 * BSTR];
    __shared__ __align__(16) short Bs[2][128 * BSTR];
    int tid = threadIdx.x, aRow = tid >> 2, aOff = (tid & 3) * 8;
    int ri = o + m0 + aRow; if (ri > NPAIR - 1) ri = NPAIR - 1;
    const float* ap = xn + (size_t)(list[ri] >> 1) * D + kbase + aOff;
    const ushort* bp0 = qwt + (size_t)e * HD * D + (size_t)aRow * D + kbase + aOff;
    const ushort* bp1 = bp0 + (size_t)64 * D;
    int w = tid >> 6, lid = tid & 63;
    int wr = (w >> 1) * 32, wc = (w & 1) * 64;
    int m16 = lid & 15, q = lid >> 4;
    f32x4 acc[2][4] = {};
    float4 ra0 = *(const float4*)ap, ra1 = *(const float4*)(ap + 4);
    u16x8 rb0 = *(const u16x8*)bp0, rb1 = *(const u16x8*)bp1;
    *(u16x8*)&As[0][aRow * BSTR + aOff] = cvt8v(ra0, ra1);
    *(u16x8*)&Bs[0][aRow * BSTR + aOff] = rb0;
    *(u16x8*)&Bs[0][(aRow + 64) * BSTR + aOff] = rb1;
    __syncthreads();
    int cur = 0;
    for (int k = 1; k < 8; k++) {
        ra0 = *(const float4*)(ap + k * 32); ra1 = *(const float4*)(ap + k * 32 + 4);
        rb0 = *(const u16x8*)(bp0 + k * 32); rb1 = *(const u16x8*)(bp1 + k * 32);
        mfma_step(As[cur], Bs[cur], wr, wc, m16, q, acc);
        int nxt = cur ^ 1;
        *(u16x8*)&As[nxt][aRow * BSTR + aOff] = cvt8v(ra0, ra1);
        *(u16x8*)&Bs[nxt][aRow * BSTR + aOff] = rb0;
        *(u16x8*)&Bs[nxt][(aRow + 64) * BSTR + aOff] = rb1;
        __syncthreads();
        cur = nxt;
    }
    mfma_step(As[cur], Bs[cur], wr, wc, m16, q, acc);
#pragma unroll
    for (int i = 0; i < 2; i++)
#pragma unroll
        for (int r = 0; r < 4; r++) {
            int pos = o + m0 + wr + i * 16 + q * 4 + r;
            if (pos < o + c) {
#pragma unroll
                for (int j = 0; j < 4; j++)
                    qpart[((size_t)s * NPAD + pos) * HD + wc + j * 16 + m16] = acc[i][j][r];
            }
        }
}

__global__ void q_reduce(const float* __restrict__ qpart, const float* __restrict__ qb,
                         const int* __restrict__ aidx, const int* __restrict__ list,
                         ushort* __restrict__ Qg) {
    int pos = blockIdx.x, h = threadIdx.x;  // 128
    int e = aidx[list[pos]];
    float a = qb[e * HD + h];
#pragma unroll
    for (int s = 0; s < 4; s++) a += qpart[((size_t)s * NPAD + pos) * HD + h];
    Qg[(size_t)pos * HD + h] = f2b(a * QSCALE);
}

// ---------------- Rel-pos dots (bf16 Q) ----------------
__global__ void rel_kernel(const ushort* __restrict__ Qg, const float* __restrict__ rel,
                           float* __restrict__ R) {
    int pos = blockIdx.x;
    __shared__ float qsh[HD];
    if (threadIdx.x < HD) qsh[threadIdx.x] = b2f(Qg[(size_t)pos * HD + threadIdx.x]);
    __syncthreads();
    int r = threadIdx.x;
    if (r < RNUM) {
        const float4* rr = (const float4*)(rel + r * HD);
        const float4* qv = (const float4*)qsh;
        float a = 0.f;
#pragma unroll
        for (int h4 = 0; h4 < HD / 4; h4++) {
            float4 rv = rr[h4], qa = qv[h4];
            a += qa.x * rv.x + qa.y * rv.y + qa.z * rv.z + qa.w * rv.w;
        }
        R[(size_t)pos * RSTRIDE + r] = a;
    }
}

// ---------------- s: MFMA QK^T + rel bias, fp32 S out ----------------
__global__ __launch_bounds__(256) void s_mfma(
    const ushort* __restrict__ Qg, const float* __restrict__ kbf,
    const float* __restrict__ R, const int* __restrict__ meta,
    const int* __restrict__ list, float* __restrict__ S) {
    int bin = blockIdx.z;
    int o = meta[32 + bin], c = meta[bin];
    int m0 = blockIdx.x * 64;
    if (m0 >= c) return;
    int b = bin & 3;
    int n0 = blockIdx.y * 128;
    __shared__ __align__(16) short As[2][64 * BSTR];
    __shared__ __align__(16) short Bs[2][128 * BSTR];
    int tid = threadIdx.x, aRow = tid >> 2, aOff = (tid & 3) * 8;
    const ushort* ap = Qg + (size_t)(o + m0 + aRow) * HD + aOff;
    const float* bp0 = kbf + (size_t)b * SEQ * HD + (size_t)(n0 + aRow) * HD + aOff;
    const float* bp1 = bp0 + (size_t)64 * HD;
    int w = tid >> 6, lid = tid & 63;
    int wr = (w >> 1) * 32, wc = (w & 1) * 64;
    int m16 = lid & 15, q = lid >> 4;
    f32x4 acc[2][4] = {};
    u16x8 ra = *(const u16x8*)ap;
    float4 rb0a = *(const float4*)bp0, rb0b = *(const float4*)(bp0 + 4);
    float4 rb1a = *(const float4*)bp1, rb1b = *(const float4*)(bp1 + 4);
    *(u16x8*)&As[0][aRow * BSTR + aOff] = ra;
    *(u16x8*)&Bs[0][aRow * BSTR + aOff] = cvt8v(rb0a, rb0b);
    *(u16x8*)&Bs[0][(aRow + 64) * BSTR + aOff] = cvt8v(rb1a, rb1b);
    __syncthreads();
    int cur = 0;
    for (int k = 1; k < 4; k++) {
        ra = *(const u16x8*)(ap + k * 32);
        rb0a = *(const float4*)(bp0 + k * 32); rb0b = *(const float4*)(bp0 + k * 32 + 4);
        rb1a = *(const float4*)(bp1 + k * 32); rb1b = *(const float4*)(bp1 + k * 32 + 4);
        mfma_step(As[cur], Bs[cur], wr, wc, m16, q, acc);
        int nxt = cur ^ 1;
        *(u16x8*)&As[nxt][aRow * BSTR + aOff] = ra;
        *(u16x8*)&Bs[nxt][aRow * BSTR + aOff] = cvt8v(rb0a, rb0b);
        *(u16x8*)&Bs[nxt][(aRow + 64) * BSTR + aOff] = cvt8v(rb1a, rb1b);
        __syncthreads();
        cur = nxt;
    }
    mfma_step(As[cur], Bs[cur], wr, wc, m16, q, acc);
#pragma unroll
    for (int i = 0; i < 2; i++)
#pragma unroll
        for (int r = 0; r < 4; r++) {
            int pos = o + m0 + wr + i * 16 + q * 4 + r;
            if (pos < o + c) {
                int qpos = (list[pos] >> 1) & (SEQ - 1);
                const float* Rrow = R + (size_t)pos * RSTRIDE;
                float* sr = S + (size_t)pos * SEQ;
#pragma unroll
                for (int j = 0; j < 4; j++) {
                    int key = n0 + wc + j * 16 + m16;
                    int rix = key - qpos;
                    rix = (rix < -MAXPOS ? -MAXPOS : (rix > MAXPOS ? MAXPOS : rix)) + MAXPOS;
                    sr[key] = acc[i][j][r] + Rrow[rix];
                }
            }
        }
}

// ---------------- Row softmax (fp32 in place) ----------------
__global__ __launch_bounds__(256) void softmax_kernel(float* __restrict__ S) {
    int row = blockIdx.x;
    float4* sr = (float4*)(S + (size_t)row * SEQ);
    float4 v = sr[threadIdx.x];
    float m = fmaxf(fmaxf(v.x, v.y), fmaxf(v.z, v.w));
#pragma unroll
    for (int off = 32; off; off >>= 1) m = fmaxf(m, __shfl_down(m, off));
    __shared__ float red0[4], red1[4];
    int wave = threadIdx.x >> 6, lane = threadIdx.x & 63;
    if (lane == 0) red0[wave] = m;
    __syncthreads();
    m = fmaxf(fmaxf(red0[0], red0[1]), fmaxf(red0[2], red0[3]));
    v.x = __expf(v.x - m); v.y = __expf(v.y - m);
    v.z = __expf(v.z - m); v.w = __expf(v.w - m);
    float s = v.x + v.y + v.z + v.w;
#pragma unroll
    for (int off = 32; off; off >>= 1) s += __shfl_down(s, off);
    if (lane == 0) red1[wave] = s;
    __syncthreads();
    float inv = 1.f / (red1[0] + red1[1] + red1[2] + red1[3]);
    v.x *= inv; v.y *= inv; v.z *= inv; v.w *= inv;
    sr[threadIdx.x] = v;
}

// ---------------- pv: split-K MFMA P@V, dense partials ----------------
__global__ __launch_bounds__(256) void pv_mfma(
    const float* __restrict__ S, const ushort* __restrict__ vt16,
    const int* __restrict__ meta, float* __restrict__ ppart) {
    int bin = blockIdx.z;
    int o = meta[32 + bin], c = meta[bin];
    int m0 = blockIdx.x * 64;
    if (m0 >= c) return;
    int b = bin & 3;
    int s = blockIdx.y;
    int kbase = s * 256;
    __shared__ __align__(16) short As[2][64 * BSTR];
    __shared__ __align__(16) short Bs[2][128 * BSTR];
    int tid = threadIdx.x, aRow = tid >> 2, aOff = (tid & 3) * 8;
    const float* ap = S + (size_t)(o + m0 + aRow) * SEQ + kbase + aOff;
    const ushort* bp0 = vt16 + (size_t)b * HD * SEQ + (size_t)aRow * SEQ + kbase + aOff;
    const ushort* bp1 = bp0 + (size_t)64 * SEQ;
    int w = tid >> 6, lid = tid & 63;
    int wr = (w >> 1) * 32, wc = (w & 1) * 64;
    int m16 = lid & 15, q = lid >> 4;
    f32x4 acc[2][4] = {};
    float4 ra0 = *(const float4*)ap, ra1 = *(const float4*)(ap + 4);
    u16x8 rb0 = *(const u16x8*)bp0, rb1 = *(const u16x8*)bp1;
    *(u16x8*)&As[0][aRow * BSTR + aOff] = cvt8v(ra0, ra1);
    *(u16x8*)&Bs[0][aRow * BSTR + aOff] = rb0;
    *(u16x8*)&Bs[0][(aRow + 64) * BSTR + aOff] = rb1;
    __syncthreads();
    int cur = 0;
    for (int k = 1; k < 8; k++) {
        ra0 = *(const float4*)(ap + k * 32); ra1 = *(const float4*)(ap + k * 32 + 4);
        rb0 = *(const u16x8*)(bp0 + k * 32); rb1 = *(const u16x8*)(bp1 + k * 32);
        mfma_step(As[cur], Bs[cur], wr, wc, m16, q, acc);
        int nxt = cur ^ 1;
        *(u16x8*)&As[nxt][aRow * BSTR + aOff] = cvt8v(ra0, ra1);
        *(u16x8*)&Bs[nxt][aRow * BSTR + aOff] = rb0;
        *(u16x8*)&Bs[nxt][(aRow + 64) * BSTR + aOff] = rb1;
        __syncthreads();
        cur = nxt;
    }
    mfma_step(As[cur], Bs[cur], wr, wc, m16, q, acc);
#pragma unroll
    for (int i = 0; i < 2; i++)
#pragma unroll
        for (int r = 0; r < 4; r++) {
            int pos = o + m0 + wr + i * 16 + q * 4 + r;
            if (pos < o + c) {
#pragma unroll
                for (int j = 0; j < 4; j++)
                    ppart[((size_t)s * NPAD + pos) * HD + wc + j * 16 + m16] = acc[i][j][r];
            }
        }
}

__global__ void pv_reduce(const float* __restrict__ ppart, const float* __restrict__ aga,
                          const int* __restrict__ list, float* __restrict__ ctxf) {
    int pos = blockIdx.x, h = threadIdx.x;  // 128
    float g = aga[list[pos]];
    float a = 0.f;
#pragma unroll
    for (int s = 0; s < 4; s++) a += ppart[((size_t)s * NPAD + pos) * HD + h];
    ctxf[(size_t)pos * HD + h] = a * g;
}

// ---------------- o: MFMA ctx@o_w, dense bf16 per-pair rows ----------------
__global__ __launch_bounds__(256) void o_mfma(
    const float* __restrict__ ctxf, const ushort* __restrict__ owt,
    const int* __restrict__ meta, ushort* __restrict__ Ofb) {
    int e = blockIdx.z;
    int o = meta[96 + e], c = meta[97 + e] - o;
    int m0 = blockIdx.x * 64;
    if (m0 >= c) return;
    int n0 = blockIdx.y * 128;
    __shared__ __align__(16) short As[2][64 * BSTR];
    __shared__ __align__(16) short Bs[2][128 * BSTR];
    int tid = threadIdx.x, aRow = tid >> 2, aOff = (tid & 3) * 8;
    const float* ap = ctxf + (size_t)(o + m0 + aRow) * HD + aOff;
    const ushort* bp0 = owt + (size_t)e * D * HD + (size_t)(n0 + aRow) * HD + aOff;
    const ushort* bp1 = bp0 + (size_t)64 * HD;
    int w = tid >> 6, lid = tid & 63;
    int wr = (w >> 1) * 32, wc = (w & 1) * 64;
    int m16 = lid & 15, q = lid >> 4;
    f32x4 acc[2][4] = {};
    float4 ra0 = *(const float4*)ap, ra1 = *(const float4*)(ap + 4);
    u16x8 rb0 = *(const u16x8*)bp0, rb1 = *(const u16x8*)bp1;
    *(u16x8*)&As[0][aRow * BSTR + aOff] = cvt8v(ra0, ra1);
    *(u16x8*)&Bs[0][aRow * BSTR + aOff] = rb0;
    *(u16x8*)&Bs[0][(aRow + 64) * BSTR + aOff] = rb1;
    __syncthreads();
    int cur = 0;
    for (int k = 1; k < 4; k++) {
        ra0 = *(const float4*)(ap + k * 32); ra1 = *(const float4*)(ap + k * 32 + 4);
        rb0 = *(const u16x8*)(bp0 + k * 32); rb1 = *(const u16x8*)(bp1 + k * 32);
        mfma_step(As[cur], Bs[cur], wr, wc, m16, q, acc);
        int nxt = cur ^ 1;
        *(u16x8*)&As[nxt][aRow * BSTR + aOff] = cvt8v(ra0, ra1);
        *(u16x8*)&Bs[nxt][aRow * BSTR + aOff] = rb0;
        *(u16x8*)&Bs[nxt][(aRow + 64) * BSTR + aOff] = rb1;
        __syncthreads();
        cur = nxt;
    }
    mfma_step(As[cur], Bs[cur], wr, wc, m16, q, acc);
#pragma unroll
    for (int i = 0; i < 2; i++)
#pragma unroll
        for (int r = 0; r < 4; r++) {
            int pos = o + m0 + wr + i * 16 + q * 4 + r;
            if (pos < o + c) {
#pragma unroll
                for (int j = 0; j < 4; j++)
                    Ofb[(size_t)pos * D + n0 + wc + j * 16 + m16] = f2b(acc[i][j][r]);
            }
        }
}

// ---------------- attn combine ----------------
__global__ void attn_combine(const float* __restrict__ src, const float* __restrict__ ob,
                             const int* __restrict__ aidx, const float* __restrict__ aga,
                             const int* __restrict__ ainv, const ushort* __restrict__ Ofb,
                             float* __restrict__ x1) {
    int t = blockIdx.x, tid = threadIdx.x;
    int e0 = aidx[t * 2], e1 = aidx[t * 2 + 1];
    float g0 = aga[t * 2], g1 = aga[t * 2 + 1];
    int p0 = ainv[t * 2], p1 = ainv[t * 2 + 1];
#pragma unroll
    for (int i = 0; i < 4; i++) {
        int d = tid + i * 256;
        x1[(size_t)t * D + d] = src[(size_t)t * D + d]
                              + g0 * ob[e0 * D + d] + g1 * ob[e1 * D + d]
                              + b2f(Ofb[(size_t)p0 * D + d]) + b2f(Ofb[(size_t)p1 * D + d]);
    }
}

// ---------------- FFN GEMM1: Hb = g*relu(xn2 @ W1 + b1) ----------------
__global__ __launch_bounds__(256) void ffn_mfma1(
    const float* __restrict__ xn2, const ushort* __restrict__ w1t,
    const float* __restrict__ b1, const int* __restrict__ meta,
    const int* __restrict__ list, const float* __restrict__ fga,
    ushort* __restrict__ Hb) {
    int e = blockIdx.z;
    int o = meta[16 + e], c = meta[e];
    int m0 = blockIdx.x * 64;
    if (m0 >= c) return;
    int n0 = blockIdx.y * 128;
    __shared__ __align__(16) short As[2][64 * BSTR];
    __shared__ __align__(16) short Bs[2][128 * BSTR];
    int tid = threadIdx.x, aRow = tid >> 2, aOff = (tid & 3) * 8;
    int ri = o + m0 + aRow; if (ri > NPAIR - 1) ri = NPAIR - 1;
    const float* ap = xn2 + (size_t)(list[ri] >> 1) * D + aOff;
    const ushort* bp0 = w1t + ((size_t)e * FH + n0 + aRow) * D + aOff;
    const ushort* bp1 = bp0 + (size_t)64 * D;
    int w = tid >> 6, lid = tid & 63;
    int wr = (w >> 1) * 32, wc = (w & 1) * 64;
    int m16 = lid & 15, q = lid >> 4;
    f32x4 acc[2][4] = {};
    float4 ra0 = *(const float4*)ap, ra1 = *(const float4*)(ap + 4);
    u16x8 rb0 = *(const u16x8*)bp0, rb1 = *(const u16x8*)bp1;
    *(u16x8*)&As[0][aRow * BSTR + aOff] = cvt8v(ra0, ra1);
    *(u16x8*)&Bs[0][aRow * BSTR + aOff] = rb0;
    *(u16x8*)&Bs[0][(aRow + 64) * BSTR + aOff] = rb1;
    __syncthreads();
    int cur = 0;
    for (int k = 1; k < 32; k++) {
        ra0 = *(const float4*)(ap + k * 32); ra1 = *(const float4*)(ap + k * 32 + 4);
        rb0 = *(const u16x8*)(bp0 + k * 32); rb1 = *(const u16x8*)(bp1 + k * 32);
        mfma_step(As[cur], Bs[cur], wr, wc, m16, q, acc);
        int nxt = cur ^ 1;
        *(u16x8*)&As[nxt][aRow * BSTR + aOff] = cvt8v(ra0, ra1);
        *(u16x8*)&Bs[nxt][aRow * BSTR + aOff] = rb0;
        *(u16x8*)&Bs[nxt][(aRow + 64) * BSTR + aOff] = rb1;
        __syncthreads();
        cur = nxt;
    }
    mfma_step(As[cur], Bs[cur], wr, wc, m16, q, acc);
#pragma unroll
    for (int i = 0; i < 2; i++)
#pragma unroll
        for (int r = 0; r < 4; r++) {
            int pos = o + m0 + wr + i * 16 + q * 4 + r;
            if (pos < o + c) {
                float g = fga[list[pos]];
#pragma unroll
                for (int j = 0; j < 4; j++) {
                    int n = n0 + wc + j * 16 + m16;
                    Hb[(size_t)pos * FH + n] = f2b(g * fmaxf(acc[i][j][r] + b1[e * FH + n], 0.f));
                }
            }
        }
}

// ---------------- FFN GEMM2: Of2b[pos] = Hb @ W2 (dense bf16 rows) ----------------
__global__ __launch_bounds__(256) void ffn_mfma2(
    const ushort* __restrict__ Hb, const ushort* __restrict__ w2t,
    const int* __restrict__ meta, ushort* __restrict__ Of2b) {
    int e = blockIdx.z;
    int o = meta[16 + e], c = meta[e];
    int m0 = blockIdx.x * 64;
    if (m0 >= c) return;
    int n0 = blockIdx.y * 128;
    __shared__ __align__(16) short As[2][64 * BSTR];
    __shared__ __align__(16) short Bs[2][128 * BSTR];
    int tid = threadIdx.x, aRow = tid >> 2, aOff = (tid & 3) * 8;
    const ushort* ap = Hb + (size_t)(o + m0 + aRow) * FH + aOff;
    const ushort* bp0 = w2t + ((size_t)e * D + n0 + aRow) * FH + aOff;
    const ushort* bp1 = bp0 + (size_t)64 * FH;
    int w = tid >> 6, lid = tid & 63;
    int wr = (w >> 1) * 32, wc = (w & 1) * 64;
    int m16 = lid & 15, q = lid >> 4;
    f32x4 acc[2][4] = {};
    u16x8 ra = *(const u16x8*)ap;
    u16x8 rb0 = *(const u16x8*)bp0, rb1 = *(const u16x8*)bp1;
    *(u16x8*)&As[0][aRow * BSTR + aOff] = ra;
    *(u16x8*)&Bs[0][aRow * BSTR + aOff] = rb0;
    *(u16x8*)&Bs[0][(aRow + 64) * BSTR + aOff] = rb1;
    __syncthreads();
    int cur = 0;
    for (int k = 1; k < 16; k++) {
        ra = *(const u16x8*)(ap + k * 32);
        rb0 = *(const u16x8*)(bp0 + k * 32); rb1 = *(const u16x8*)(bp1 + k * 32);
        mfma_step(As[cur], Bs[cur], wr, wc, m16, q, acc);
        int nxt = cur ^ 1;
        *(u16x8*)&As[nxt][aRow * BSTR + aOff] = ra;
        *(u16x8*)&Bs[nxt][aRow * BSTR + aOff] = rb0;
        *(u16x8*)&Bs[nxt][(aRow + 64) * BSTR + aOff] = rb1;
        __syncthreads();
        cur = nxt;
    }
    mfma_step(As[cur], Bs[cur], wr, wc, m16, q, acc);
#pragma unroll
    for (int i = 0; i < 2; i++)
#pragma unroll
        for (int r = 0; r < 4; r++) {
            int pos = o + m0 + wr + i * 16 + q * 4 + r;
            if (pos < o + c) {
#pragma unroll
                for (int j = 0; j < 4; j++)
                    Of2b[(size_t)pos * D + n0 + wc + j * 16 + m16] = f2b(acc[i][j][r]);
            }
        }
}

// ---------------- FFN combine ----------------
__global__ void ffn_combine(const float* __restrict__ x1, const float* __restrict__ b2,
                            const int* __restrict__ fidx, const float* __restrict__ fga,
                            const int* __restrict__ finv, const ushort* __restrict__ Of2b,
                            float* __restrict__ out) {
    int t = blockIdx.x, tid = threadIdx.x;
    int e0 = fidx[t * 2], e1 = fidx[t * 2 + 1];
    float g0 = fga[t * 2], g1 = fga[t * 2 + 1];
    int p0 = finv[t * 2], p1 = finv[t * 2 + 1];
#pragma unroll
    for (int i = 0; i < 4; i++) {
        int d = tid + i * 256;
        out[(size_t)t * D + d] = x1[(size_t)t * D + d]
                               + g0 * b2[e0 * D + d] + g1 * b2[e1 * D + d]
                               + b2f(Of2b[(size_t)p0 * D + d]) + b2f(Of2b[(size_t)p1 * D + d]);
    }
}

extern "C" void kernel_launch(void* const* d_in, const int* in_sizes, int n_in,
                              void* d_out, int out_size, void* d_ws, size_t ws_size,
                              hipStream_t stream) {
    const float* src   = (const float*)d_in[0];
    const float* ln1_w = (const float*)d_in[1];
    const float* ln1_b = (const float*)d_in[2];
    const float* ln2_w = (const float*)d_in[3];
    const float* ln2_b = (const float*)d_in[4];
    const float* agw   = (const float*)d_in[5];
    const float* qw    = (const float*)d_in[6];
    const float* qb    = (const float*)d_in[7];
    const float* kw    = (const float*)d_in[8];
    const float* kb    = (const float*)d_in[9];
    const float* vw    = (const float*)d_in[10];
    const float* vb    = (const float*)d_in[11];
    const float* ow    = (const float*)d_in[12];
    const float* ob    = (const float*)d_in[13];
    const float* rel   = (const float*)d_in[14];
    const float* fgw   = (const float*)d_in[15];
    const float* w1    = (const float*)d_in[16];
    const float* b1    = (const float*)d_in[17];
    const float* w2    = (const float*)d_in[18];
    const float* b2    = (const float*)d_in[19];
    float* out = (float*)d_out;

    char* p = (char*)d_ws;
    float* xn1  = (float*)p; p += (size_t)NTOK * D * 4;               // LN out (both LNs)
    float* x1   = (float*)p; p += (size_t)NTOK * D * 4;
    char*  sreg = p;         p += (size_t)NPAD * SEQ * 4;             // 34.1 MB
    float*  Sbuf = (float*)sreg;                                      // attn: scores/P
    ushort* Ofb  = (ushort*)sreg;                                     // attn: o rows (17 MB)
    ushort* w1t  = (ushort*)sreg;                                     // FFN: 16.78 MB
    ushort* w2t  = (ushort*)(sreg + (size_t)16777216);                // FFN: 16.78 MB
    char*  reg  = p;         p += (size_t)NPAD * 128 * 6 + (size_t)NPAIR * RSTRIDE * 4;
    float*  ctxf = (float*)reg;                                       // 4.26 MB
    ushort* Qg   = (ushort*)(reg + (size_t)NPAD * 128 * 4);           // 2.13 MB
    float*  Rbuf = (float*)(reg + (size_t)NPAD * 128 * 6);            // 4.33 MB
    ushort* Hb   = (ushort*)reg;                                      // FFN hidden (8.52 MB)
    char*  arena = p;        p += (size_t)4 * NPAD * 128 * 4;         // 17.04 MB
    float*  kpart = (float*)arena;
    float*  vpart = (float*)(arena + (size_t)4 * NTOK * HD * 4);
    float*  qpart = (float*)arena;
    float*  ppart = (float*)arena;
    ushort* Of2b  = (ushort*)arena;
    float* kbf  = (float*)p; p += (size_t)NTOK * HD * 4;
    float* vbf  = (float*)p; p += (size_t)NTOK * HD * 4;
    ushort* vt16 = (ushort*)p; p += (size_t)NTOK * HD * 2;
    ushort* kwt = (ushort*)p; p += (size_t)HD * D * 2;
    ushort* vwt = (ushort*)p; p += (size_t)HD * D * 2;
    ushort* qwt = (ushort*)p; p += (size_t)EA * HD * D * 2;
    ushort* owt = (ushort*)p; p += (size_t)EA * D * HD * 2;
    int*   aidx = (int*)p;   p += NPAIR * 4;
    float* aga  = (float*)p; p += NPAIR * 4;
    int*   fidx = (int*)p;   p += NPAIR * 4;
    float* fga  = (float*)p; p += NPAIR * 4;
    int*   ameta = (int*)p;  p += 128 * 4;
    int*   alist = (int*)p;  p += NPAIR * 4;
    int*   ainv = (int*)p;   p += NPAIR * 4;
    int*   fmeta = (int*)p;  p += 64 * 4;
    int*   flist = (int*)p;  p += NPAIR * 4;
    int*   finv = (int*)p;   p += NPAIR * 4;
    float* xn2 = xn1;

    // ---- attention ----
    ln_kernel<<<NTOK, 256, 0, stream>>>(src, ln1_w, ln1_b, xn1);
    router_kernel<EA><<<NTOK, 64, 0, stream>>>(xn1, agw, aidx, aga);
    abin_zero<<<1, 128, 0, stream>>>(ameta);
    abin_count<<<NPAIR / 256, 256, 0, stream>>>(aidx, ameta);
    abin_scan<<<1, 64, 0, stream>>>(ameta);
    abin_scatter<<<NPAIR / 256, 256, 0, stream>>>(aidx, ameta, alist, ainv);
    convT_kernel<1024, 128><<<dim3(32, 4, 1), 256, 0, stream>>>(kw, kwt);
    convT_kernel<1024, 128><<<dim3(32, 4, 1), 256, 0, stream>>>(vw, vwt);
    convT_kernel<1024, 128><<<dim3(32, 4, EA), 256, 0, stream>>>(qw, qwt);
    convT_kernel<128, 1024><<<dim3(4, 32, EA), 256, 0, stream>>>(ow, owt);
    kv_mfma<<<dim3(64, 4, 2), 256, 0, stream>>>(xn1, kwt, vwt, kpart, vpart);
    kv_reduce<<<NTOK, 128, 0, stream>>>(kpart, vpart, kb, vb, kbf, vbf);
    convT_kernel<1024, 128><<<dim3(32, 4, 4), 256, 0, stream>>>(vbf, vt16);
    q_mfma<<<dim3(40, 4, EA), 256, 0, stream>>>(xn1, qwt, ameta, alist, qpart);
    q_reduce<<<NPAIR, 128, 0, stream>>>(qpart, qb, aidx, alist, Qg);
    rel_kernel<<<NPAIR, 192, 0, stream>>>(Qg, rel, Rbuf);
    s_mfma<<<dim3(12, 8, 32), 256, 0, stream>>>(Qg, kbf, Rbuf, ameta, alist, Sbuf);
    softmax_kernel<<<NPAIR, 256, 0, stream>>>(Sbuf);
    pv_mfma<<<dim3(12, 4, 32), 256, 0, stream>>>(Sbuf, vt16, ameta, ppart);
    pv_reduce<<<NPAIR, 128, 0, stream>>>(ppart, aga, alist, ctxf);
    o_mfma<<<dim3(40, 8, EA), 256, 0, stream>>>(ctxf, owt, ameta, Ofb);
    attn_combine<<<NTOK, 256, 0, stream>>>(src, ob, aidx, aga, ainv, Ofb, x1);

    // ---- FFN ----
    ln_kernel<<<NTOK, 256, 0, stream>>>(x1, ln2_w, ln2_b, xn2);
    router_kernel<EF><<<NTOK, 64, 0, stream>>>(xn2, fgw, fidx, fga);
    bin_zero<<<1, 64, 0, stream>>>(fmeta);
    bin_count<<<NPAIR / 256, 256, 0, stream>>>(fidx, fmeta);
    bin_scan<<<1, 64, 0, stream>>>(fmeta);
    bin_scatter<<<NPAIR / 256, 256, 0, stream>>>(fidx, fmeta, flist, finv);
    convT_kernel<1024, 512><<<dim3(32, 16, EF), 256, 0, stream>>>(w1, w1t);
    convT_kernel<512, 1024><<<dim3(16, 32, EF), 256, 0, stream>>>(w2, w2t);
    ffn_mfma1<<<dim3(20, 4, EF), 256, 0, stream>>>(xn2, w1t, b1, fmeta, flist, fga, Hb);
    ffn_mfma2<<<dim3(20, 8, EF), 256, 0, stream>>>(Hb, w2t, fmeta, Of2b);
    ffn_combine<<<NTOK, 256, 0, stream>>>(x1, b2, fidx, fga, finv, Of2b, out);
}

// Round 8
// 518.669 us; speedup vs baseline: 9.9811x; 1.1254x over previous
//
#include <hip/hip_runtime.h>

#define D 1024
#define HD 128
#define EA 8
#define EF 16
#define FH 512
#define MAXPOS 64
#define RNUM 129
#define RSTRIDE 132
#define SEQ 1024
#define NTOK 4096
#define NPAIR (NTOK * 2)
#define NPAD 8320          // NPAIR + 128 slack
#define LN_EPS 1e-5f
#define QSCALE 0.08838834764831845f
#define BSTR 40            // LDS row stride in bf16 elems
#define PROW 2048          // bf16 P row stride in ushorts (= SEQ*4B slot)

typedef __attribute__((ext_vector_type(8))) short bf16x8;
typedef __attribute__((ext_vector_type(4))) float f32x4;
typedef __attribute__((ext_vector_type(8))) unsigned short u16x8;

__device__ inline ushort f2b(float f) {
    union { float f; unsigned u; } v; v.f = f;
    unsigned r = (v.u + 0x7fffu + ((v.u >> 16) & 1u)) >> 16;
    return (ushort)r;
}
__device__ inline float b2f(ushort u) {
    union { unsigned u; float f; } v; v.u = (unsigned)u << 16; return v.f;
}
__device__ inline u16x8 cvt8v(float4 a, float4 b) {
    u16x8 r;
    r[0] = f2b(a.x); r[1] = f2b(a.y); r[2] = f2b(a.z); r[3] = f2b(a.w);
    r[4] = f2b(b.x); r[5] = f2b(b.y); r[6] = f2b(b.z); r[7] = f2b(b.w);
    return r;
}

// one double-buffer compute step: 64x128 tile, wave = 32x64
__device__ inline void mfma_step(const short* Asb, const short* Bsb,
                                 int wr, int wc, int m16, int q, f32x4 (&acc)[2][4]) {
    bf16x8 af[2], bfr[4];
#pragma unroll
    for (int i = 0; i < 2; i++) af[i] = *(const bf16x8*)&Asb[(wr + i * 16 + m16) * BSTR + q * 8];
#pragma unroll
    for (int j = 0; j < 4; j++) bfr[j] = *(const bf16x8*)&Bsb[(wc + j * 16 + m16) * BSTR + q * 8];
#pragma unroll
    for (int i = 0; i < 2; i++)
#pragma unroll
        for (int j = 0; j < 4; j++)
            acc[i][j] = __builtin_amdgcn_mfma_f32_16x16x32_bf16(af[i], bfr[j], acc[i][j], 0, 0, 0);
}

// ---------------- LayerNorm ----------------
__global__ void ln_kernel(const float* __restrict__ x, const float* __restrict__ w,
                          const float* __restrict__ b, float* __restrict__ y) {
    int row = blockIdx.x;
    const float* xr = x + (size_t)row * D;
    float v[4];
    float s = 0.f, s2 = 0.f;
#pragma unroll
    for (int i = 0; i < 4; i++) {
        v[i] = xr[threadIdx.x + i * 256];
        s += v[i]; s2 += v[i] * v[i];
    }
#pragma unroll
    for (int off = 32; off; off >>= 1) { s += __shfl_down(s, off); s2 += __shfl_down(s2, off); }
    __shared__ float red0[4], red1[4];
    int wave = threadIdx.x >> 6, lane = threadIdx.x & 63;
    if (lane == 0) { red0[wave] = s; red1[wave] = s2; }
    __syncthreads();
    float ts = red0[0] + red0[1] + red0[2] + red0[3];
    float ts2 = red1[0] + red1[1] + red1[2] + red1[3];
    float mu = ts * (1.f / D);
    float var = ts2 * (1.f / D) - mu * mu;
    float inv = rsqrtf(var + LN_EPS);
#pragma unroll
    for (int i = 0; i < 4; i++) {
        int d = threadIdx.x + i * 256;
        y[(size_t)row * D + d] = (v[i] - mu) * inv * w[d] + b[d];
    }
}

// ---------------- Router ----------------
template <int E>
__global__ void router_kernel(const float* __restrict__ xn, const float* __restrict__ gw,
                              int* __restrict__ idx, float* __restrict__ gate) {
    int t = blockIdx.x;
    int lane = threadIdx.x;  // block=64
    float acc[E];
#pragma unroll
    for (int e = 0; e < E; e++) acc[e] = 0.f;
    const float* xr = xn + (size_t)t * D;
    for (int d = lane; d < D; d += 64) {
        float xv = xr[d];
#pragma unroll
        for (int e = 0; e < E; e++) acc[e] += xv * gw[d * E + e];
    }
#pragma unroll
    for (int e = 0; e < E; e++) {
#pragma unroll
        for (int off = 32; off; off >>= 1) acc[e] += __shfl_down(acc[e], off);
    }
    if (lane == 0) {
        float v0 = -1e30f, v1 = -1e30f;
        int i0 = 0, i1 = 0;
#pragma unroll
        for (int e = 0; e < E; e++) {
            float a = acc[e];
            if (a > v0) { v1 = v0; i1 = i0; v0 = a; i0 = e; }
            else if (a > v1) { v1 = a; i1 = e; }
        }
        float g0 = 1.f / (1.f + expf(v1 - v0));
        idx[t * 2] = i0; idx[t * 2 + 1] = i1;
        gate[t * 2] = g0; gate[t * 2 + 1] = 1.f - g0;
    }
}

// ---------------- Attention binning: 32 bins keyed (expert*4 + batch) ----------------
__global__ void abin_zero(int* __restrict__ meta) {
    if (threadIdx.x < 105) meta[threadIdx.x] = 0;
}
__global__ void abin_count(const int* __restrict__ aidx, int* __restrict__ meta) {
    int i = blockIdx.x * 256 + threadIdx.x;
    if (i < NPAIR) {
        int e = aidx[i];
        int b = (i >> 1) >> 10;
        atomicAdd(&meta[e * 4 + b], 1);
    }
}
__global__ void abin_scan(int* __restrict__ meta) {
    if (threadIdx.x == 0 && blockIdx.x == 0) {
        int s = 0;
        for (int bin = 0; bin < 32; bin++) {
            if ((bin & 3) == 0) meta[96 + (bin >> 2)] = s;
            meta[32 + bin] = s; meta[64 + bin] = s; s += meta[bin];
        }
        meta[96 + 8] = s;
    }
}
__global__ void abin_scatter(const int* __restrict__ aidx, int* __restrict__ meta,
                             int* __restrict__ list, int* __restrict__ inv) {
    int i = blockIdx.x * 256 + threadIdx.x;
    if (i < NPAIR) {
        int e = aidx[i];
        int b = (i >> 1) >> 10;
        int pos = atomicAdd(&meta[64 + e * 4 + b], 1);
        list[pos] = i;
        inv[i] = pos;
    }
}

// ---------------- FFN binning ----------------
__global__ void bin_zero(int* __restrict__ meta) {
    if (threadIdx.x < 48) meta[threadIdx.x] = 0;
}
__global__ void bin_count(const int* __restrict__ fidx, int* __restrict__ meta) {
    int i = blockIdx.x * 256 + threadIdx.x;
    if (i < NPAIR) atomicAdd(&meta[fidx[i]], 1);
}
__global__ void bin_scan(int* __restrict__ meta) {
    if (threadIdx.x == 0 && blockIdx.x == 0) {
        int s = 0;
        for (int e = 0; e < EF; e++) { meta[16 + e] = s; meta[32 + e] = s; s += meta[e]; }
    }
}
__global__ void bin_scatter(const int* __restrict__ fidx, int* __restrict__ meta,
                            int* __restrict__ list, int* __restrict__ inv) {
    int i = blockIdx.x * 256 + threadIdx.x;
    if (i < NPAIR) {
        int e = fidx[i];
        int pos = atomicAdd(&meta[32 + e], 1);
        list[pos] = i;
        inv[i] = pos;
    }
}

// ---------------- transpose-convert [E][R][C] fp32 -> [E][C][R] bf16 ----------------
template <int R, int C>
__global__ void convT_kernel(const float* __restrict__ in, ushort* __restrict__ out) {
    int e = blockIdx.z;
    int r0 = blockIdx.x * 32, c0 = blockIdx.y * 32;
    __shared__ float tile[32][33];
    int tx = threadIdx.x & 31, ty = threadIdx.x >> 5;  // 256 thr
    const float* src = in + (size_t)e * R * C;
#pragma unroll
    for (int i = 0; i < 32; i += 8)
        tile[ty + i][tx] = src[(size_t)(r0 + ty + i) * C + c0 + tx];
    __syncthreads();
    ushort* dst = out + (size_t)e * C * R;
#pragma unroll
    for (int i = 0; i < 32; i += 8)
        dst[(size_t)(c0 + ty + i) * R + r0 + tx] = f2b(tile[tx][ty + i]);
}

// elementwise fp32 -> bf16 (small arrays)
__global__ void conv_kernel(const float* __restrict__ in, ushort* __restrict__ out, int n) {
    int i = blockIdx.x * 256 + threadIdx.x;
    if (i < n) out[i] = f2b(in[i]);
}

// ---------------- kv: split-K MFMA, dense per-split partials ----------------
__global__ __launch_bounds__(256) void kv_mfma(
    const float* __restrict__ xn, const ushort* __restrict__ kwt,
    const ushort* __restrict__ vwt, float* __restrict__ kpart, float* __restrict__ vpart) {
    const ushort* W = blockIdx.z ? vwt : kwt;
    float* outp = blockIdx.z ? vpart : kpart;
    int m0 = blockIdx.x * 64;
    int s = blockIdx.y;
    int kbase = s * 256;
    __shared__ __align__(16) short As[2][64 * BSTR];
    __shared__ __align__(16) short Bs[2][128 * BSTR];
    int tid = threadIdx.x, aRow = tid >> 2, aOff = (tid & 3) * 8;
    const float* ap = xn + (size_t)(m0 + aRow) * D + kbase + aOff;
    const ushort* bp0 = W + (size_t)aRow * D + kbase + aOff;
    const ushort* bp1 = bp0 + (size_t)64 * D;
    int w = tid >> 6, lid = tid & 63;
    int wr = (w >> 1) * 32, wc = (w & 1) * 64;
    int m16 = lid & 15, q = lid >> 4;
    f32x4 acc[2][4] = {};
    float4 ra0 = *(const float4*)ap, ra1 = *(const float4*)(ap + 4);
    u16x8 rb0 = *(const u16x8*)bp0, rb1 = *(const u16x8*)bp1;
    *(u16x8*)&As[0][aRow * BSTR + aOff] = cvt8v(ra0, ra1);
    *(u16x8*)&Bs[0][aRow * BSTR + aOff] = rb0;
    *(u16x8*)&Bs[0][(aRow + 64) * BSTR + aOff] = rb1;
    __syncthreads();
    int cur = 0;
    for (int k = 1; k < 8; k++) {
        ra0 = *(const float4*)(ap + k * 32); ra1 = *(const float4*)(ap + k * 32 + 4);
        rb0 = *(const u16x8*)(bp0 + k * 32); rb1 = *(const u16x8*)(bp1 + k * 32);
        mfma_step(As[cur], Bs[cur], wr, wc, m16, q, acc);
        int nxt = cur ^ 1;
        *(u16x8*)&As[nxt][aRow * BSTR + aOff] = cvt8v(ra0, ra1);
        *(u16x8*)&Bs[nxt][aRow * BSTR + aOff] = rb0;
        *(u16x8*)&Bs[nxt][(aRow + 64) * BSTR + aOff] = rb1;
        __syncthreads();
        cur = nxt;
    }
    mfma_step(As[cur], Bs[cur], wr, wc, m16, q, acc);
#pragma unroll
    for (int i = 0; i < 2; i++)
#pragma unroll
        for (int r = 0; r < 4; r++) {
            int m = m0 + wr + i * 16 + q * 4 + r;
#pragma unroll
            for (int j = 0; j < 4; j++)
                outp[((size_t)s * NTOK + m) * HD + wc + j * 16 + m16] = acc[i][j][r];
        }
}

__global__ void kv_reduce(const float* __restrict__ kpart, const float* __restrict__ vpart,
                          const float* __restrict__ kb, const float* __restrict__ vb,
                          float* __restrict__ kbf, float* __restrict__ vbf) {
    int t = blockIdx.x, h = threadIdx.x;  // 128
    float ka = kb[h], va = vb[h];
#pragma unroll
    for (int s = 0; s < 4; s++) {
        ka += kpart[((size_t)s * NTOK + t) * HD + h];
        va += vpart[((size_t)s * NTOK + t) * HD + h];
    }
    kbf[(size_t)t * HD + h] = ka;
    vbf[(size_t)t * HD + h] = va;
}

// ---------------- q: split-K MFMA, indirect A, dense partials ----------------
__global__ __launch_bounds__(256) void q_mfma(
    const float* __restrict__ xn, const ushort* __restrict__ qwt,
    const int* __restrict__ meta, const int* __restrict__ list, float* __restrict__ qpart) {
    int e = blockIdx.z;
    int o = meta[96 + e], c = meta[97 + e] - o;
    int m0 = blockIdx.x * 64;
    if (m0 >= c) return;
    int s = blockIdx.y;
    int kbase = s * 256;
    __shared__ __align__(16) short As[2][64 * BSTR];
    __shared__ __align__(16) short Bs[2][128 * BSTR];
    int tid = threadIdx.x, aRow = tid >> 2, aOff = (tid & 3) * 8;
    int ri = o + m0 + aRow; if (ri > NPAIR - 1) ri = NPAIR - 1;
    const float* ap = xn + (size_t)(list[ri] >> 1) * D + kbase + aOff;
    const ushort* bp0 = qwt + (size_t)e * HD * D + (size_t)aRow * D + kbase + aOff;
    const ushort* bp1 = bp0 + (size_t)64 * D;
    int w = tid >> 6, lid = tid & 63;
    int wr = (w >> 1) * 32, wc = (w & 1) * 64;
    int m16 = lid & 15, q = lid >> 4;
    f32x4 acc[2][4] = {};
    float4 ra0 = *(const float4*)ap, ra1 = *(const float4*)(ap + 4);
    u16x8 rb0 = *(const u16x8*)bp0, rb1 = *(const u16x8*)bp1;
    *(u16x8*)&As[0][aRow * BSTR + aOff] = cvt8v(ra0, ra1);
    *(u16x8*)&Bs[0][aRow * BSTR + aOff] = rb0;
    *(u16x8*)&Bs[0][(aRow + 64) * BSTR + aOff] = rb1;
    __syncthreads();
    int cur = 0;
    for (int k = 1; k < 8; k++) {
        ra0 = *(const float4*)(ap + k * 32); ra1 = *(const float4*)(ap + k * 32 + 4);
        rb0 = *(const u16x8*)(bp0 + k * 32); rb1 = *(const u16x8*)(bp1 + k * 32);
        mfma_step(As[cur], Bs[cur], wr, wc, m16, q, acc);
        int nxt = cur ^ 1;
        *(u16x8*)&As[nxt][aRow * BSTR + aOff] = cvt8v(ra0, ra1);
        *(u16x8*)&Bs[nxt][aRow * BSTR + aOff] = rb0;
        *(u16x8*)&Bs[nxt][(aRow + 64) * BSTR + aOff] = rb1;
        __syncthreads();
        cur = nxt;
    }
    mfma_step(As[cur], Bs[cur], wr, wc, m16, q, acc);
#pragma unroll
    for (int i = 0; i < 2; i++)
#pragma unroll
        for (int r = 0; r < 4; r++) {
            int pos = o + m0 + wr + i * 16 + q * 4 + r;
            if (pos < o + c) {
#pragma unroll
                for (int j = 0; j < 4; j++)
                    qpart[((size_t)s * NPAD + pos) * HD + wc + j * 16 + m16] = acc[i][j][r];
            }
        }
}

__global__ void q_reduce(const float* __restrict__ qpart, const float* __restrict__ qb,
                         const int* __restrict__ aidx, const int* __restrict__ list,
                         ushort* __restrict__ Qg) {
    int pos = blockIdx.x, h = threadIdx.x;  // 128
    int e = aidx[list[pos]];
    float a = qb[e * HD + h];
#pragma unroll
    for (int s = 0; s < 4; s++) a += qpart[((size_t)s * NPAD + pos) * HD + h];
    Qg[(size_t)pos * HD + h] = f2b(a * QSCALE);
}

// ---------------- rel: MFMA GEMM  R[pos][r] = Qg[pos] . rel[r] ----------------
__global__ __launch_bounds__(256) void rel_mfma(
    const ushort* __restrict__ Qg, const ushort* __restrict__ relb,
    float* __restrict__ R) {
    int m0 = blockIdx.x * 64;
    int n0 = blockIdx.y * 128;
    __shared__ __align__(16) short As[2][64 * BSTR];
    __shared__ __align__(16) short Bs[2][128 * BSTR];
    int tid = threadIdx.x, aRow = tid >> 2, aOff = (tid & 3) * 8;
    const ushort* ap = Qg + (size_t)(m0 + aRow) * HD + aOff;
    int br0 = n0 + aRow;      if (br0 > RNUM - 1) br0 = RNUM - 1;
    int br1 = n0 + aRow + 64; if (br1 > RNUM - 1) br1 = RNUM - 1;
    const ushort* bp0 = relb + (size_t)br0 * HD + aOff;
    const ushort* bp1 = relb + (size_t)br1 * HD + aOff;
    int w = tid >> 6, lid = tid & 63;
    int wr = (w >> 1) * 32, wc = (w & 1) * 64;
    int m16 = lid & 15, q = lid >> 4;
    f32x4 acc[2][4] = {};
    u16x8 ra = *(const u16x8*)ap;
    u16x8 rb0 = *(const u16x8*)bp0, rb1 = *(const u16x8*)bp1;
    *(u16x8*)&As[0][aRow * BSTR + aOff] = ra;
    *(u16x8*)&Bs[0][aRow * BSTR + aOff] = rb0;
    *(u16x8*)&Bs[0][(aRow + 64) * BSTR + aOff] = rb1;
    __syncthreads();
    int cur = 0;
    for (int k = 1; k < 4; k++) {
        ra = *(const u16x8*)(ap + k * 32);
        rb0 = *(const u16x8*)(bp0 + k * 32); rb1 = *(const u16x8*)(bp1 + k * 32);
        mfma_step(As[cur], Bs[cur], wr, wc, m16, q, acc);
        int nxt = cur ^ 1;
        *(u16x8*)&As[nxt][aRow * BSTR + aOff] = ra;
        *(u16x8*)&Bs[nxt][aRow * BSTR + aOff] = rb0;
        *(u16x8*)&Bs[nxt][(aRow + 64) * BSTR + aOff] = rb1;
        __syncthreads();
        cur = nxt;
    }
    mfma_step(As[cur], Bs[cur], wr, wc, m16, q, acc);
#pragma unroll
    for (int i = 0; i < 2; i++)
#pragma unroll
        for (int r = 0; r < 4; r++) {
            int pos = m0 + wr + i * 16 + q * 4 + r;
#pragma unroll
            for (int j = 0; j < 4; j++) {
                int n = n0 + wc + j * 16 + m16;
                if (n < RNUM) R[(size_t)pos * RSTRIDE + n] = acc[i][j][r];
            }
        }
}

// ---------------- s: MFMA QK^T + rel bias, fp32 S out ----------------
__global__ __launch_bounds__(256) void s_mfma(
    const ushort* __restrict__ Qg, const float* __restrict__ kbf,
    const float* __restrict__ R, const int* __restrict__ meta,
    const int* __restrict__ list, float* __restrict__ S) {
    int bin = blockIdx.z;
    int o = meta[32 + bin], c = meta[bin];
    int m0 = blockIdx.x * 64;
    if (m0 >= c) return;
    int b = bin & 3;
    int n0 = blockIdx.y * 128;
    __shared__ __align__(16) short As[2][64 * BSTR];
    __shared__ __align__(16) short Bs[2][128 * BSTR];
    int tid = threadIdx.x, aRow = tid >> 2, aOff = (tid & 3) * 8;
    const ushort* ap = Qg + (size_t)(o + m0 + aRow) * HD + aOff;
    const float* bp0 = kbf + (size_t)b * SEQ * HD + (size_t)(n0 + aRow) * HD + aOff;
    const float* bp1 = bp0 + (size_t)64 * HD;
    int w = tid >> 6, lid = tid & 63;
    int wr = (w >> 1) * 32, wc = (w & 1) * 64;
    int m16 = lid & 15, q = lid >> 4;
    f32x4 acc[2][4] = {};
    u16x8 ra = *(const u16x8*)ap;
    float4 rb0a = *(const float4*)bp0, rb0b = *(const float4*)(bp0 + 4);
    float4 rb1a = *(const float4*)bp1, rb1b = *(const float4*)(bp1 + 4);
    *(u16x8*)&As[0][aRow * BSTR + aOff] = ra;
    *(u16x8*)&Bs[0][aRow * BSTR + aOff] = cvt8v(rb0a, rb0b);
    *(u16x8*)&Bs[0][(aRow + 64) * BSTR + aOff] = cvt8v(rb1a, rb1b);
    __syncthreads();
    int cur = 0;
    for (int k = 1; k < 4; k++) {
        ra = *(const u16x8*)(ap + k * 32);
        rb0a = *(const float4*)(bp0 + k * 32); rb0b = *(const float4*)(bp0 + k * 32 + 4);
        rb1a = *(const float4*)(bp1 + k * 32); rb1b = *(const float4*)(bp1 + k * 32 + 4);
        mfma_step(As[cur], Bs[cur], wr, wc, m16, q, acc);
        int nxt = cur ^ 1;
        *(u16x8*)&As[nxt][aRow * BSTR + aOff] = ra;
        *(u16x8*)&Bs[nxt][aRow * BSTR + aOff] = cvt8v(rb0a, rb0b);
        *(u16x8*)&Bs[nxt][(aRow + 64) * BSTR + aOff] = cvt8v(rb1a, rb1b);
        __syncthreads();
        cur = nxt;
    }
    mfma_step(As[cur], Bs[cur], wr, wc, m16, q, acc);
#pragma unroll
    for (int i = 0; i < 2; i++)
#pragma unroll
        for (int r = 0; r < 4; r++) {
            int pos = o + m0 + wr + i * 16 + q * 4 + r;
            if (pos < o + c) {
                int qpos = (list[pos] >> 1) & (SEQ - 1);
                const float* Rrow = R + (size_t)pos * RSTRIDE;
                float* sr = S + (size_t)pos * SEQ;
#pragma unroll
                for (int j = 0; j < 4; j++) {
                    int key = n0 + wc + j * 16 + m16;
                    int rix = key - qpos;
                    rix = (rix < -MAXPOS ? -MAXPOS : (rix > MAXPOS ? MAXPOS : rix)) + MAXPOS;
                    sr[key] = acc[i][j][r] + Rrow[rix];
                }
            }
        }
}

// ---------------- Row softmax: fp32 S in, bf16 P out (in place, same row slot) ----------------
__global__ __launch_bounds__(256) void softmax_kernel(float* __restrict__ S) {
    int row = blockIdx.x;
    float4* sr = (float4*)(S + (size_t)row * SEQ);
    float4 v = sr[threadIdx.x];
    float m = fmaxf(fmaxf(v.x, v.y), fmaxf(v.z, v.w));
#pragma unroll
    for (int off = 32; off; off >>= 1) m = fmaxf(m, __shfl_down(m, off));
    __shared__ float red0[4], red1[4];
    int wave = threadIdx.x >> 6, lane = threadIdx.x & 63;
    if (lane == 0) red0[wave] = m;
    __syncthreads();
    m = fmaxf(fmaxf(red0[0], red0[1]), fmaxf(red0[2], red0[3]));
    v.x = __expf(v.x - m); v.y = __expf(v.y - m);
    v.z = __expf(v.z - m); v.w = __expf(v.w - m);
    float s = v.x + v.y + v.z + v.w;
#pragma unroll
    for (int off = 32; off; off >>= 1) s += __shfl_down(s, off);
    if (lane == 0) red1[wave] = s;
    __syncthreads();
    float inv = 1.f / (red1[0] + red1[1] + red1[2] + red1[3]);
    // all reads of this row completed before the preceding barrier; safe in-place bf16 write
    ushort* pr = (ushort*)(S + (size_t)row * SEQ);
    ushort4 p4 = { f2b(v.x * inv), f2b(v.y * inv), f2b(v.z * inv), f2b(v.w * inv) };
    *(ushort4*)(pr + threadIdx.x * 4) = p4;
}

// ---------------- pv: split-K MFMA P@V (bf16 P direct), dense partials ----------------
__global__ __launch_bounds__(256) void pv_mfma(
    const ushort* __restrict__ Pb, const ushort* __restrict__ vt16,
    const int* __restrict__ meta, float* __restrict__ ppart) {
    int bin = blockIdx.z;
    int o = meta[32 + bin], c = meta[bin];
    int m0 = blockIdx.x * 64;
    if (m0 >= c) return;
    int b = bin & 3;
    int s = blockIdx.y;
    int kbase = s * 256;
    __shared__ __align__(16) short As[2][64 * BSTR];
    __shared__ __align__(16) short Bs[2][128 * BSTR];
    int tid = threadIdx.x, aRow = tid >> 2, aOff = (tid & 3) * 8;
    const ushort* ap = Pb + (size_t)(o + m0 + aRow) * PROW + kbase + aOff;
    const ushort* bp0 = vt16 + (size_t)b * HD * SEQ + (size_t)aRow * SEQ + kbase + aOff;
    const ushort* bp1 = bp0 + (size_t)64 * SEQ;
    int w = tid >> 6, lid = tid & 63;
    int wr = (w >> 1) * 32, wc = (w & 1) * 64;
    int m16 = lid & 15, q = lid >> 4;
    f32x4 acc[2][4] = {};
    u16x8 ra = *(const u16x8*)ap;
    u16x8 rb0 = *(const u16x8*)bp0, rb1 = *(const u16x8*)bp1;
    *(u16x8*)&As[0][aRow * BSTR + aOff] = ra;
    *(u16x8*)&Bs[0][aRow * BSTR + aOff] = rb0;
    *(u16x8*)&Bs[0][(aRow + 64) * BSTR + aOff] = rb1;
    __syncthreads();
    int cur = 0;
    for (int k = 1; k < 8; k++) {
        ra = *(const u16x8*)(ap + k * 32);
        rb0 = *(const u16x8*)(bp0 + k * 32); rb1 = *(const u16x8*)(bp1 + k * 32);
        mfma_step(As[cur], Bs[cur], wr, wc, m16, q, acc);
        int nxt = cur ^ 1;
        *(u16x8*)&As[nxt][aRow * BSTR + aOff] = ra;
        *(u16x8*)&Bs[nxt][aRow * BSTR + aOff] = rb0;
        *(u16x8*)&Bs[nxt][(aRow + 64) * BSTR + aOff] = rb1;
        __syncthreads();
        cur = nxt;
    }
    mfma_step(As[cur], Bs[cur], wr, wc, m16, q, acc);
#pragma unroll
    for (int i = 0; i < 2; i++)
#pragma unroll
        for (int r = 0; r < 4; r++) {
            int pos = o + m0 + wr + i * 16 + q * 4 + r;
            if (pos < o + c) {
#pragma unroll
                for (int j = 0; j < 4; j++)
                    ppart[((size_t)s * NPAD + pos) * HD + wc + j * 16 + m16] = acc[i][j][r];
            }
        }
}

__global__ void pv_reduce(const float* __restrict__ ppart, const float* __restrict__ aga,
                          const int* __restrict__ list, float* __restrict__ ctxf) {
    int pos = blockIdx.x, h = threadIdx.x;  // 128
    float g = aga[list[pos]];
    float a = 0.f;
#pragma unroll
    for (int s = 0; s < 4; s++) a += ppart[((size_t)s * NPAD + pos) * HD + h];
    ctxf[(size_t)pos * HD + h] = a * g;
}

// ---------------- o: MFMA ctx@o_w, dense bf16 per-pair rows ----------------
__global__ __launch_bounds__(256) void o_mfma(
    const float* __restrict__ ctxf, const ushort* __restrict__ owt,
    const int* __restrict__ meta, ushort* __restrict__ Ofb) {
    int e = blockIdx.z;
    int o = meta[96 + e], c = meta[97 + e] - o;
    int m0 = blockIdx.x * 64;
    if (m0 >= c) return;
    int n0 = blockIdx.y * 128;
    __shared__ __align__(16) short As[2][64 * BSTR];
    __shared__ __align__(16) short Bs[2][128 * BSTR];
    int tid = threadIdx.x, aRow = tid >> 2, aOff = (tid & 3) * 8;
    const float* ap = ctxf + (size_t)(o + m0 + aRow) * HD + aOff;
    const ushort* bp0 = owt + (size_t)e * D * HD + (size_t)(n0 + aRow) * HD + aOff;
    const ushort* bp1 = bp0 + (size_t)64 * HD;
    int w = tid >> 6, lid = tid & 63;
    int wr = (w >> 1) * 32, wc = (w & 1) * 64;
    int m16 = lid & 15, q = lid >> 4;
    f32x4 acc[2][4] = {};
    float4 ra0 = *(const float4*)ap, ra1 = *(const float4*)(ap + 4);
    u16x8 rb0 = *(const u16x8*)bp0, rb1 = *(const u16x8*)bp1;
    *(u16x8*)&As[0][aRow * BSTR + aOff] = cvt8v(ra0, ra1);
    *(u16x8*)&Bs[0][aRow * BSTR + aOff] = rb0;
    *(u16x8*)&Bs[0][(aRow + 64) * BSTR + aOff] = rb1;
    __syncthreads();
    int cur = 0;
    for (int k = 1; k < 4; k++) {
        ra0 = *(const float4*)(ap + k * 32); ra1 = *(const float4*)(ap + k * 32 + 4);
        rb0 = *(const u16x8*)(bp0 + k * 32); rb1 = *(const u16x8*)(bp1 + k * 32);
        mfma_step(As[cur], Bs[cur], wr, wc, m16, q, acc);
        int nxt = cur ^ 1;
        *(u16x8*)&As[nxt][aRow * BSTR + aOff] = cvt8v(ra0, ra1);
        *(u16x8*)&Bs[nxt][aRow * BSTR + aOff] = rb0;
        *(u16x8*)&Bs[nxt][(aRow + 64) * BSTR + aOff] = rb1;
        __syncthreads();
        cur = nxt;
    }
    mfma_step(As[cur], Bs[cur], wr, wc, m16, q, acc);
#pragma unroll
    for (int i = 0; i < 2; i++)
#pragma unroll
        for (int r = 0; r < 4; r++) {
            int pos = o + m0 + wr + i * 16 + q * 4 + r;
            if (pos < o + c) {
#pragma unroll
                for (int j = 0; j < 4; j++)
                    Ofb[(size_t)pos * D + n0 + wc + j * 16 + m16] = f2b(acc[i][j][r]);
            }
        }
}

// ---------------- attn combine ----------------
__global__ void attn_combine(const float* __restrict__ src, const float* __restrict__ ob,
                             const int* __restrict__ aidx, const float* __restrict__ aga,
                             const int* __restrict__ ainv, const ushort* __restrict__ Ofb,
                             float* __restrict__ x1) {
    int t = blockIdx.x, tid = threadIdx.x;
    int e0 = aidx[t * 2], e1 = aidx[t * 2 + 1];
    float g0 = aga[t * 2], g1 = aga[t * 2 + 1];
    int p0 = ainv[t * 2], p1 = ainv[t * 2 + 1];
#pragma unroll
    for (int i = 0; i < 4; i++) {
        int d = tid + i * 256;
        x1[(size_t)t * D + d] = src[(size_t)t * D + d]
                              + g0 * ob[e0 * D + d] + g1 * ob[e1 * D + d]
                              + b2f(Ofb[(size_t)p0 * D + d]) + b2f(Ofb[(size_t)p1 * D + d]);
    }
}

// ---------------- FFN GEMM1: Hb = g*relu(xn2 @ W1 + b1) ----------------
__global__ __launch_bounds__(256) void ffn_mfma1(
    const float* __restrict__ xn2, const ushort* __restrict__ w1t,
    const float* __restrict__ b1, const int* __restrict__ meta,
    const int* __restrict__ list, const float* __restrict__ fga,
    ushort* __restrict__ Hb) {
    int e = blockIdx.z;
    int o = meta[16 + e], c = meta[e];
    int m0 = blockIdx.x * 64;
    if (m0 >= c) return;
    int n0 = blockIdx.y * 128;
    __shared__ __align__(16) short As[2][64 * BSTR];
    __shared__ __align__(16) short Bs[2][128 * BSTR];
    int tid = threadIdx.x, aRow = tid >> 2, aOff = (tid & 3) * 8;
    int ri = o + m0 + aRow; if (ri > NPAIR - 1) ri = NPAIR - 1;
    const float* ap = xn2 + (size_t)(list[ri] >> 1) * D + aOff;
    const ushort* bp0 = w1t + ((size_t)e * FH + n0 + aRow) * D + aOff;
    const ushort* bp1 = bp0 + (size_t)64 * D;
    int w = tid >> 6, lid = tid & 63;
    int wr = (w >> 1) * 32, wc = (w & 1) * 64;
    int m16 = lid & 15, q = lid >> 4;
    f32x4 acc[2][4] = {};
    float4 ra0 = *(const float4*)ap, ra1 = *(const float4*)(ap + 4);
    u16x8 rb0 = *(const u16x8*)bp0, rb1 = *(const u16x8*)bp1;
    *(u16x8*)&As[0][aRow * BSTR + aOff] = cvt8v(ra0, ra1);
    *(u16x8*)&Bs[0][aRow * BSTR + aOff] = rb0;
    *(u16x8*)&Bs[0][(aRow + 64) * BSTR + aOff] = rb1;
    __syncthreads();
    int cur = 0;
    for (int k = 1; k < 32; k++) {
        ra0 = *(const float4*)(ap + k * 32); ra1 = *(const float4*)(ap + k * 32 + 4);
        rb0 = *(const u16x8*)(bp0 + k * 32); rb1 = *(const u16x8*)(bp1 + k * 32);
        mfma_step(As[cur], Bs[cur], wr, wc, m16, q, acc);
        int nxt = cur ^ 1;
        *(u16x8*)&As[nxt][aRow * BSTR + aOff] = cvt8v(ra0, ra1);
        *(u16x8*)&Bs[nxt][aRow * BSTR + aOff] = rb0;
        *(u16x8*)&Bs[nxt][(aRow + 64) * BSTR + aOff] = rb1;
        __syncthreads();
        cur = nxt;
    }
    mfma_step(As[cur], Bs[cur], wr, wc, m16, q, acc);
#pragma unroll
    for (int i = 0; i < 2; i++)
#pragma unroll
        for (int r = 0; r < 4; r++) {
            int pos = o + m0 + wr + i * 16 + q * 4 + r;
            if (pos < o + c) {
                float g = fga[list[pos]];
#pragma unroll
                for (int j = 0; j < 4; j++) {
                    int n = n0 + wc + j * 16 + m16;
                    Hb[(size_t)pos * FH + n] = f2b(g * fmaxf(acc[i][j][r] + b1[e * FH + n], 0.f));
                }
            }
        }
}

// ---------------- FFN GEMM2: Of2b[pos] = Hb @ W2 (dense bf16 rows) ----------------
__global__ __launch_bounds__(256) void ffn_mfma2(
    const ushort* __restrict__ Hb, const ushort* __restrict__ w2t,
    const int* __restrict__ meta, ushort* __restrict__ Of2b) {
    int e = blockIdx.z;
    int o = meta[16 + e], c = meta[e];
    int m0 = blockIdx.x * 64;
    if (m0 >= c) return;
    int n0 = blockIdx.y * 128;
    __shared__ __align__(16) short As[2][64 * BSTR];
    __shared__ __align__(16) short Bs[2][128 * BSTR];
    int tid = threadIdx.x, aRow = tid >> 2, aOff = (tid & 3) * 8;
    const ushort* ap = Hb + (size_t)(o + m0 + aRow) * FH + aOff;
    const ushort* bp0 = w2t + ((size_t)e * D + n0 + aRow) * FH + aOff;
    const ushort* bp1 = bp0 + (size_t)64 * FH;
    int w = tid >> 6, lid = tid & 63;
    int wr = (w >> 1) * 32, wc = (w & 1) * 64;
    int m16 = lid & 15, q = lid >> 4;
    f32x4 acc[2][4] = {};
    u16x8 ra = *(const u16x8*)ap;
    u16x8 rb0 = *(const u16x8*)bp0, rb1 = *(const u16x8*)bp1;
    *(u16x8*)&As[0][aRow * BSTR + aOff] = ra;
    *(u16x8*)&Bs[0][aRow * BSTR + aOff] = rb0;
    *(u16x8*)&Bs[0][(aRow + 64) * BSTR + aOff] = rb1;
    __syncthreads();
    int cur = 0;
    for (int k = 1; k < 16; k++) {
        ra = *(const u16x8*)(ap + k * 32);
        rb0 = *(const u16x8*)(bp0 + k * 32); rb1 = *(const u16x8*)(bp1 + k * 32);
        mfma_step(As[cur], Bs[cur], wr, wc, m16, q, acc);
        int nxt = cur ^ 1;
        *(u16x8*)&As[nxt][aRow * BSTR + aOff] = ra;
        *(u16x8*)&Bs[nxt][aRow * BSTR + aOff] = rb0;
        *(u16x8*)&Bs[nxt][(aRow + 64) * BSTR + aOff] = rb1;
        __syncthreads();
        cur = nxt;
    }
    mfma_step(As[cur], Bs[cur], wr, wc, m16, q, acc);
#pragma unroll
    for (int i = 0; i < 2; i++)
#pragma unroll
        for (int r = 0; r < 4; r++) {
            int pos = o + m0 + wr + i * 16 + q * 4 + r;
            if (pos < o + c) {
#pragma unroll
                for (int j = 0; j < 4; j++)
                    Of2b[(size_t)pos * D + n0 + wc + j * 16 + m16] = f2b(acc[i][j][r]);
            }
        }
}

// ---------------- FFN combine ----------------
__global__ void ffn_combine(const float* __restrict__ x1, const float* __restrict__ b2,
                            const int* __restrict__ fidx, const float* __restrict__ fga,
                            const int* __restrict__ finv, const ushort* __restrict__ Of2b,
                            float* __restrict__ out) {
    int t = blockIdx.x, tid = threadIdx.x;
    int e0 = fidx[t * 2], e1 = fidx[t * 2 + 1];
    float g0 = fga[t * 2], g1 = fga[t * 2 + 1];
    int p0 = finv[t * 2], p1 = finv[t * 2 + 1];
#pragma unroll
    for (int i = 0; i < 4; i++) {
        int d = tid + i * 256;
        out[(size_t)t * D + d] = x1[(size_t)t * D + d]
                               + g0 * b2[e0 * D + d] + g1 * b2[e1 * D + d]
                               + b2f(Of2b[(size_t)p0 * D + d]) + b2f(Of2b[(size_t)p1 * D + d]);
    }
}

extern "C" void kernel_launch(void* const* d_in, const int* in_sizes, int n_in,
                              void* d_out, int out_size, void* d_ws, size_t ws_size,
                              hipStream_t stream) {
    const float* src   = (const float*)d_in[0];
    const float* ln1_w = (const float*)d_in[1];
    const float* ln1_b = (const float*)d_in[2];
    const float* ln2_w = (const float*)d_in[3];
    const float* ln2_b = (const float*)d_in[4];
    const float* agw   = (const float*)d_in[5];
    const float* qw    = (const float*)d_in[6];
    const float* qb    = (const float*)d_in[7];
    const float* kw    = (const float*)d_in[8];
    const float* kb    = (const float*)d_in[9];
    const float* vw    = (const float*)d_in[10];
    const float* vb    = (const float*)d_in[11];
    const float* ow    = (const float*)d_in[12];
    const float* ob    = (const float*)d_in[13];
    const float* rel   = (const float*)d_in[14];
    const float* fgw   = (const float*)d_in[15];
    const float* w1    = (const float*)d_in[16];
    const float* b1    = (const float*)d_in[17];
    const float* w2    = (const float*)d_in[18];
    const float* b2    = (const float*)d_in[19];
    float* out = (float*)d_out;

    char* p = (char*)d_ws;
    float* xn1  = (float*)p; p += (size_t)NTOK * D * 4;               // LN out (both LNs)
    float* x1   = (float*)p; p += (size_t)NTOK * D * 4;
    char*  sreg = p;         p += (size_t)NPAD * SEQ * 4;             // 34.1 MB
    float*  Sbuf = (float*)sreg;                                      // attn: scores (fp32) / P (bf16 in place)
    ushort* Pb   = (ushort*)sreg;                                     // bf16 P, row stride PROW
    ushort* Ofb  = (ushort*)sreg;                                     // attn: o rows (17 MB)
    ushort* w1t  = (ushort*)sreg;                                     // FFN: 16.78 MB
    ushort* w2t  = (ushort*)(sreg + (size_t)16777216);                // FFN: 16.78 MB
    char*  reg  = p;         p += (size_t)NPAD * 128 * 6 + (size_t)NPAIR * RSTRIDE * 4;
    float*  ctxf = (float*)reg;                                       // 4.26 MB
    ushort* Qg   = (ushort*)(reg + (size_t)NPAD * 128 * 4);           // 2.13 MB
    float*  Rbuf = (float*)(reg + (size_t)NPAD * 128 * 6);            // 4.33 MB
    ushort* Hb   = (ushort*)reg;                                      // FFN hidden (8.52 MB)
    char*  arena = p;        p += (size_t)4 * NPAD * 128 * 4;         // 17.04 MB
    float*  kpart = (float*)arena;
    float*  vpart = (float*)(arena + (size_t)4 * NTOK * HD * 4);
    float*  qpart = (float*)arena;
    float*  ppart = (float*)arena;
    ushort* Of2b  = (ushort*)arena;
    float* kbf  = (float*)p; p += (size_t)NTOK * HD * 4;
    float* vbf  = (float*)p; p += (size_t)NTOK * HD * 4;
    ushort* vt16 = (ushort*)p; p += (size_t)NTOK * HD * 2;
    ushort* kwt = (ushort*)p; p += (size_t)HD * D * 2;
    ushort* vwt = (ushort*)p; p += (size_t)HD * D * 2;
    ushort* qwt = (ushort*)p; p += (size_t)EA * HD * D * 2;
    ushort* owt = (ushort*)p; p += (size_t)EA * D * HD * 2;
    ushort* relb = (ushort*)p; p += (size_t)RNUM * HD * 2 + 256;
    int*   aidx = (int*)p;   p += NPAIR * 4;
    float* aga  = (float*)p; p += NPAIR * 4;
    int*   fidx = (int*)p;   p += NPAIR * 4;
    float* fga  = (float*)p; p += NPAIR * 4;
    int*   ameta = (int*)p;  p += 128 * 4;
    int*   alist = (int*)p;  p += NPAIR * 4;
    int*   ainv = (int*)p;   p += NPAIR * 4;
    int*   fmeta = (int*)p;  p += 64 * 4;
    int*   flist = (int*)p;  p += NPAIR * 4;
    int*   finv = (int*)p;   p += NPAIR * 4;
    float* xn2 = xn1;

    // ---- attention ----
    ln_kernel<<<NTOK, 256, 0, stream>>>(src, ln1_w, ln1_b, xn1);
    router_kernel<EA><<<NTOK, 64, 0, stream>>>(xn1, agw, aidx, aga);
    abin_zero<<<1, 128, 0, stream>>>(ameta);
    abin_count<<<NPAIR / 256, 256, 0, stream>>>(aidx, ameta);
    abin_scan<<<1, 64, 0, stream>>>(ameta);
    abin_scatter<<<NPAIR / 256, 256, 0, stream>>>(aidx, ameta, alist, ainv);
    convT_kernel<1024, 128><<<dim3(32, 4, 1), 256, 0, stream>>>(kw, kwt);
    convT_kernel<1024, 128><<<dim3(32, 4, 1), 256, 0, stream>>>(vw, vwt);
    convT_kernel<1024, 128><<<dim3(32, 4, EA), 256, 0, stream>>>(qw, qwt);
    convT_kernel<128, 1024><<<dim3(4, 32, EA), 256, 0, stream>>>(ow, owt);
    conv_kernel<<<(RNUM * HD + 255) / 256, 256, 0, stream>>>(rel, relb, RNUM * HD);
    kv_mfma<<<dim3(64, 4, 2), 256, 0, stream>>>(xn1, kwt, vwt, kpart, vpart);
    kv_reduce<<<NTOK, 128, 0, stream>>>(kpart, vpart, kb, vb, kbf, vbf);
    convT_kernel<1024, 128><<<dim3(32, 4, 4), 256, 0, stream>>>(vbf, vt16);
    q_mfma<<<dim3(40, 4, EA), 256, 0, stream>>>(xn1, qwt, ameta, alist, qpart);
    q_reduce<<<NPAIR, 128, 0, stream>>>(qpart, qb, aidx, alist, Qg);
    rel_mfma<<<dim3(NPAIR / 64, 2), 256, 0, stream>>>(Qg, relb, Rbuf);
    s_mfma<<<dim3(12, 8, 32), 256, 0, stream>>>(Qg, kbf, Rbuf, ameta, alist, Sbuf);
    softmax_kernel<<<NPAIR, 256, 0, stream>>>(Sbuf);
    pv_mfma<<<dim3(12, 4, 32), 256, 0, stream>>>(Pb, vt16, ameta, ppart);
    pv_reduce<<<NPAIR, 128, 0, stream>>>(ppart, aga, alist, ctxf);
    o_mfma<<<dim3(40, 8, EA), 256, 0, stream>>>(ctxf, owt, ameta, Ofb);
    attn_combine<<<NTOK, 256, 0, stream>>>(src, ob, aidx, aga, ainv, Ofb, x1);

    // ---- FFN ----
    ln_kernel<<<NTOK, 256, 0, stream>>>(x1, ln2_w, ln2_b, xn2);
    router_kernel<EF><<<NTOK, 64, 0, stream>>>(xn2, fgw, fidx, fga);
    bin_zero<<<1, 64, 0, stream>>>(fmeta);
    bin_count<<<NPAIR / 256, 256, 0, stream>>>(fidx, fmeta);
    bin_scan<<<1, 64, 0, stream>>>(fmeta);
    bin_scatter<<<NPAIR / 256, 256, 0, stream>>>(fidx, fmeta, flist, finv);
    convT_kernel<1024, 512><<<dim3(32, 16, EF), 256, 0, stream>>>(w1, w1t);
    convT_kernel<512, 1024><<<dim3(16, 32, EF), 256, 0, stream>>>(w2, w2t);
    ffn_mfma1<<<dim3(20, 4, EF), 256, 0, stream>>>(xn2, w1t, b1, fmeta, flist, fga, Hb);
    ffn_mfma2<<<dim3(20, 8, EF), 256, 0, stream>>>(Hb, w2t, fmeta, Of2b);
    ffn_combine<<<NTOK, 256, 0, stream>>>(x1, b2, fidx, fga, finv, Of2b, out);
}